// Round 1
// baseline (1198.281 us; speedup 1.0000x reference)
//
#include <hip/hip_runtime.h>
#include <hip/hip_bf16.h>
#include <hip/hip_cooperative_groups.h>

namespace cg = cooperative_groups;

#define B_ 16
#define T_ 32
#define N_ 256
#define F_ 128
#define H_ 128
#define HL_ 256

typedef float f32x4 __attribute__((ext_vector_type(4)));
typedef short bf16x8 __attribute__((ext_vector_type(8)));

#define MFMA16(A, Bv, C) __builtin_amdgcn_mfma_f32_16x16x32_bf16((A), (Bv), (C), 0, 0, 0)

__device__ __forceinline__ unsigned short f2bf(float f) {
    unsigned u = __builtin_bit_cast(unsigned, f);
    return (unsigned short)((u + 0x7FFFu + ((u >> 16) & 1u)) >> 16);
}

__device__ __forceinline__ bf16x8 cvt8(const float* p) {
    f32x4 a = *(const f32x4*)p;
    f32x4 b = *(const f32x4*)(p + 4);
    bf16x8 r;
    r[0] = (short)f2bf(a[0]); r[1] = (short)f2bf(a[1]);
    r[2] = (short)f2bf(a[2]); r[3] = (short)f2bf(a[3]);
    r[4] = (short)f2bf(b[0]); r[5] = (short)f2bf(b[1]);
    r[6] = (short)f2bf(b[2]); r[7] = (short)f2bf(b[3]);
    return r;
}

__device__ __forceinline__ bf16x8 expand_bits(unsigned b) {
    bf16x8 r;
#pragma unroll
    for (int j = 0; j < 8; ++j) r[j] = (short)(((b >> j) & 1u) ? 0x3F80 : 0);
    return r;
}

__device__ __forceinline__ float sigf(float x) { return 1.f / (1.f + __expf(-x)); }
__device__ __forceinline__ float tanhf_(float x) { float e = __expf(2.f * x); return 1.f - 2.f / (e + 1.f); }

// ---------------- weight prep: W1^T, W2^T in bf16 ----------------
__global__ void k_prep(const float* __restrict__ W1, const float* __restrict__ W2,
                       unsigned short* __restrict__ w1t, unsigned short* __restrict__ w2t) {
    int idx = blockIdx.x * 256 + threadIdx.x;   // 64 blocks * 256 = 16384
    int h = idx >> 7, f = idx & 127;
    w1t[idx] = f2bf(W1[f * 128 + h]);
    w2t[idx] = f2bf(W2[f * 128 + h]);
}

// ---------------- gcn_a: bitmask+dinv from adj, XWT' = dinv .* (x@W1)^T bf16 ----------------
__global__ __launch_bounds__(512, 2) void k_gcn_a(
    const int* __restrict__ adj, const float* __restrict__ x,
    const unsigned short* __restrict__ w1t,
    unsigned short* __restrict__ ft, unsigned char* __restrict__ gbm,
    float* __restrict__ gdinv) {
    __shared__ unsigned char s_bm[256 * 32];
    __shared__ float s_dinv[256];
    __shared__ unsigned short s_w[128 * 136];
    const int bt = blockIdx.x;
    const int tid = threadIdx.x;
    const int* adjb = adj + (size_t)bt * (N_ * N_);

    for (int it = 0; it < 16; ++it) {
        int row = it * 16 + (tid >> 5);
        int c = tid & 31, m0 = c * 8;
        const int* p = adjb + row * N_ + m0;
        int4 q0 = *(const int4*)p;
        int4 q1 = *(const int4*)(p + 4);
        unsigned by = 0;
        by |= (((q0.x != 0) | (m0 + 0 == row)) ? 1u : 0u);
        by |= (((q0.y != 0) | (m0 + 1 == row)) ? 2u : 0u);
        by |= (((q0.z != 0) | (m0 + 2 == row)) ? 4u : 0u);
        by |= (((q0.w != 0) | (m0 + 3 == row)) ? 8u : 0u);
        by |= (((q1.x != 0) | (m0 + 4 == row)) ? 16u : 0u);
        by |= (((q1.y != 0) | (m0 + 5 == row)) ? 32u : 0u);
        by |= (((q1.z != 0) | (m0 + 6 == row)) ? 64u : 0u);
        by |= (((q1.w != 0) | (m0 + 7 == row)) ? 128u : 0u);
        s_bm[row * 32 + c] = (unsigned char)by;
        int pc = __popc(by);
        pc += __shfl_xor(pc, 1); pc += __shfl_xor(pc, 2); pc += __shfl_xor(pc, 4);
        pc += __shfl_xor(pc, 8); pc += __shfl_xor(pc, 16);
        if (c == 0) s_dinv[row] = rsqrtf((float)pc);
    }
    for (int it = 0; it < 4; ++it) {
        int g = it * 512 + tid;
        *(int4*)(&s_w[(g >> 4) * 136 + (g & 15) * 8]) = *(const int4*)(w1t + g * 8);
    }
    __syncthreads();
    *(int4*)(gbm + (size_t)bt * 8192 + tid * 16) = *(const int4*)(s_bm + tid * 16);
    if (tid < 64) *(float4*)(gdinv + bt * 256 + tid * 4) = *(const float4*)(s_dinv + tid * 4);

    const int w = tid >> 6, l = tid & 63, li = l & 15, lg = l >> 4;
    const float* xb = x + (size_t)bt * (N_ * F_);
    f32x4 acc[2][8];
#pragma unroll
    for (int a = 0; a < 2; ++a)
#pragma unroll
        for (int c = 0; c < 8; ++c) acc[a][c] = (f32x4){0.f, 0.f, 0.f, 0.f};

#pragma unroll
    for (int ks = 0; ks < 4; ++ks) {
        bf16x8 a0 = cvt8(xb + (size_t)(32 * w + li) * F_ + lg * 8 + ks * 32);
        bf16x8 a1 = cvt8(xb + (size_t)(32 * w + 16 + li) * F_ + lg * 8 + ks * 32);
#pragma unroll
        for (int ct = 0; ct < 8; ++ct) {
            bf16x8 bv = *(const bf16x8*)(&s_w[(16 * ct + li) * 136 + lg * 8 + ks * 32]);
            acc[0][ct] = MFMA16(a0, bv, acc[0][ct]);
            acc[1][ct] = MFMA16(a1, bv, acc[1][ct]);
        }
    }
#pragma unroll
    for (int rt = 0; rt < 2; ++rt) {
        int m0 = 32 * w + 16 * rt + 4 * lg;
        f32x4 dv = *(const f32x4*)(&s_dinv[m0]);
#pragma unroll
        for (int ct = 0; ct < 8; ++ct) {
            int h = 16 * ct + li;
            f32x4 v = acc[rt][ct];
            unsigned p0 = (unsigned)f2bf(v[0] * dv[0]) | ((unsigned)f2bf(v[1] * dv[1]) << 16);
            unsigned p1 = (unsigned)f2bf(v[2] * dv[2]) | ((unsigned)f2bf(v[3] * dv[3]) << 16);
            uint2 pk; pk.x = p0; pk.y = p1;
            *(uint2*)(ft + ((size_t)bt * H_ + h) * N_ + m0) = pk;
        }
    }
}

// ---------------- gcn_b: h1 = relu(norm@XW + b1); FT <- dinv .* (h1@W2)^T ----------------
__global__ __launch_bounds__(512, 2) void k_gcn_b(
    unsigned short* ft,
    const unsigned char* __restrict__ gbm, const float* __restrict__ gdinv,
    const float* __restrict__ b1, const unsigned short* __restrict__ w2t) {
    __shared__ unsigned short s_ft[256 * 136];   // XWT [128][264] then h1 [256][136]
    __shared__ unsigned short s_w[128 * 136];
    __shared__ unsigned char s_bm[8192];
    __shared__ float s_dinv[256];
    __shared__ float s_b[128];
    const int bt = blockIdx.x, tid = threadIdx.x;
#pragma unroll
    for (int it = 0; it < 8; ++it) {
        int g = it * 512 + tid;
        *(int4*)(&s_ft[(g >> 5) * 264 + (g & 31) * 8]) = *(const int4*)(ft + (size_t)bt * 32768 + g * 8);
    }
#pragma unroll
    for (int it = 0; it < 4; ++it) {
        int g = it * 512 + tid;
        *(int4*)(&s_w[(g >> 4) * 136 + (g & 15) * 8]) = *(const int4*)(w2t + g * 8);
    }
    *(int4*)(s_bm + tid * 16) = *(const int4*)(gbm + (size_t)bt * 8192 + tid * 16);
    if (tid < 64) *(float4*)(&s_dinv[tid * 4]) = *(const float4*)(gdinv + bt * 256 + tid * 4);
    if (tid < 32) *(float4*)(&s_b[tid * 4]) = *(const float4*)(b1 + tid * 4);
    __syncthreads();

    const int w = tid >> 6, l = tid & 63, li = l & 15, lg = l >> 4;
    f32x4 acc[2][8];
#pragma unroll
    for (int a = 0; a < 2; ++a)
#pragma unroll
        for (int c = 0; c < 8; ++c) acc[a][c] = (f32x4){0.f, 0.f, 0.f, 0.f};

#pragma unroll
    for (int ks = 0; ks < 8; ++ks) {
        bf16x8 a0 = expand_bits(s_bm[(32 * w + li) * 32 + 4 * ks + lg]);
        bf16x8 a1 = expand_bits(s_bm[(32 * w + 16 + li) * 32 + 4 * ks + lg]);
#pragma unroll
        for (int ct = 0; ct < 8; ++ct) {
            bf16x8 bv = *(const bf16x8*)(&s_ft[(16 * ct + li) * 264 + lg * 8 + ks * 32]);
            acc[0][ct] = MFMA16(a0, bv, acc[0][ct]);
            acc[1][ct] = MFMA16(a1, bv, acc[1][ct]);
        }
    }
    __syncthreads();   // all XWT reads done; reuse region as h1
#pragma unroll
    for (int rt = 0; rt < 2; ++rt) {
        int i0 = 32 * w + 16 * rt + 4 * lg;
        f32x4 dv = *(const f32x4*)(&s_dinv[i0]);
#pragma unroll
        for (int ct = 0; ct < 8; ++ct) {
            int h = 16 * ct + li;
            float bb = s_b[h];
#pragma unroll
            for (int r = 0; r < 4; ++r)
                s_ft[(i0 + r) * 136 + h] = f2bf(fmaxf(acc[rt][ct][r] * dv[r] + bb, 0.f));
        }
    }
    __syncthreads();
    // gemm2: h1 @ W2  (K=128)
#pragma unroll
    for (int a = 0; a < 2; ++a)
#pragma unroll
        for (int c = 0; c < 8; ++c) acc[a][c] = (f32x4){0.f, 0.f, 0.f, 0.f};
#pragma unroll
    for (int ks = 0; ks < 4; ++ks) {
        bf16x8 a0 = *(const bf16x8*)(&s_ft[(32 * w + li) * 136 + lg * 8 + ks * 32]);
        bf16x8 a1 = *(const bf16x8*)(&s_ft[(32 * w + 16 + li) * 136 + lg * 8 + ks * 32]);
#pragma unroll
        for (int ct = 0; ct < 8; ++ct) {
            bf16x8 bv = *(const bf16x8*)(&s_w[(16 * ct + li) * 136 + lg * 8 + ks * 32]);
            acc[0][ct] = MFMA16(a0, bv, acc[0][ct]);
            acc[1][ct] = MFMA16(a1, bv, acc[1][ct]);
        }
    }
#pragma unroll
    for (int rt = 0; rt < 2; ++rt) {
        int m0 = 32 * w + 16 * rt + 4 * lg;
        f32x4 dv = *(const f32x4*)(&s_dinv[m0]);
#pragma unroll
        for (int ct = 0; ct < 8; ++ct) {
            int h = 16 * ct + li;
            f32x4 v = acc[rt][ct];
            unsigned p0 = (unsigned)f2bf(v[0] * dv[0]) | ((unsigned)f2bf(v[1] * dv[1]) << 16);
            unsigned p1 = (unsigned)f2bf(v[2] * dv[2]) | ((unsigned)f2bf(v[3] * dv[3]) << 16);
            uint2 pk; pk.x = p0; pk.y = p1;
            *(uint2*)(ft + ((size_t)bt * H_ + h) * N_ + m0) = pk;
        }
    }
}

// ---------------- gcn_c: h2 = relu(norm@H1W + b2); emb = mean_n(h2) ----------------
__global__ __launch_bounds__(512, 2) void k_gcn_c(
    const unsigned short* __restrict__ ft, const unsigned char* __restrict__ gbm,
    const float* __restrict__ gdinv, const float* __restrict__ b2,
    float* __restrict__ emb) {
    __shared__ unsigned short s_ft[128 * 264];
    __shared__ unsigned char s_bm[8192];
    __shared__ float s_dinv[256];
    __shared__ float s_b[128];
    __shared__ float s_pool[8 * 128];
    const int bt = blockIdx.x, tid = threadIdx.x;
#pragma unroll
    for (int it = 0; it < 8; ++it) {
        int g = it * 512 + tid;
        *(int4*)(&s_ft[(g >> 5) * 264 + (g & 31) * 8]) = *(const int4*)(ft + (size_t)bt * 32768 + g * 8);
    }
    *(int4*)(s_bm + tid * 16) = *(const int4*)(gbm + (size_t)bt * 8192 + tid * 16);
    if (tid < 64) *(float4*)(&s_dinv[tid * 4]) = *(const float4*)(gdinv + bt * 256 + tid * 4);
    if (tid < 32) *(float4*)(&s_b[tid * 4]) = *(const float4*)(b2 + tid * 4);
    __syncthreads();

    const int w = tid >> 6, l = tid & 63, li = l & 15, lg = l >> 4;
    f32x4 acc[2][8];
#pragma unroll
    for (int a = 0; a < 2; ++a)
#pragma unroll
        for (int c = 0; c < 8; ++c) acc[a][c] = (f32x4){0.f, 0.f, 0.f, 0.f};
#pragma unroll
    for (int ks = 0; ks < 8; ++ks) {
        bf16x8 a0 = expand_bits(s_bm[(32 * w + li) * 32 + 4 * ks + lg]);
        bf16x8 a1 = expand_bits(s_bm[(32 * w + 16 + li) * 32 + 4 * ks + lg]);
#pragma unroll
        for (int ct = 0; ct < 8; ++ct) {
            bf16x8 bv = *(const bf16x8*)(&s_ft[(16 * ct + li) * 264 + lg * 8 + ks * 32]);
            acc[0][ct] = MFMA16(a0, bv, acc[0][ct]);
            acc[1][ct] = MFMA16(a1, bv, acc[1][ct]);
        }
    }
    int i0a = 32 * w + 4 * lg;
    f32x4 dv0 = *(const f32x4*)(&s_dinv[i0a]);
    f32x4 dv1 = *(const f32x4*)(&s_dinv[i0a + 16]);
#pragma unroll
    for (int ct = 0; ct < 8; ++ct) {
        int h = 16 * ct + li;
        float bb = s_b[h];
        float s = 0.f;
#pragma unroll
        for (int r = 0; r < 4; ++r) {
            s += fmaxf(acc[0][ct][r] * dv0[r] + bb, 0.f);
            s += fmaxf(acc[1][ct][r] * dv1[r] + bb, 0.f);
        }
        s += __shfl_xor(s, 16);
        s += __shfl_xor(s, 32);
        if (lg == 0) s_pool[w * 128 + h] = s;
    }
    __syncthreads();
    if (tid < 128) {
        float e = 0.f;
#pragma unroll
        for (int ww = 0; ww < 8; ++ww) e += s_pool[ww * 128 + tid];
        emb[(size_t)bt * 128 + tid] = e * (1.f / 256.f);
    }
}

// ---------------- xg = emb @ Wih0^T + bih0 + bhh0   (layout [t][b][1024]) ----------------
__global__ __launch_bounds__(256, 2) void k_xg(
    const float* __restrict__ emb, const float* __restrict__ Wih0,
    const float* __restrict__ bih0, const float* __restrict__ bhh0,
    float* __restrict__ xg) {
    __shared__ float s_e[8][128];
    const int bk = blockIdx.x, tid = threadIdx.x;
    for (int q = 0; q < 4; ++q) {
        int idx = q * 256 + tid;
        int p = idx >> 7, k = idx & 127;
        int tb2 = bk * 8 + p;
        int t = tb2 >> 4, b = tb2 & 15;
        s_e[p][k] = emb[(size_t)(b * T_ + t) * 128 + k];
    }
    __syncthreads();
    for (int cc = 0; cc < 4; ++cc) {
        int col = cc * 256 + tid;
        float bias = bih0[col] + bhh0[col];
        const float4* wr = (const float4*)(Wih0 + (size_t)col * 128);
        float accv[8] = {0, 0, 0, 0, 0, 0, 0, 0};
        for (int k4 = 0; k4 < 32; ++k4) {
            float4 wv = wr[k4];
#pragma unroll
            for (int p = 0; p < 8; ++p) {
                float4 ev = *(const float4*)(&s_e[p][k4 * 4]);
                accv[p] += wv.x * ev.x + wv.y * ev.y + wv.z * ev.z + wv.w * ev.w;
            }
        }
#pragma unroll
        for (int p = 0; p < 8; ++p) {
            int tb2 = bk * 8 + p;
            xg[(size_t)tb2 * 1024 + col] = accv[p] + bias;
        }
    }
}

// ---------------- cooperative 2-layer LSTM + FC ----------------
// hbuf: h0[2][16][256] @ 0 floats, h1[2][16][256] @ 8192 floats
__global__ __launch_bounds__(512, 2) void k_lstm(
    const float* __restrict__ xg, const float* __restrict__ Whh0,
    const float* __restrict__ Wih1, const float* __restrict__ Whh1,
    const float* __restrict__ bih1, const float* __restrict__ bhh1,
    const float* __restrict__ Wfc, const float* __restrict__ bfc,
    float* hbuf, float* __restrict__ out) {
    cg::grid_group grid = cg::this_grid();
    const int wg = blockIdx.x, tid = threadIdx.x;
    __shared__ float s_part[512];
    __shared__ float s_gates[256];
    if (wg < 32) hbuf[wg * 512 + tid] = 0.f;
    grid.sync();
    float c_reg = 0.f;

    for (int p = 0; p < 33; ++p) {
        if (wg < 64) {
            if (p < 32) {   // layer0 step t=p : j-slice [4*wg, 4*wg+4)
                const int b = tid >> 5, rem = tid & 31;
                const int jl = rem & 3, g = (rem >> 2) & 3, kh = rem >> 4;
                const int r = g * 256 + wg * 4 + jl;
                float s = 0.f;
                if (p > 0) {
                    const float* hp = hbuf + ((p + 1) & 1) * 4096 + b * 256 + kh * 128;
                    const float* wr = Whh0 + (size_t)r * 256 + kh * 128;
                    for (int k = 0; k < 128; k += 4) {
                        float4 w4 = *(const float4*)(wr + k);
                        float4 h4 = *(const float4*)(hp + k);
                        s += w4.x * h4.x + w4.y * h4.y + w4.z * h4.z + w4.w * h4.w;
                    }
                }
                s_part[tid] = s;
                __syncthreads();
                if (tid < 256) {
                    int b2 = tid >> 4, rem2 = tid & 15, jl2 = rem2 >> 2, g2 = rem2 & 3;
                    int pi = b2 * 32 + jl2 + 4 * g2;
                    float gate = xg[(size_t)(p * 16 + b2) * 1024 + g2 * 256 + wg * 4 + jl2]
                               + s_part[pi] + s_part[pi + 16];
                    s_gates[b2 * 16 + jl2 * 4 + g2] = gate;
                }
                __syncthreads();
                if (tid < 64) {
                    int b3 = tid >> 2, jl3 = tid & 3;
                    const float* gp = s_gates + b3 * 16 + jl3 * 4;
                    float gi = gp[0], gf = gp[1], gg = gp[2], go = gp[3];
                    c_reg = sigf(gf) * c_reg + sigf(gi) * tanhf_(gg);
                    hbuf[(p & 1) * 4096 + b3 * 256 + wg * 4 + jl3] = sigf(go) * tanhf_(c_reg);
                }
            }
        } else {
            if (p >= 1) {   // layer1 step t=p-1 : j-slice [2*w2, 2*w2+2)
                const int w2 = wg - 64, t = p - 1;
                const int b = tid >> 5, rem = tid & 31;
                const int jl = rem & 1, g = (rem >> 1) & 3, kq = rem >> 3;
                const int r = g * 256 + w2 * 2 + jl;
                float s = 0.f;
                const float* hp; const float* wr;
                bool act = true;
                if (kq < 2) {
                    hp = hbuf + (t & 1) * 4096 + b * 256 + kq * 128;
                    wr = Wih1 + (size_t)r * 256 + kq * 128;
                } else {
                    act = (t > 0);
                    hp = hbuf + 8192 + ((t + 1) & 1) * 4096 + b * 256 + (kq - 2) * 128;
                    wr = Whh1 + (size_t)r * 256 + (kq - 2) * 128;
                }
                if (act) {
                    for (int k = 0; k < 128; k += 4) {
                        float4 w4 = *(const float4*)(wr + k);
                        float4 h4 = *(const float4*)(hp + k);
                        s += w4.x * h4.x + w4.y * h4.y + w4.z * h4.z + w4.w * h4.w;
                    }
                }
                s_part[tid] = s;
                __syncthreads();
                if (tid < 128) {
                    int b2 = tid >> 3, rem2 = tid & 7, jl2 = rem2 >> 2, g2 = rem2 & 3;
                    int pi = b2 * 32 + jl2 + 2 * g2;
                    int col = g2 * 256 + w2 * 2 + jl2;
                    float gate = bih1[col] + bhh1[col]
                               + s_part[pi] + s_part[pi + 8] + s_part[pi + 16] + s_part[pi + 24];
                    s_gates[b2 * 8 + jl2 * 4 + g2] = gate;
                }
                __syncthreads();
                if (tid < 32) {
                    int b3 = tid >> 1, jl3 = tid & 1;
                    const float* gp = s_gates + b3 * 8 + jl3 * 4;
                    float gi = gp[0], gf = gp[1], gg = gp[2], go = gp[3];
                    c_reg = sigf(gf) * c_reg + sigf(gi) * tanhf_(gg);
                    hbuf[8192 + (t & 1) * 4096 + b3 * 256 + w2 * 2 + jl3] = sigf(go) * tanhf_(c_reg);
                }
            }
        }
        grid.sync();
    }
    if (wg == 0) {   // FC + sigmoid; h1 final at parity (31&1)=1
        const float* hf = hbuf + 8192 + 4096;
        if (tid < 256) {
            int b = tid >> 4, ks = tid & 15;
            float s = 0.f;
#pragma unroll
            for (int k = 0; k < 16; ++k) s += Wfc[ks * 16 + k] * hf[b * 256 + ks * 16 + k];
            s_part[tid] = s;
        }
        __syncthreads();
        if (tid < 16) {
            float s = bfc[0];
#pragma unroll
            for (int q = 0; q < 16; ++q) s += s_part[tid * 16 + q];
            out[tid] = sigf(s);
        }
    }
}

extern "C" void kernel_launch(void* const* d_in, const int* in_sizes, int n_in,
                              void* d_out, int out_size, void* d_ws, size_t ws_size,
                              hipStream_t stream) {
    const int*   adj  = (const int*)  d_in[0];
    const float* x    = (const float*)d_in[1];
    const float* W1   = (const float*)d_in[2];
    const float* b1   = (const float*)d_in[3];
    const float* W2   = (const float*)d_in[4];
    const float* b2   = (const float*)d_in[5];
    const float* Wih0 = (const float*)d_in[6];
    const float* Whh0 = (const float*)d_in[7];
    const float* bih0 = (const float*)d_in[8];
    const float* bhh0 = (const float*)d_in[9];
    const float* Wih1 = (const float*)d_in[10];
    const float* Whh1 = (const float*)d_in[11];
    const float* bih1 = (const float*)d_in[12];
    const float* bhh1 = (const float*)d_in[13];
    const float* Wfc  = (const float*)d_in[14];
    const float* bfc  = (const float*)d_in[15];
    float* out = (float*)d_out;

    if (ws_size < 40763392) return;   // need ~40.8 MB scratch

    char* ws = (char*)d_ws;
    unsigned short* ft    = (unsigned short*)(ws);              // 33,554,432 B
    unsigned char*  gbm   = (unsigned char*)(ws + 33554432);    //  4,194,304 B
    float*          gdinv = (float*)(ws + 37748736);            //    524,288 B
    float*          emb   = (float*)(ws + 38273024);            //    262,144 B
    unsigned short* w1t   = (unsigned short*)(ws + 38535168);   //     32,768 B
    unsigned short* w2t   = (unsigned short*)(ws + 38567936);   //     32,768 B
    float*          xg    = (float*)(ws + 38600704);            //  2,097,152 B
    float*          hbuf  = (float*)(ws + 40697856);            //     65,536 B

    k_prep<<<64, 256, 0, stream>>>(W1, W2, w1t, w2t);
    k_gcn_a<<<512, 512, 0, stream>>>(adj, x, w1t, ft, gbm, gdinv);
    k_gcn_b<<<512, 512, 0, stream>>>(ft, gbm, gdinv, b1, w2t);
    k_gcn_c<<<512, 512, 0, stream>>>(ft, gbm, gdinv, b2, emb);
    k_xg<<<64, 256, 0, stream>>>(emb, Wih0, bih0, bhh0, xg);

    void* args[10];
    args[0] = (void*)&xg;
    args[1] = (void*)&Whh0;
    args[2] = (void*)&Wih1;
    args[3] = (void*)&Whh1;
    args[4] = (void*)&bih1;
    args[5] = (void*)&bhh1;
    args[6] = (void*)&Wfc;
    args[7] = (void*)&bfc;
    args[8] = (void*)&hbuf;
    args[9] = (void*)&out;
    hipLaunchCooperativeKernel((const void*)k_lstm, dim3(192), dim3(512), args, 0, stream);
}

// Round 2
// 928.610 us; speedup vs baseline: 1.2904x; 1.2904x over previous
//
#include <hip/hip_runtime.h>
#include <hip/hip_bf16.h>

#define B_ 16
#define T_ 32
#define N_ 256
#define F_ 128
#define H_ 128
#define HL_ 256

typedef float f32x4 __attribute__((ext_vector_type(4)));
typedef short bf16x8 __attribute__((ext_vector_type(8)));

#define MFMA16(A, Bv, C) __builtin_amdgcn_mfma_f32_16x16x32_bf16((A), (Bv), (C), 0, 0, 0)

__device__ __forceinline__ unsigned short f2bf(float f) {
    unsigned u = __builtin_bit_cast(unsigned, f);
    return (unsigned short)((u + 0x7FFFu + ((u >> 16) & 1u)) >> 16);
}

__device__ __forceinline__ bf16x8 cvt8(const float* p) {
    f32x4 a = *(const f32x4*)p;
    f32x4 b = *(const f32x4*)(p + 4);
    bf16x8 r;
    r[0] = (short)f2bf(a[0]); r[1] = (short)f2bf(a[1]);
    r[2] = (short)f2bf(a[2]); r[3] = (short)f2bf(a[3]);
    r[4] = (short)f2bf(b[0]); r[5] = (short)f2bf(b[1]);
    r[6] = (short)f2bf(b[2]); r[7] = (short)f2bf(b[3]);
    return r;
}

__device__ __forceinline__ bf16x8 expand_bits(unsigned b) {
    bf16x8 r;
#pragma unroll
    for (int j = 0; j < 8; ++j) r[j] = (short)(((b >> j) & 1u) ? 0x3F80 : 0);
    return r;
}

__device__ __forceinline__ float sigf(float x) { return 1.f / (1.f + __expf(-x)); }
__device__ __forceinline__ float tanhf_(float x) { float e = __expf(2.f * x); return 1.f - 2.f / (e + 1.f); }

__device__ __forceinline__ float ld_agent(const float* p) {
    return __hip_atomic_load(p, __ATOMIC_RELAXED, __HIP_MEMORY_SCOPE_AGENT);
}
__device__ __forceinline__ void st_agent(float* p, float v) {
    __hip_atomic_store(p, v, __ATOMIC_RELAXED, __HIP_MEMORY_SCOPE_AGENT);
}

// LLC flag barrier: block0 gathers arrivals, broadcasts release. Flags monotonic.
__device__ __forceinline__ void gbar(int* arrive, int* release, int target,
                                     int wg, int tid, int nblk) {
    __syncthreads();   // per-wave vmcnt drain => all block stores visible at LLC
    if (wg == 0) {
        if (tid >= 1 && tid < nblk) {
            while (__hip_atomic_load(arrive + tid, __ATOMIC_RELAXED, __HIP_MEMORY_SCOPE_AGENT) < target)
                __builtin_amdgcn_s_sleep(2);
        }
        __syncthreads();
        if (tid == 0) {
            (void)__hip_atomic_load(arrive + 1, __ATOMIC_ACQUIRE, __HIP_MEMORY_SCOPE_AGENT);
            __hip_atomic_store(release, target, __ATOMIC_RELEASE, __HIP_MEMORY_SCOPE_AGENT);
        }
    } else {
        if (tid == 0) {
            __hip_atomic_store(arrive + wg, target, __ATOMIC_RELEASE, __HIP_MEMORY_SCOPE_AGENT);
            while (__hip_atomic_load(release, __ATOMIC_RELAXED, __HIP_MEMORY_SCOPE_AGENT) < target)
                __builtin_amdgcn_s_sleep(2);
            (void)__hip_atomic_load(release, __ATOMIC_ACQUIRE, __HIP_MEMORY_SCOPE_AGENT);
        }
        __syncthreads();
    }
}

// ---------------- weight prep: W1^T, W2^T in bf16 ----------------
__global__ void k_prep(const float* __restrict__ W1, const float* __restrict__ W2,
                       unsigned short* __restrict__ w1t, unsigned short* __restrict__ w2t) {
    int idx = blockIdx.x * 256 + threadIdx.x;   // 64 blocks * 256 = 16384
    int h = idx >> 7, f = idx & 127;
    w1t[idx] = f2bf(W1[f * 128 + h]);
    w2t[idx] = f2bf(W2[f * 128 + h]);
}

// ---------------- gcn_a: bitmask+dinv from adj, XWT' = dinv .* (x@W1)^T bf16 ----------------
__global__ __launch_bounds__(512, 2) void k_gcn_a(
    const int* __restrict__ adj, const float* __restrict__ x,
    const unsigned short* __restrict__ w1t,
    unsigned short* __restrict__ ft, unsigned char* __restrict__ gbm,
    float* __restrict__ gdinv) {
    __shared__ unsigned char s_bm[256 * 32];
    __shared__ float s_dinv[256];
    __shared__ unsigned short s_w[128 * 136];
    const int bt = blockIdx.x;
    const int tid = threadIdx.x;
    const int* adjb = adj + (size_t)bt * (N_ * N_);

    for (int it = 0; it < 16; ++it) {
        int row = it * 16 + (tid >> 5);
        int c = tid & 31, m0 = c * 8;
        const int* p = adjb + row * N_ + m0;
        int4 q0 = *(const int4*)p;
        int4 q1 = *(const int4*)(p + 4);
        unsigned by = 0;
        by |= (((q0.x != 0) | (m0 + 0 == row)) ? 1u : 0u);
        by |= (((q0.y != 0) | (m0 + 1 == row)) ? 2u : 0u);
        by |= (((q0.z != 0) | (m0 + 2 == row)) ? 4u : 0u);
        by |= (((q0.w != 0) | (m0 + 3 == row)) ? 8u : 0u);
        by |= (((q1.x != 0) | (m0 + 4 == row)) ? 16u : 0u);
        by |= (((q1.y != 0) | (m0 + 5 == row)) ? 32u : 0u);
        by |= (((q1.z != 0) | (m0 + 6 == row)) ? 64u : 0u);
        by |= (((q1.w != 0) | (m0 + 7 == row)) ? 128u : 0u);
        s_bm[row * 32 + c] = (unsigned char)by;
        int pc = __popc(by);
        pc += __shfl_xor(pc, 1); pc += __shfl_xor(pc, 2); pc += __shfl_xor(pc, 4);
        pc += __shfl_xor(pc, 8); pc += __shfl_xor(pc, 16);
        if (c == 0) s_dinv[row] = rsqrtf((float)pc);
    }
    for (int it = 0; it < 4; ++it) {
        int g = it * 512 + tid;
        *(int4*)(&s_w[(g >> 4) * 136 + (g & 15) * 8]) = *(const int4*)(w1t + g * 8);
    }
    __syncthreads();
    *(int4*)(gbm + (size_t)bt * 8192 + tid * 16) = *(const int4*)(s_bm + tid * 16);
    if (tid < 64) *(float4*)(gdinv + bt * 256 + tid * 4) = *(const float4*)(s_dinv + tid * 4);

    const int w = tid >> 6, l = tid & 63, li = l & 15, lg = l >> 4;
    const float* xb = x + (size_t)bt * (N_ * F_);
    f32x4 acc[2][8];
#pragma unroll
    for (int a = 0; a < 2; ++a)
#pragma unroll
        for (int c = 0; c < 8; ++c) acc[a][c] = (f32x4){0.f, 0.f, 0.f, 0.f};

#pragma unroll
    for (int ks = 0; ks < 4; ++ks) {
        bf16x8 a0 = cvt8(xb + (size_t)(32 * w + li) * F_ + lg * 8 + ks * 32);
        bf16x8 a1 = cvt8(xb + (size_t)(32 * w + 16 + li) * F_ + lg * 8 + ks * 32);
#pragma unroll
        for (int ct = 0; ct < 8; ++ct) {
            bf16x8 bv = *(const bf16x8*)(&s_w[(16 * ct + li) * 136 + lg * 8 + ks * 32]);
            acc[0][ct] = MFMA16(a0, bv, acc[0][ct]);
            acc[1][ct] = MFMA16(a1, bv, acc[1][ct]);
        }
    }
#pragma unroll
    for (int rt = 0; rt < 2; ++rt) {
        int m0 = 32 * w + 16 * rt + 4 * lg;
        f32x4 dv = *(const f32x4*)(&s_dinv[m0]);
#pragma unroll
        for (int ct = 0; ct < 8; ++ct) {
            int h = 16 * ct + li;
            f32x4 v = acc[rt][ct];
            unsigned p0 = (unsigned)f2bf(v[0] * dv[0]) | ((unsigned)f2bf(v[1] * dv[1]) << 16);
            unsigned p1 = (unsigned)f2bf(v[2] * dv[2]) | ((unsigned)f2bf(v[3] * dv[3]) << 16);
            uint2 pk; pk.x = p0; pk.y = p1;
            *(uint2*)(ft + ((size_t)bt * H_ + h) * N_ + m0) = pk;
        }
    }
}

// ---------------- gcn_b: h1 = relu(norm@XW + b1); FT <- dinv .* (h1@W2)^T ----------------
__global__ __launch_bounds__(512, 2) void k_gcn_b(
    unsigned short* ft,
    const unsigned char* __restrict__ gbm, const float* __restrict__ gdinv,
    const float* __restrict__ b1, const unsigned short* __restrict__ w2t) {
    __shared__ unsigned short s_ft[256 * 136];   // XWT [128][264] then h1 [256][136]
    __shared__ unsigned short s_w[128 * 136];
    __shared__ unsigned char s_bm[8192];
    __shared__ float s_dinv[256];
    __shared__ float s_b[128];
    const int bt = blockIdx.x, tid = threadIdx.x;
#pragma unroll
    for (int it = 0; it < 8; ++it) {
        int g = it * 512 + tid;
        *(int4*)(&s_ft[(g >> 5) * 264 + (g & 31) * 8]) = *(const int4*)(ft + (size_t)bt * 32768 + g * 8);
    }
#pragma unroll
    for (int it = 0; it < 4; ++it) {
        int g = it * 512 + tid;
        *(int4*)(&s_w[(g >> 4) * 136 + (g & 15) * 8]) = *(const int4*)(w2t + g * 8);
    }
    *(int4*)(s_bm + tid * 16) = *(const int4*)(gbm + (size_t)bt * 8192 + tid * 16);
    if (tid < 64) *(float4*)(&s_dinv[tid * 4]) = *(const float4*)(gdinv + bt * 256 + tid * 4);
    if (tid < 32) *(float4*)(&s_b[tid * 4]) = *(const float4*)(b1 + tid * 4);
    __syncthreads();

    const int w = tid >> 6, l = tid & 63, li = l & 15, lg = l >> 4;
    f32x4 acc[2][8];
#pragma unroll
    for (int a = 0; a < 2; ++a)
#pragma unroll
        for (int c = 0; c < 8; ++c) acc[a][c] = (f32x4){0.f, 0.f, 0.f, 0.f};

#pragma unroll
    for (int ks = 0; ks < 8; ++ks) {
        bf16x8 a0 = expand_bits(s_bm[(32 * w + li) * 32 + 4 * ks + lg]);
        bf16x8 a1 = expand_bits(s_bm[(32 * w + 16 + li) * 32 + 4 * ks + lg]);
#pragma unroll
        for (int ct = 0; ct < 8; ++ct) {
            bf16x8 bv = *(const bf16x8*)(&s_ft[(16 * ct + li) * 264 + lg * 8 + ks * 32]);
            acc[0][ct] = MFMA16(a0, bv, acc[0][ct]);
            acc[1][ct] = MFMA16(a1, bv, acc[1][ct]);
        }
    }
    __syncthreads();   // all XWT reads done; reuse region as h1
#pragma unroll
    for (int rt = 0; rt < 2; ++rt) {
        int i0 = 32 * w + 16 * rt + 4 * lg;
        f32x4 dv = *(const f32x4*)(&s_dinv[i0]);
#pragma unroll
        for (int ct = 0; ct < 8; ++ct) {
            int h = 16 * ct + li;
            float bb = s_b[h];
#pragma unroll
            for (int r = 0; r < 4; ++r)
                s_ft[(i0 + r) * 136 + h] = f2bf(fmaxf(acc[rt][ct][r] * dv[r] + bb, 0.f));
        }
    }
    __syncthreads();
    // gemm2: h1 @ W2  (K=128)
#pragma unroll
    for (int a = 0; a < 2; ++a)
#pragma unroll
        for (int c = 0; c < 8; ++c) acc[a][c] = (f32x4){0.f, 0.f, 0.f, 0.f};
#pragma unroll
    for (int ks = 0; ks < 4; ++ks) {
        bf16x8 a0 = *(const bf16x8*)(&s_ft[(32 * w + li) * 136 + lg * 8 + ks * 32]);
        bf16x8 a1 = *(const bf16x8*)(&s_ft[(32 * w + 16 + li) * 136 + lg * 8 + ks * 32]);
#pragma unroll
        for (int ct = 0; ct < 8; ++ct) {
            bf16x8 bv = *(const bf16x8*)(&s_w[(16 * ct + li) * 136 + lg * 8 + ks * 32]);
            acc[0][ct] = MFMA16(a0, bv, acc[0][ct]);
            acc[1][ct] = MFMA16(a1, bv, acc[1][ct]);
        }
    }
#pragma unroll
    for (int rt = 0; rt < 2; ++rt) {
        int m0 = 32 * w + 16 * rt + 4 * lg;
        f32x4 dv = *(const f32x4*)(&s_dinv[m0]);
#pragma unroll
        for (int ct = 0; ct < 8; ++ct) {
            int h = 16 * ct + li;
            f32x4 v = acc[rt][ct];
            unsigned p0 = (unsigned)f2bf(v[0] * dv[0]) | ((unsigned)f2bf(v[1] * dv[1]) << 16);
            unsigned p1 = (unsigned)f2bf(v[2] * dv[2]) | ((unsigned)f2bf(v[3] * dv[3]) << 16);
            uint2 pk; pk.x = p0; pk.y = p1;
            *(uint2*)(ft + ((size_t)bt * H_ + h) * N_ + m0) = pk;
        }
    }
}

// ---------------- gcn_c: h2 = relu(norm@H1W + b2); emb = mean_n(h2) ----------------
__global__ __launch_bounds__(512, 2) void k_gcn_c(
    const unsigned short* __restrict__ ft, const unsigned char* __restrict__ gbm,
    const float* __restrict__ gdinv, const float* __restrict__ b2,
    float* __restrict__ emb) {
    __shared__ unsigned short s_ft[128 * 264];
    __shared__ unsigned char s_bm[8192];
    __shared__ float s_dinv[256];
    __shared__ float s_b[128];
    __shared__ float s_pool[8 * 128];
    const int bt = blockIdx.x, tid = threadIdx.x;
#pragma unroll
    for (int it = 0; it < 8; ++it) {
        int g = it * 512 + tid;
        *(int4*)(&s_ft[(g >> 5) * 264 + (g & 31) * 8]) = *(const int4*)(ft + (size_t)bt * 32768 + g * 8);
    }
    *(int4*)(s_bm + tid * 16) = *(const int4*)(gbm + (size_t)bt * 8192 + tid * 16);
    if (tid < 64) *(float4*)(&s_dinv[tid * 4]) = *(const float4*)(gdinv + bt * 256 + tid * 4);
    if (tid < 32) *(float4*)(&s_b[tid * 4]) = *(const float4*)(b2 + tid * 4);
    __syncthreads();

    const int w = tid >> 6, l = tid & 63, li = l & 15, lg = l >> 4;
    f32x4 acc[2][8];
#pragma unroll
    for (int a = 0; a < 2; ++a)
#pragma unroll
        for (int c = 0; c < 8; ++c) acc[a][c] = (f32x4){0.f, 0.f, 0.f, 0.f};
#pragma unroll
    for (int ks = 0; ks < 8; ++ks) {
        bf16x8 a0 = expand_bits(s_bm[(32 * w + li) * 32 + 4 * ks + lg]);
        bf16x8 a1 = expand_bits(s_bm[(32 * w + 16 + li) * 32 + 4 * ks + lg]);
#pragma unroll
        for (int ct = 0; ct < 8; ++ct) {
            bf16x8 bv = *(const bf16x8*)(&s_ft[(16 * ct + li) * 264 + lg * 8 + ks * 32]);
            acc[0][ct] = MFMA16(a0, bv, acc[0][ct]);
            acc[1][ct] = MFMA16(a1, bv, acc[1][ct]);
        }
    }
    int i0a = 32 * w + 4 * lg;
    f32x4 dv0 = *(const f32x4*)(&s_dinv[i0a]);
    f32x4 dv1 = *(const f32x4*)(&s_dinv[i0a + 16]);
#pragma unroll
    for (int ct = 0; ct < 8; ++ct) {
        int h = 16 * ct + li;
        float bb = s_b[h];
        float s = 0.f;
#pragma unroll
        for (int r = 0; r < 4; ++r) {
            s += fmaxf(acc[0][ct][r] * dv0[r] + bb, 0.f);
            s += fmaxf(acc[1][ct][r] * dv1[r] + bb, 0.f);
        }
        s += __shfl_xor(s, 16);
        s += __shfl_xor(s, 32);
        if (lg == 0) s_pool[w * 128 + h] = s;
    }
    __syncthreads();
    if (tid < 128) {
        float e = 0.f;
#pragma unroll
        for (int ww = 0; ww < 8; ++ww) e += s_pool[ww * 128 + tid];
        emb[(size_t)bt * 128 + tid] = e * (1.f / 256.f);
    }
}

// ---------------- xg = emb @ Wih0^T + bih0 + bhh0   (layout [t][b][1024]) ----------------
__global__ __launch_bounds__(256, 2) void k_xg(
    const float* __restrict__ emb, const float* __restrict__ Wih0,
    const float* __restrict__ bih0, const float* __restrict__ bhh0,
    float* __restrict__ xg) {
    __shared__ float s_e[8][128];
    const int bk = blockIdx.x, tid = threadIdx.x;
    for (int q = 0; q < 4; ++q) {
        int idx = q * 256 + tid;
        int p = idx >> 7, k = idx & 127;
        int tb2 = bk * 8 + p;
        int t = tb2 >> 4, b = tb2 & 15;
        s_e[p][k] = emb[(size_t)(b * T_ + t) * 128 + k];
    }
    __syncthreads();
    for (int cc = 0; cc < 4; ++cc) {
        int col = cc * 256 + tid;
        float bias = bih0[col] + bhh0[col];
        const float4* wr = (const float4*)(Wih0 + (size_t)col * 128);
        float accv[8] = {0, 0, 0, 0, 0, 0, 0, 0};
        for (int k4 = 0; k4 < 32; ++k4) {
            float4 wv = wr[k4];
#pragma unroll
            for (int p = 0; p < 8; ++p) {
                float4 ev = *(const float4*)(&s_e[p][k4 * 4]);
                accv[p] += wv.x * ev.x + wv.y * ev.y + wv.z * ev.z + wv.w * ev.w;
            }
        }
#pragma unroll
        for (int p = 0; p < 8; ++p) {
            int tb2 = bk * 8 + p;
            xg[(size_t)tb2 * 1024 + col] = accv[p] + bias;
        }
    }
}

// ---------------- 2-layer LSTM + FC, custom LLC barrier ----------------
// hbuf: h0[2][16][256] @ 0 floats, h1[2][16][256] @ 8192 floats (agent-scope only)
// 128 blocks: wg<64 layer0 (4 j-cols), wg>=64 layer1 (4 j-cols)
__global__ __launch_bounds__(512, 1) void k_lstm(
    const float* __restrict__ xg, const float* __restrict__ Whh0,
    const float* __restrict__ Wih1, const float* __restrict__ Whh1,
    const float* __restrict__ bih1, const float* __restrict__ bhh1,
    const float* __restrict__ Wfc, const float* __restrict__ bfc,
    float* hbuf, int* flags, float* __restrict__ out) {
    const int wg = blockIdx.x, tid = threadIdx.x;
    __shared__ float s_h0[16][2][132];
    __shared__ float s_h1[16][2][132];
    __shared__ float s_g[16][4][4];

    int* arrive = flags;          // [128]
    int* release = flags + 192;

    const int b = tid >> 5, rem = tid & 31;
    const int jl = rem & 3, g = (rem >> 2) & 3, kq = rem >> 4;   // kq in {0,1}

    const int L1 = (wg >= 64);
    const int j0 = (L1 ? (wg - 64) : wg) * 4;
    const int r = g * 256 + j0 + jl;

    const float* wrow0 = Whh0 + (size_t)r * 256 + kq * 128;           // layer0
    const float* wrow1 = (kq == 0 ? Wih1 : Whh1) + (size_t)r * 256;   // layer1
    float bias1 = 0.f;
    if (L1) bias1 = bih1[r] + bhh1[r];

    float c_reg = 0.f;

    for (int p = 0; p < 33; ++p) {
        if (!L1) {
            if (p < 32) {   // layer0 step t=p
                float s = 0.f;
                if (p > 0) {
                    const float* src = hbuf + ((p + 1) & 1) * 4096;
#pragma unroll
                    for (int q = 0; q < 8; ++q) {
                        int idx = q * 512 + tid;
                        int bb = idx >> 8, cc = idx & 255;
                        s_h0[bb][cc >> 7][cc & 127] = ld_agent(src + idx);
                    }
                    __syncthreads();
                    const float* hp = &s_h0[b][kq][0];
                    for (int k = 0; k < 128; k += 4) {
                        f32x4 w4 = *(const f32x4*)(wrow0 + k);
                        f32x4 h4 = *(const f32x4*)(hp + k);
                        s += w4[0] * h4[0] + w4[1] * h4[1] + w4[2] * h4[2] + w4[3] * h4[3];
                    }
                }
                s += __shfl_xor(s, 16);   // combine kq halves
                if (kq == 0) {
                    float gate = xg[(size_t)(p * 16 + b) * 1024 + r] + s;
                    s_g[b][jl][g] = gate;
                }
                __syncthreads();
                if (tid < 64) {
                    int b3 = tid >> 2, j3 = tid & 3;
                    float gi = s_g[b3][j3][0], gf = s_g[b3][j3][1];
                    float gg = s_g[b3][j3][2], go = s_g[b3][j3][3];
                    c_reg = sigf(gf) * c_reg + sigf(gi) * tanhf_(gg);
                    float h = sigf(go) * tanhf_(c_reg);
                    st_agent(hbuf + (p & 1) * 4096 + b3 * 256 + j0 + j3, h);
                }
            }
        } else {
            if (p >= 1) {   // layer1 step t=p-1
                const int t = p - 1;
                const float* src0 = hbuf + (t & 1) * 4096;
#pragma unroll
                for (int q = 0; q < 8; ++q) {
                    int idx = q * 512 + tid;
                    int bb = idx >> 8, cc = idx & 255;
                    s_h0[bb][cc >> 7][cc & 127] = ld_agent(src0 + idx);
                }
                if (t > 0) {
                    const float* src1 = hbuf + 8192 + ((t + 1) & 1) * 4096;
#pragma unroll
                    for (int q = 0; q < 8; ++q) {
                        int idx = q * 512 + tid;
                        int bb = idx >> 8, cc = idx & 255;
                        s_h1[bb][cc >> 7][cc & 127] = ld_agent(src1 + idx);
                    }
                }
                __syncthreads();
                float s = 0.f;
                if (kq == 0) {   // Wih1 . h0[t]
                    const float* hp0 = &s_h0[b][0][0];
                    const float* hp1 = &s_h0[b][1][0];
                    for (int k = 0; k < 128; k += 4) {
                        f32x4 w4 = *(const f32x4*)(wrow1 + k);
                        f32x4 h4 = *(const f32x4*)(hp0 + k);
                        s += w4[0] * h4[0] + w4[1] * h4[1] + w4[2] * h4[2] + w4[3] * h4[3];
                    }
                    for (int k = 0; k < 128; k += 4) {
                        f32x4 w4 = *(const f32x4*)(wrow1 + 128 + k);
                        f32x4 h4 = *(const f32x4*)(hp1 + k);
                        s += w4[0] * h4[0] + w4[1] * h4[1] + w4[2] * h4[2] + w4[3] * h4[3];
                    }
                } else if (t > 0) {   // Whh1 . h1[t-1]
                    const float* hp0 = &s_h1[b][0][0];
                    const float* hp1 = &s_h1[b][1][0];
                    for (int k = 0; k < 128; k += 4) {
                        f32x4 w4 = *(const f32x4*)(wrow1 + k);
                        f32x4 h4 = *(const f32x4*)(hp0 + k);
                        s += w4[0] * h4[0] + w4[1] * h4[1] + w4[2] * h4[2] + w4[3] * h4[3];
                    }
                    for (int k = 0; k < 128; k += 4) {
                        f32x4 w4 = *(const f32x4*)(wrow1 + 128 + k);
                        f32x4 h4 = *(const f32x4*)(hp1 + k);
                        s += w4[0] * h4[0] + w4[1] * h4[1] + w4[2] * h4[2] + w4[3] * h4[3];
                    }
                }
                s += __shfl_xor(s, 16);   // Wih1 part + Whh1 part
                if (kq == 0) {
                    s_g[b][jl][g] = bias1 + s;
                }
                __syncthreads();
                if (tid < 64) {
                    int b3 = tid >> 2, j3 = tid & 3;
                    float gi = s_g[b3][j3][0], gf = s_g[b3][j3][1];
                    float gg = s_g[b3][j3][2], go = s_g[b3][j3][3];
                    c_reg = sigf(gf) * c_reg + sigf(gi) * tanhf_(gg);
                    float h = sigf(go) * tanhf_(c_reg);
                    st_agent(hbuf + 8192 + (t & 1) * 4096 + b3 * 256 + j0 + j3, h);
                }
            }
        }
        gbar(arrive, release, p + 1, wg, tid, 128);
    }

    if (wg == 0) {   // FC + sigmoid; final h1 at parity (31&1)=1
        const float* hf = hbuf + 8192 + 4096;
        float* s_fc = &s_g[0][0][0];
        if (tid < 256) {
            int bb = tid >> 4, ks = tid & 15;
            float s = 0.f;
#pragma unroll
            for (int k = 0; k < 16; ++k)
                s += Wfc[ks * 16 + k] * ld_agent(hf + bb * 256 + ks * 16 + k);
            s_fc[tid] = s;
        }
        __syncthreads();
        if (tid < 16) {
            float s = bfc[0];
#pragma unroll
            for (int q = 0; q < 16; ++q) s += s_fc[tid * 16 + q];
            out[tid] = sigf(s);
        }
    }
}

extern "C" void kernel_launch(void* const* d_in, const int* in_sizes, int n_in,
                              void* d_out, int out_size, void* d_ws, size_t ws_size,
                              hipStream_t stream) {
    const int*   adj  = (const int*)  d_in[0];
    const float* x    = (const float*)d_in[1];
    const float* W1   = (const float*)d_in[2];
    const float* b1   = (const float*)d_in[3];
    const float* W2   = (const float*)d_in[4];
    const float* b2   = (const float*)d_in[5];
    const float* Wih0 = (const float*)d_in[6];
    const float* Whh0 = (const float*)d_in[7];
    const float* bih0 = (const float*)d_in[8];
    const float* bhh0 = (const float*)d_in[9];
    const float* Wih1 = (const float*)d_in[10];
    const float* Whh1 = (const float*)d_in[11];
    const float* bih1 = (const float*)d_in[12];
    const float* bhh1 = (const float*)d_in[13];
    const float* Wfc  = (const float*)d_in[14];
    const float* bfc  = (const float*)d_in[15];
    float* out = (float*)d_out;

    if (ws_size < 40764416) return;   // ~40.8 MB scratch

    char* ws = (char*)d_ws;
    unsigned short* ft    = (unsigned short*)(ws);              // 33,554,432 B
    unsigned char*  gbm   = (unsigned char*)(ws + 33554432);    //  4,194,304 B
    float*          gdinv = (float*)(ws + 37748736);            //    524,288 B
    float*          emb   = (float*)(ws + 38273024);            //    262,144 B
    unsigned short* w1t   = (unsigned short*)(ws + 38535168);   //     32,768 B
    unsigned short* w2t   = (unsigned short*)(ws + 38567936);   //     32,768 B
    float*          xg    = (float*)(ws + 38600704);            //  2,097,152 B
    float*          hbuf  = (float*)(ws + 40697856);            //     65,536 B
    int*            flags = (int*)(ws + 40763392);              //      1,024 B

    hipMemsetAsync(flags, 0, 1024, stream);

    k_prep<<<64, 256, 0, stream>>>(W1, W2, w1t, w2t);
    k_gcn_a<<<512, 512, 0, stream>>>(adj, x, w1t, ft, gbm, gdinv);
    k_gcn_b<<<512, 512, 0, stream>>>(ft, gbm, gdinv, b1, w2t);
    k_gcn_c<<<512, 512, 0, stream>>>(ft, gbm, gdinv, b2, emb);
    k_xg<<<64, 256, 0, stream>>>(emb, Wih0, bih0, bhh0, xg);

    void* args[11];
    args[0] = (void*)&xg;
    args[1] = (void*)&Whh0;
    args[2] = (void*)&Wih1;
    args[3] = (void*)&Whh1;
    args[4] = (void*)&bih1;
    args[5] = (void*)&bhh1;
    args[6] = (void*)&Wfc;
    args[7] = (void*)&bfc;
    args[8] = (void*)&hbuf;
    args[9] = (void*)&flags;
    args[10] = (void*)&out;
    hipLaunchCooperativeKernel((const void*)k_lstm, dim3(128), dim3(512), args, 0, stream);
}

// Round 3
// 878.664 us; speedup vs baseline: 1.3638x; 1.0568x over previous
//
#include <hip/hip_runtime.h>
#include <hip/hip_bf16.h>

#define B_ 16
#define T_ 32
#define N_ 256
#define F_ 128
#define H_ 128
#define HL_ 256

typedef float f32x4 __attribute__((ext_vector_type(4)));
typedef short bf16x8 __attribute__((ext_vector_type(8)));

#define MFMA16(A, Bv, C) __builtin_amdgcn_mfma_f32_16x16x32_bf16((A), (Bv), (C), 0, 0, 0)

__device__ __forceinline__ unsigned short f2bf(float f) {
    unsigned u = __builtin_bit_cast(unsigned, f);
    return (unsigned short)((u + 0x7FFFu + ((u >> 16) & 1u)) >> 16);
}

__device__ __forceinline__ bf16x8 cvt8(const float* p) {
    f32x4 a = *(const f32x4*)p;
    f32x4 b = *(const f32x4*)(p + 4);
    bf16x8 r;
    r[0] = (short)f2bf(a[0]); r[1] = (short)f2bf(a[1]);
    r[2] = (short)f2bf(a[2]); r[3] = (short)f2bf(a[3]);
    r[4] = (short)f2bf(b[0]); r[5] = (short)f2bf(b[1]);
    r[6] = (short)f2bf(b[2]); r[7] = (short)f2bf(b[3]);
    return r;
}

__device__ __forceinline__ bf16x8 expand_bits(unsigned b) {
    bf16x8 r;
#pragma unroll
    for (int j = 0; j < 8; ++j) r[j] = (short)(((b >> j) & 1u) ? 0x3F80 : 0);
    return r;
}

__device__ __forceinline__ float sigf(float x) { return 1.f / (1.f + __expf(-x)); }
__device__ __forceinline__ float tanhf_(float x) { float e = __expf(2.f * x); return 1.f - 2.f / (e + 1.f); }

__device__ __forceinline__ float ld_agent(const float* p) {
    return __hip_atomic_load(p, __ATOMIC_RELAXED, __HIP_MEMORY_SCOPE_AGENT);
}
__device__ __forceinline__ void st_agent(float* p, float v) {
    __hip_atomic_store(p, v, __ATOMIC_RELAXED, __HIP_MEMORY_SCOPE_AGENT);
}

// LLC flag barrier, RELAXED-only protocol (all cross-block data uses sc1
// cache-bypass atomics, so no buffer_inv/wbl2 cache maintenance is needed).
// Ordering: per-wave s_waitcnt vmcnt(0) drains h-stores to the coherence
// point BEFORE any flag store is issued (same primitive the compiler's
// release lowering uses); readers' sc1 loads cannot hit stale cache.
__device__ __forceinline__ void gbar(int* arrive, int* release, int target,
                                     int wg, int tid, int nblk) {
    asm volatile("s_waitcnt vmcnt(0)" ::: "memory");
    __syncthreads();
    if (wg == 0) {
        if (tid >= 1 && tid < nblk) {
            while (__hip_atomic_load(arrive + tid, __ATOMIC_RELAXED, __HIP_MEMORY_SCOPE_AGENT) < target)
                __builtin_amdgcn_s_sleep(1);
        }
        __syncthreads();
        if (tid == 0)
            __hip_atomic_store(release, target, __ATOMIC_RELAXED, __HIP_MEMORY_SCOPE_AGENT);
    } else {
        if (tid == 0) {
            __hip_atomic_store(arrive + wg, target, __ATOMIC_RELAXED, __HIP_MEMORY_SCOPE_AGENT);
            while (__hip_atomic_load(release, __ATOMIC_RELAXED, __HIP_MEMORY_SCOPE_AGENT) < target)
                __builtin_amdgcn_s_sleep(1);
        }
        __syncthreads();
    }
}

// ---------------- weight prep: W1^T, W2^T in bf16 ----------------
__global__ void k_prep(const float* __restrict__ W1, const float* __restrict__ W2,
                       unsigned short* __restrict__ w1t, unsigned short* __restrict__ w2t) {
    int idx = blockIdx.x * 256 + threadIdx.x;   // 64 blocks * 256 = 16384
    int h = idx >> 7, f = idx & 127;
    w1t[idx] = f2bf(W1[f * 128 + h]);
    w2t[idx] = f2bf(W2[f * 128 + h]);
}

// ---------------- gcn_a: bitmask+dinv from adj, XWT' = dinv .* (x@W1)^T bf16 ----------------
__global__ __launch_bounds__(512, 2) void k_gcn_a(
    const int* __restrict__ adj, const float* __restrict__ x,
    const unsigned short* __restrict__ w1t,
    unsigned short* __restrict__ ft, unsigned char* __restrict__ gbm,
    float* __restrict__ gdinv) {
    __shared__ unsigned char s_bm[256 * 32];
    __shared__ float s_dinv[256];
    __shared__ unsigned short s_w[128 * 136];
    const int bt = blockIdx.x;
    const int tid = threadIdx.x;
    const int* adjb = adj + (size_t)bt * (N_ * N_);

    for (int it = 0; it < 16; ++it) {
        int row = it * 16 + (tid >> 5);
        int c = tid & 31, m0 = c * 8;
        const int* p = adjb + row * N_ + m0;
        int4 q0 = *(const int4*)p;
        int4 q1 = *(const int4*)(p + 4);
        unsigned by = 0;
        by |= (((q0.x != 0) | (m0 + 0 == row)) ? 1u : 0u);
        by |= (((q0.y != 0) | (m0 + 1 == row)) ? 2u : 0u);
        by |= (((q0.z != 0) | (m0 + 2 == row)) ? 4u : 0u);
        by |= (((q0.w != 0) | (m0 + 3 == row)) ? 8u : 0u);
        by |= (((q1.x != 0) | (m0 + 4 == row)) ? 16u : 0u);
        by |= (((q1.y != 0) | (m0 + 5 == row)) ? 32u : 0u);
        by |= (((q1.z != 0) | (m0 + 6 == row)) ? 64u : 0u);
        by |= (((q1.w != 0) | (m0 + 7 == row)) ? 128u : 0u);
        s_bm[row * 32 + c] = (unsigned char)by;
        int pc = __popc(by);
        pc += __shfl_xor(pc, 1); pc += __shfl_xor(pc, 2); pc += __shfl_xor(pc, 4);
        pc += __shfl_xor(pc, 8); pc += __shfl_xor(pc, 16);
        if (c == 0) s_dinv[row] = rsqrtf((float)pc);
    }
    for (int it = 0; it < 4; ++it) {
        int g = it * 512 + tid;
        *(int4*)(&s_w[(g >> 4) * 136 + (g & 15) * 8]) = *(const int4*)(w1t + g * 8);
    }
    __syncthreads();
    *(int4*)(gbm + (size_t)bt * 8192 + tid * 16) = *(const int4*)(s_bm + tid * 16);
    if (tid < 64) *(float4*)(gdinv + bt * 256 + tid * 4) = *(const float4*)(s_dinv + tid * 4);

    const int w = tid >> 6, l = tid & 63, li = l & 15, lg = l >> 4;
    const float* xb = x + (size_t)bt * (N_ * F_);
    f32x4 acc[2][8];
#pragma unroll
    for (int a = 0; a < 2; ++a)
#pragma unroll
        for (int c = 0; c < 8; ++c) acc[a][c] = (f32x4){0.f, 0.f, 0.f, 0.f};

#pragma unroll
    for (int ks = 0; ks < 4; ++ks) {
        bf16x8 a0 = cvt8(xb + (size_t)(32 * w + li) * F_ + lg * 8 + ks * 32);
        bf16x8 a1 = cvt8(xb + (size_t)(32 * w + 16 + li) * F_ + lg * 8 + ks * 32);
#pragma unroll
        for (int ct = 0; ct < 8; ++ct) {
            bf16x8 bv = *(const bf16x8*)(&s_w[(16 * ct + li) * 136 + lg * 8 + ks * 32]);
            acc[0][ct] = MFMA16(a0, bv, acc[0][ct]);
            acc[1][ct] = MFMA16(a1, bv, acc[1][ct]);
        }
    }
#pragma unroll
    for (int rt = 0; rt < 2; ++rt) {
        int m0 = 32 * w + 16 * rt + 4 * lg;
        f32x4 dv = *(const f32x4*)(&s_dinv[m0]);
#pragma unroll
        for (int ct = 0; ct < 8; ++ct) {
            int h = 16 * ct + li;
            f32x4 v = acc[rt][ct];
            unsigned p0 = (unsigned)f2bf(v[0] * dv[0]) | ((unsigned)f2bf(v[1] * dv[1]) << 16);
            unsigned p1 = (unsigned)f2bf(v[2] * dv[2]) | ((unsigned)f2bf(v[3] * dv[3]) << 16);
            uint2 pk; pk.x = p0; pk.y = p1;
            *(uint2*)(ft + ((size_t)bt * H_ + h) * N_ + m0) = pk;
        }
    }
}

// ---------------- gcn_b: h1 = relu(norm@XW + b1); FT <- dinv .* (h1@W2)^T ----------------
__global__ __launch_bounds__(512, 2) void k_gcn_b(
    unsigned short* ft,
    const unsigned char* __restrict__ gbm, const float* __restrict__ gdinv,
    const float* __restrict__ b1, const unsigned short* __restrict__ w2t) {
    __shared__ unsigned short s_ft[256 * 136];   // XWT [128][264] then h1 [256][136]
    __shared__ unsigned short s_w[128 * 136];
    __shared__ unsigned char s_bm[8192];
    __shared__ float s_dinv[256];
    __shared__ float s_b[128];
    const int bt = blockIdx.x, tid = threadIdx.x;
#pragma unroll
    for (int it = 0; it < 8; ++it) {
        int g = it * 512 + tid;
        *(int4*)(&s_ft[(g >> 5) * 264 + (g & 31) * 8]) = *(const int4*)(ft + (size_t)bt * 32768 + g * 8);
    }
#pragma unroll
    for (int it = 0; it < 4; ++it) {
        int g = it * 512 + tid;
        *(int4*)(&s_w[(g >> 4) * 136 + (g & 15) * 8]) = *(const int4*)(w2t + g * 8);
    }
    *(int4*)(s_bm + tid * 16) = *(const int4*)(gbm + (size_t)bt * 8192 + tid * 16);
    if (tid < 64) *(float4*)(&s_dinv[tid * 4]) = *(const float4*)(gdinv + bt * 256 + tid * 4);
    if (tid < 32) *(float4*)(&s_b[tid * 4]) = *(const float4*)(b1 + tid * 4);
    __syncthreads();

    const int w = tid >> 6, l = tid & 63, li = l & 15, lg = l >> 4;
    f32x4 acc[2][8];
#pragma unroll
    for (int a = 0; a < 2; ++a)
#pragma unroll
        for (int c = 0; c < 8; ++c) acc[a][c] = (f32x4){0.f, 0.f, 0.f, 0.f};

#pragma unroll
    for (int ks = 0; ks < 8; ++ks) {
        bf16x8 a0 = expand_bits(s_bm[(32 * w + li) * 32 + 4 * ks + lg]);
        bf16x8 a1 = expand_bits(s_bm[(32 * w + 16 + li) * 32 + 4 * ks + lg]);
#pragma unroll
        for (int ct = 0; ct < 8; ++ct) {
            bf16x8 bv = *(const bf16x8*)(&s_ft[(16 * ct + li) * 264 + lg * 8 + ks * 32]);
            acc[0][ct] = MFMA16(a0, bv, acc[0][ct]);
            acc[1][ct] = MFMA16(a1, bv, acc[1][ct]);
        }
    }
    __syncthreads();   // all XWT reads done; reuse region as h1
#pragma unroll
    for (int rt = 0; rt < 2; ++rt) {
        int i0 = 32 * w + 16 * rt + 4 * lg;
        f32x4 dv = *(const f32x4*)(&s_dinv[i0]);
#pragma unroll
        for (int ct = 0; ct < 8; ++ct) {
            int h = 16 * ct + li;
            float bb = s_b[h];
#pragma unroll
            for (int r = 0; r < 4; ++r)
                s_ft[(i0 + r) * 136 + h] = f2bf(fmaxf(acc[rt][ct][r] * dv[r] + bb, 0.f));
        }
    }
    __syncthreads();
    // gemm2: h1 @ W2  (K=128)
#pragma unroll
    for (int a = 0; a < 2; ++a)
#pragma unroll
        for (int c = 0; c < 8; ++c) acc[a][c] = (f32x4){0.f, 0.f, 0.f, 0.f};
#pragma unroll
    for (int ks = 0; ks < 4; ++ks) {
        bf16x8 a0 = *(const bf16x8*)(&s_ft[(32 * w + li) * 136 + lg * 8 + ks * 32]);
        bf16x8 a1 = *(const bf16x8*)(&s_ft[(32 * w + 16 + li) * 136 + lg * 8 + ks * 32]);
#pragma unroll
        for (int ct = 0; ct < 8; ++ct) {
            bf16x8 bv = *(const bf16x8*)(&s_w[(16 * ct + li) * 136 + lg * 8 + ks * 32]);
            acc[0][ct] = MFMA16(a0, bv, acc[0][ct]);
            acc[1][ct] = MFMA16(a1, bv, acc[1][ct]);
        }
    }
#pragma unroll
    for (int rt = 0; rt < 2; ++rt) {
        int m0 = 32 * w + 16 * rt + 4 * lg;
        f32x4 dv = *(const f32x4*)(&s_dinv[m0]);
#pragma unroll
        for (int ct = 0; ct < 8; ++ct) {
            int h = 16 * ct + li;
            f32x4 v = acc[rt][ct];
            unsigned p0 = (unsigned)f2bf(v[0] * dv[0]) | ((unsigned)f2bf(v[1] * dv[1]) << 16);
            unsigned p1 = (unsigned)f2bf(v[2] * dv[2]) | ((unsigned)f2bf(v[3] * dv[3]) << 16);
            uint2 pk; pk.x = p0; pk.y = p1;
            *(uint2*)(ft + ((size_t)bt * H_ + h) * N_ + m0) = pk;
        }
    }
}

// ---------------- gcn_c: h2 = relu(norm@H1W + b2); emb = mean_n(h2) ----------------
__global__ __launch_bounds__(512, 2) void k_gcn_c(
    const unsigned short* __restrict__ ft, const unsigned char* __restrict__ gbm,
    const float* __restrict__ gdinv, const float* __restrict__ b2,
    float* __restrict__ emb) {
    __shared__ unsigned short s_ft[128 * 264];
    __shared__ unsigned char s_bm[8192];
    __shared__ float s_dinv[256];
    __shared__ float s_b[128];
    __shared__ float s_pool[8 * 128];
    const int bt = blockIdx.x, tid = threadIdx.x;
#pragma unroll
    for (int it = 0; it < 8; ++it) {
        int g = it * 512 + tid;
        *(int4*)(&s_ft[(g >> 5) * 264 + (g & 31) * 8]) = *(const int4*)(ft + (size_t)bt * 32768 + g * 8);
    }
    *(int4*)(s_bm + tid * 16) = *(const int4*)(gbm + (size_t)bt * 8192 + tid * 16);
    if (tid < 64) *(float4*)(&s_dinv[tid * 4]) = *(const float4*)(gdinv + bt * 256 + tid * 4);
    if (tid < 32) *(float4*)(&s_b[tid * 4]) = *(const float4*)(b2 + tid * 4);
    __syncthreads();

    const int w = tid >> 6, l = tid & 63, li = l & 15, lg = l >> 4;
    f32x4 acc[2][8];
#pragma unroll
    for (int a = 0; a < 2; ++a)
#pragma unroll
        for (int c = 0; c < 8; ++c) acc[a][c] = (f32x4){0.f, 0.f, 0.f, 0.f};
#pragma unroll
    for (int ks = 0; ks < 8; ++ks) {
        bf16x8 a0 = expand_bits(s_bm[(32 * w + li) * 32 + 4 * ks + lg]);
        bf16x8 a1 = expand_bits(s_bm[(32 * w + 16 + li) * 32 + 4 * ks + lg]);
#pragma unroll
        for (int ct = 0; ct < 8; ++ct) {
            bf16x8 bv = *(const bf16x8*)(&s_ft[(16 * ct + li) * 264 + lg * 8 + ks * 32]);
            acc[0][ct] = MFMA16(a0, bv, acc[0][ct]);
            acc[1][ct] = MFMA16(a1, bv, acc[1][ct]);
        }
    }
    int i0a = 32 * w + 4 * lg;
    f32x4 dv0 = *(const f32x4*)(&s_dinv[i0a]);
    f32x4 dv1 = *(const f32x4*)(&s_dinv[i0a + 16]);
#pragma unroll
    for (int ct = 0; ct < 8; ++ct) {
        int h = 16 * ct + li;
        float bb = s_b[h];
        float s = 0.f;
#pragma unroll
        for (int r = 0; r < 4; ++r) {
            s += fmaxf(acc[0][ct][r] * dv0[r] + bb, 0.f);
            s += fmaxf(acc[1][ct][r] * dv1[r] + bb, 0.f);
        }
        s += __shfl_xor(s, 16);
        s += __shfl_xor(s, 32);
        if (lg == 0) s_pool[w * 128 + h] = s;
    }
    __syncthreads();
    if (tid < 128) {
        float e = 0.f;
#pragma unroll
        for (int ww = 0; ww < 8; ++ww) e += s_pool[ww * 128 + tid];
        emb[(size_t)bt * 128 + tid] = e * (1.f / 256.f);
    }
}

// ---------------- xg = emb @ Wih0^T + bih0 + bhh0   (layout [t][b][1024]) ----------------
__global__ __launch_bounds__(256, 2) void k_xg(
    const float* __restrict__ emb, const float* __restrict__ Wih0,
    const float* __restrict__ bih0, const float* __restrict__ bhh0,
    float* __restrict__ xg) {
    __shared__ float s_e[8][128];
    const int bk = blockIdx.x, tid = threadIdx.x;
    for (int q = 0; q < 4; ++q) {
        int idx = q * 256 + tid;
        int p = idx >> 7, k = idx & 127;
        int tb2 = bk * 8 + p;
        int t = tb2 >> 4, b = tb2 & 15;
        s_e[p][k] = emb[(size_t)(b * T_ + t) * 128 + k];
    }
    __syncthreads();
    for (int cc = 0; cc < 4; ++cc) {
        int col = cc * 256 + tid;
        float bias = bih0[col] + bhh0[col];
        const float4* wr = (const float4*)(Wih0 + (size_t)col * 128);
        float accv[8] = {0, 0, 0, 0, 0, 0, 0, 0};
        for (int k4 = 0; k4 < 32; ++k4) {
            float4 wv = wr[k4];
#pragma unroll
            for (int p = 0; p < 8; ++p) {
                float4 ev = *(const float4*)(&s_e[p][k4 * 4]);
                accv[p] += wv.x * ev.x + wv.y * ev.y + wv.z * ev.z + wv.w * ev.w;
            }
        }
#pragma unroll
        for (int p = 0; p < 8; ++p) {
            int tb2 = bk * 8 + p;
            xg[(size_t)tb2 * 1024 + col] = accv[p] + bias;
        }
    }
}

// ---------------- 2-layer LSTM + FC, relaxed-only LLC barrier ----------------
// hbuf: h0[2][16][256] @ 0 floats, h1[2][16][256] @ 8192 floats (sc1 atomics only)
// 128 blocks: wg<64 layer0 (4 j-cols), wg>=64 layer1 (4 j-cols)
__global__ __launch_bounds__(512, 1) void k_lstm(
    const float* __restrict__ xg, const float* __restrict__ Whh0,
    const float* __restrict__ Wih1, const float* __restrict__ Whh1,
    const float* __restrict__ bih1, const float* __restrict__ bhh1,
    const float* __restrict__ Wfc, const float* __restrict__ bfc,
    float* hbuf, int* flags, float* __restrict__ out) {
    const int wg = blockIdx.x, tid = threadIdx.x;
    __shared__ float s_h0[16][2][132];
    __shared__ float s_h1[16][2][132];
    __shared__ float s_g[16][4][4];

    int* arrive = flags;          // [128]
    int* release = flags + 192;

    const int b = tid >> 5, rem = tid & 31;
    const int jl = rem & 3, g = (rem >> 2) & 3, kq = rem >> 4;   // kq in {0,1}

    const int L1 = (wg >= 64);
    const int j0 = (L1 ? (wg - 64) : wg) * 4;
    const int r = g * 256 + j0 + jl;

    const float* wrow0 = Whh0 + (size_t)r * 256 + kq * 128;           // layer0
    const float* wrow1 = (kq == 0 ? Wih1 : Whh1) + (size_t)r * 256;   // layer1
    float bias1 = 0.f;
    if (L1) bias1 = bih1[r] + bhh1[r];

    float c_reg = 0.f;

    for (int p = 0; p < 33; ++p) {
        if (!L1) {
            if (p < 32) {   // layer0 step t=p
                float s = 0.f;
                if (p > 0) {
                    const float* src = hbuf + ((p + 1) & 1) * 4096;
#pragma unroll
                    for (int q = 0; q < 8; ++q) {
                        int idx = q * 512 + tid;
                        int bb = idx >> 8, cc = idx & 255;
                        s_h0[bb][cc >> 7][cc & 127] = ld_agent(src + idx);
                    }
                    __syncthreads();
                    const float* hp = &s_h0[b][kq][0];
                    for (int k = 0; k < 128; k += 4) {
                        f32x4 w4 = *(const f32x4*)(wrow0 + k);
                        f32x4 h4 = *(const f32x4*)(hp + k);
                        s += w4[0] * h4[0] + w4[1] * h4[1] + w4[2] * h4[2] + w4[3] * h4[3];
                    }
                }
                s += __shfl_xor(s, 16);   // combine kq halves
                if (kq == 0) {
                    float gate = xg[(size_t)(p * 16 + b) * 1024 + r] + s;
                    s_g[b][jl][g] = gate;
                }
                __syncthreads();
                if (tid < 64) {
                    int b3 = tid >> 2, j3 = tid & 3;
                    float gi = s_g[b3][j3][0], gf = s_g[b3][j3][1];
                    float gg = s_g[b3][j3][2], go = s_g[b3][j3][3];
                    c_reg = sigf(gf) * c_reg + sigf(gi) * tanhf_(gg);
                    float h = sigf(go) * tanhf_(c_reg);
                    st_agent(hbuf + (p & 1) * 4096 + b3 * 256 + j0 + j3, h);
                }
            }
        } else {
            if (p >= 1) {   // layer1 step t=p-1
                const int t = p - 1;
                const float* src0 = hbuf + (t & 1) * 4096;
#pragma unroll
                for (int q = 0; q < 8; ++q) {
                    int idx = q * 512 + tid;
                    int bb = idx >> 8, cc = idx & 255;
                    s_h0[bb][cc >> 7][cc & 127] = ld_agent(src0 + idx);
                }
                if (t > 0) {
                    const float* src1 = hbuf + 8192 + ((t + 1) & 1) * 4096;
#pragma unroll
                    for (int q = 0; q < 8; ++q) {
                        int idx = q * 512 + tid;
                        int bb = idx >> 8, cc = idx & 255;
                        s_h1[bb][cc >> 7][cc & 127] = ld_agent(src1 + idx);
                    }
                }
                __syncthreads();
                float s = 0.f;
                if (kq == 0) {   // Wih1 . h0[t]
                    const float* hp0 = &s_h0[b][0][0];
                    const float* hp1 = &s_h0[b][1][0];
                    for (int k = 0; k < 128; k += 4) {
                        f32x4 w4 = *(const f32x4*)(wrow1 + k);
                        f32x4 h4 = *(const f32x4*)(hp0 + k);
                        s += w4[0] * h4[0] + w4[1] * h4[1] + w4[2] * h4[2] + w4[3] * h4[3];
                    }
                    for (int k = 0; k < 128; k += 4) {
                        f32x4 w4 = *(const f32x4*)(wrow1 + 128 + k);
                        f32x4 h4 = *(const f32x4*)(hp1 + k);
                        s += w4[0] * h4[0] + w4[1] * h4[1] + w4[2] * h4[2] + w4[3] * h4[3];
                    }
                } else if (t > 0) {   // Whh1 . h1[t-1]
                    const float* hp0 = &s_h1[b][0][0];
                    const float* hp1 = &s_h1[b][1][0];
                    for (int k = 0; k < 128; k += 4) {
                        f32x4 w4 = *(const f32x4*)(wrow1 + k);
                        f32x4 h4 = *(const f32x4*)(hp0 + k);
                        s += w4[0] * h4[0] + w4[1] * h4[1] + w4[2] * h4[2] + w4[3] * h4[3];
                    }
                    for (int k = 0; k < 128; k += 4) {
                        f32x4 w4 = *(const f32x4*)(wrow1 + 128 + k);
                        f32x4 h4 = *(const f32x4*)(hp1 + k);
                        s += w4[0] * h4[0] + w4[1] * h4[1] + w4[2] * h4[2] + w4[3] * h4[3];
                    }
                }
                s += __shfl_xor(s, 16);   // Wih1 part + Whh1 part
                if (kq == 0) {
                    s_g[b][jl][g] = bias1 + s;
                }
                __syncthreads();
                if (tid < 64) {
                    int b3 = tid >> 2, j3 = tid & 3;
                    float gi = s_g[b3][j3][0], gf = s_g[b3][j3][1];
                    float gg = s_g[b3][j3][2], go = s_g[b3][j3][3];
                    c_reg = sigf(gf) * c_reg + sigf(gi) * tanhf_(gg);
                    float h = sigf(go) * tanhf_(c_reg);
                    st_agent(hbuf + 8192 + (t & 1) * 4096 + b3 * 256 + j0 + j3, h);
                }
            }
        }
        gbar(arrive, release, p + 1, wg, tid, 128);
    }

    if (wg == 0) {   // FC + sigmoid; final h1 at parity (31&1)=1
        const float* hf = hbuf + 8192 + 4096;
        float* s_fc = &s_g[0][0][0];
        if (tid < 256) {
            int bb = tid >> 4, ks = tid & 15;
            float s = 0.f;
#pragma unroll
            for (int k = 0; k < 16; ++k)
                s += Wfc[ks * 16 + k] * ld_agent(hf + bb * 256 + ks * 16 + k);
            s_fc[tid] = s;
        }
        __syncthreads();
        if (tid < 16) {
            float s = bfc[0];
#pragma unroll
            for (int q = 0; q < 16; ++q) s += s_fc[tid * 16 + q];
            out[tid] = sigf(s);
        }
    }
}

extern "C" void kernel_launch(void* const* d_in, const int* in_sizes, int n_in,
                              void* d_out, int out_size, void* d_ws, size_t ws_size,
                              hipStream_t stream) {
    const int*   adj  = (const int*)  d_in[0];
    const float* x    = (const float*)d_in[1];
    const float* W1   = (const float*)d_in[2];
    const float* b1   = (const float*)d_in[3];
    const float* W2   = (const float*)d_in[4];
    const float* b2   = (const float*)d_in[5];
    const float* Wih0 = (const float*)d_in[6];
    const float* Whh0 = (const float*)d_in[7];
    const float* bih0 = (const float*)d_in[8];
    const float* bhh0 = (const float*)d_in[9];
    const float* Wih1 = (const float*)d_in[10];
    const float* Whh1 = (const float*)d_in[11];
    const float* bih1 = (const float*)d_in[12];
    const float* bhh1 = (const float*)d_in[13];
    const float* Wfc  = (const float*)d_in[14];
    const float* bfc  = (const float*)d_in[15];
    float* out = (float*)d_out;

    if (ws_size < 40764416) return;   // ~40.8 MB scratch

    char* ws = (char*)d_ws;
    unsigned short* ft    = (unsigned short*)(ws);              // 33,554,432 B
    unsigned char*  gbm   = (unsigned char*)(ws + 33554432);    //  4,194,304 B
    float*          gdinv = (float*)(ws + 37748736);            //    524,288 B
    float*          emb   = (float*)(ws + 38273024);            //    262,144 B
    unsigned short* w1t   = (unsigned short*)(ws + 38535168);   //     32,768 B
    unsigned short* w2t   = (unsigned short*)(ws + 38567936);   //     32,768 B
    float*          xg    = (float*)(ws + 38600704);            //  2,097,152 B
    float*          hbuf  = (float*)(ws + 40697856);            //     65,536 B
    int*            flags = (int*)(ws + 40763392);              //      1,024 B

    hipMemsetAsync(flags, 0, 1024, stream);

    k_prep<<<64, 256, 0, stream>>>(W1, W2, w1t, w2t);
    k_gcn_a<<<512, 512, 0, stream>>>(adj, x, w1t, ft, gbm, gdinv);
    k_gcn_b<<<512, 512, 0, stream>>>(ft, gbm, gdinv, b1, w2t);
    k_gcn_c<<<512, 512, 0, stream>>>(ft, gbm, gdinv, b2, emb);
    k_xg<<<64, 256, 0, stream>>>(emb, Wih0, bih0, bhh0, xg);

    void* args[11];
    args[0] = (void*)&xg;
    args[1] = (void*)&Whh0;
    args[2] = (void*)&Wih1;
    args[3] = (void*)&Whh1;
    args[4] = (void*)&bih1;
    args[5] = (void*)&bhh1;
    args[6] = (void*)&Wfc;
    args[7] = (void*)&bfc;
    args[8] = (void*)&hbuf;
    args[9] = (void*)&flags;
    args[10] = (void*)&out;
    hipLaunchCooperativeKernel((const void*)k_lstm, dim3(128), dim3(512), args, 0, stream);
}

// Round 4
// 389.478 us; speedup vs baseline: 3.0766x; 2.2560x over previous
//
#include <hip/hip_runtime.h>
#include <hip/hip_bf16.h>

#define B_ 16
#define T_ 32
#define N_ 256
#define F_ 128
#define H_ 128
#define HL_ 256

typedef float f32x4 __attribute__((ext_vector_type(4)));
typedef float f32x2 __attribute__((ext_vector_type(2)));
typedef short bf16x8 __attribute__((ext_vector_type(8)));

#define MFMA16(A, Bv, C) __builtin_amdgcn_mfma_f32_16x16x32_bf16((A), (Bv), (C), 0, 0, 0)

__device__ __forceinline__ unsigned short f2bf(float f) {
    unsigned u = __builtin_bit_cast(unsigned, f);
    return (unsigned short)((u + 0x7FFFu + ((u >> 16) & 1u)) >> 16);
}
__device__ __forceinline__ float bf2f(unsigned short s) {
    unsigned u = ((unsigned)s) << 16;
    return __builtin_bit_cast(float, u);
}

__device__ __forceinline__ bf16x8 cvt8(const float* p) {
    f32x4 a = *(const f32x4*)p;
    f32x4 b = *(const f32x4*)(p + 4);
    bf16x8 r;
    r[0] = (short)f2bf(a[0]); r[1] = (short)f2bf(a[1]);
    r[2] = (short)f2bf(a[2]); r[3] = (short)f2bf(a[3]);
    r[4] = (short)f2bf(b[0]); r[5] = (short)f2bf(b[1]);
    r[6] = (short)f2bf(b[2]); r[7] = (short)f2bf(b[3]);
    return r;
}

__device__ __forceinline__ bf16x8 expand_bits(unsigned b) {
    bf16x8 r;
#pragma unroll
    for (int j = 0; j < 8; ++j) r[j] = (short)(((b >> j) & 1u) ? 0x3F80 : 0);
    return r;
}

__device__ __forceinline__ float sigf(float x) { return 1.f / (1.f + __expf(-x)); }
__device__ __forceinline__ float tanhf_(float x) { float e = __expf(2.f * x); return 1.f - 2.f / (e + 1.f); }

__device__ __forceinline__ unsigned ld_agent_u32(const unsigned* p) {
    return __hip_atomic_load(p, __ATOMIC_RELAXED, __HIP_MEMORY_SCOPE_AGENT);
}
__device__ __forceinline__ void st_agent_u32(unsigned* p, unsigned v) {
    __hip_atomic_store(p, v, __ATOMIC_RELAXED, __HIP_MEMORY_SCOPE_AGENT);
}
__device__ __forceinline__ int ld_flag(const int* p) {
    return __hip_atomic_load(p, __ATOMIC_RELAXED, __HIP_MEMORY_SCOPE_AGENT);
}
__device__ __forceinline__ void st_flag(int* p, int v) {
    __hip_atomic_store(p, v, __ATOMIC_RELAXED, __HIP_MEMORY_SCOPE_AGENT);
}

// ---------------- weight prep: W1^T, W2^T in bf16 ----------------
__global__ void k_prep(const float* __restrict__ W1, const float* __restrict__ W2,
                       unsigned short* __restrict__ w1t, unsigned short* __restrict__ w2t) {
    int idx = blockIdx.x * 256 + threadIdx.x;   // 64 blocks * 256 = 16384
    int h = idx >> 7, f = idx & 127;
    w1t[idx] = f2bf(W1[f * 128 + h]);
    w2t[idx] = f2bf(W2[f * 128 + h]);
}

// ---------------- gcn_a: bitmask+dinv from adj, XWT' = dinv .* (x@W1)^T bf16 ----------------
__global__ __launch_bounds__(512, 2) void k_gcn_a(
    const int* __restrict__ adj, const float* __restrict__ x,
    const unsigned short* __restrict__ w1t,
    unsigned short* __restrict__ ft, unsigned char* __restrict__ gbm,
    float* __restrict__ gdinv) {
    __shared__ unsigned char s_bm[256 * 32];
    __shared__ float s_dinv[256];
    __shared__ unsigned short s_w[128 * 136];
    const int bt = blockIdx.x;
    const int tid = threadIdx.x;
    const int* adjb = adj + (size_t)bt * (N_ * N_);

    for (int it = 0; it < 16; ++it) {
        int row = it * 16 + (tid >> 5);
        int c = tid & 31, m0 = c * 8;
        const int* p = adjb + row * N_ + m0;
        int4 q0 = *(const int4*)p;
        int4 q1 = *(const int4*)(p + 4);
        unsigned by = 0;
        by |= (((q0.x != 0) | (m0 + 0 == row)) ? 1u : 0u);
        by |= (((q0.y != 0) | (m0 + 1 == row)) ? 2u : 0u);
        by |= (((q0.z != 0) | (m0 + 2 == row)) ? 4u : 0u);
        by |= (((q0.w != 0) | (m0 + 3 == row)) ? 8u : 0u);
        by |= (((q1.x != 0) | (m0 + 4 == row)) ? 16u : 0u);
        by |= (((q1.y != 0) | (m0 + 5 == row)) ? 32u : 0u);
        by |= (((q1.z != 0) | (m0 + 6 == row)) ? 64u : 0u);
        by |= (((q1.w != 0) | (m0 + 7 == row)) ? 128u : 0u);
        s_bm[row * 32 + c] = (unsigned char)by;
        int pc = __popc(by);
        pc += __shfl_xor(pc, 1); pc += __shfl_xor(pc, 2); pc += __shfl_xor(pc, 4);
        pc += __shfl_xor(pc, 8); pc += __shfl_xor(pc, 16);
        if (c == 0) s_dinv[row] = rsqrtf((float)pc);
    }
    for (int it = 0; it < 4; ++it) {
        int g = it * 512 + tid;
        *(int4*)(&s_w[(g >> 4) * 136 + (g & 15) * 8]) = *(const int4*)(w1t + g * 8);
    }
    __syncthreads();
    *(int4*)(gbm + (size_t)bt * 8192 + tid * 16) = *(const int4*)(s_bm + tid * 16);
    if (tid < 64) *(float4*)(gdinv + bt * 256 + tid * 4) = *(const float4*)(s_dinv + tid * 4);

    const int w = tid >> 6, l = tid & 63, li = l & 15, lg = l >> 4;
    const float* xb = x + (size_t)bt * (N_ * F_);
    f32x4 acc[2][8];
#pragma unroll
    for (int a = 0; a < 2; ++a)
#pragma unroll
        for (int c = 0; c < 8; ++c) acc[a][c] = (f32x4){0.f, 0.f, 0.f, 0.f};

#pragma unroll
    for (int ks = 0; ks < 4; ++ks) {
        bf16x8 a0 = cvt8(xb + (size_t)(32 * w + li) * F_ + lg * 8 + ks * 32);
        bf16x8 a1 = cvt8(xb + (size_t)(32 * w + 16 + li) * F_ + lg * 8 + ks * 32);
#pragma unroll
        for (int ct = 0; ct < 8; ++ct) {
            bf16x8 bv = *(const bf16x8*)(&s_w[(16 * ct + li) * 136 + lg * 8 + ks * 32]);
            acc[0][ct] = MFMA16(a0, bv, acc[0][ct]);
            acc[1][ct] = MFMA16(a1, bv, acc[1][ct]);
        }
    }
#pragma unroll
    for (int rt = 0; rt < 2; ++rt) {
        int m0 = 32 * w + 16 * rt + 4 * lg;
        f32x4 dv = *(const f32x4*)(&s_dinv[m0]);
#pragma unroll
        for (int ct = 0; ct < 8; ++ct) {
            int h = 16 * ct + li;
            f32x4 v = acc[rt][ct];
            unsigned p0 = (unsigned)f2bf(v[0] * dv[0]) | ((unsigned)f2bf(v[1] * dv[1]) << 16);
            unsigned p1 = (unsigned)f2bf(v[2] * dv[2]) | ((unsigned)f2bf(v[3] * dv[3]) << 16);
            uint2 pk; pk.x = p0; pk.y = p1;
            *(uint2*)(ft + ((size_t)bt * H_ + h) * N_ + m0) = pk;
        }
    }
}

// ---------------- gcn_b: h1 = relu(norm@XW + b1); FT <- dinv .* (h1@W2)^T ----------------
__global__ __launch_bounds__(512, 2) void k_gcn_b(
    unsigned short* ft,
    const unsigned char* __restrict__ gbm, const float* __restrict__ gdinv,
    const float* __restrict__ b1, const unsigned short* __restrict__ w2t) {
    __shared__ unsigned short s_ft[256 * 136];   // XWT [128][264] then h1 [256][136]
    __shared__ unsigned short s_w[128 * 136];
    __shared__ unsigned char s_bm[8192];
    __shared__ float s_dinv[256];
    __shared__ float s_b[128];
    const int bt = blockIdx.x, tid = threadIdx.x;
#pragma unroll
    for (int it = 0; it < 8; ++it) {
        int g = it * 512 + tid;
        *(int4*)(&s_ft[(g >> 5) * 264 + (g & 31) * 8]) = *(const int4*)(ft + (size_t)bt * 32768 + g * 8);
    }
#pragma unroll
    for (int it = 0; it < 4; ++it) {
        int g = it * 512 + tid;
        *(int4*)(&s_w[(g >> 4) * 136 + (g & 15) * 8]) = *(const int4*)(w2t + g * 8);
    }
    *(int4*)(s_bm + tid * 16) = *(const int4*)(gbm + (size_t)bt * 8192 + tid * 16);
    if (tid < 64) *(float4*)(&s_dinv[tid * 4]) = *(const float4*)(gdinv + bt * 256 + tid * 4);
    if (tid < 32) *(float4*)(&s_b[tid * 4]) = *(const float4*)(b1 + tid * 4);
    __syncthreads();

    const int w = tid >> 6, l = tid & 63, li = l & 15, lg = l >> 4;
    f32x4 acc[2][8];
#pragma unroll
    for (int a = 0; a < 2; ++a)
#pragma unroll
        for (int c = 0; c < 8; ++c) acc[a][c] = (f32x4){0.f, 0.f, 0.f, 0.f};

#pragma unroll
    for (int ks = 0; ks < 8; ++ks) {
        bf16x8 a0 = expand_bits(s_bm[(32 * w + li) * 32 + 4 * ks + lg]);
        bf16x8 a1 = expand_bits(s_bm[(32 * w + 16 + li) * 32 + 4 * ks + lg]);
#pragma unroll
        for (int ct = 0; ct < 8; ++ct) {
            bf16x8 bv = *(const bf16x8*)(&s_ft[(16 * ct + li) * 264 + lg * 8 + ks * 32]);
            acc[0][ct] = MFMA16(a0, bv, acc[0][ct]);
            acc[1][ct] = MFMA16(a1, bv, acc[1][ct]);
        }
    }
    __syncthreads();   // all XWT reads done; reuse region as h1
#pragma unroll
    for (int rt = 0; rt < 2; ++rt) {
        int i0 = 32 * w + 16 * rt + 4 * lg;
        f32x4 dv = *(const f32x4*)(&s_dinv[i0]);
#pragma unroll
        for (int ct = 0; ct < 8; ++ct) {
            int h = 16 * ct + li;
            float bb = s_b[h];
#pragma unroll
            for (int r = 0; r < 4; ++r)
                s_ft[(i0 + r) * 136 + h] = f2bf(fmaxf(acc[rt][ct][r] * dv[r] + bb, 0.f));
        }
    }
    __syncthreads();
    // gemm2: h1 @ W2  (K=128)
#pragma unroll
    for (int a = 0; a < 2; ++a)
#pragma unroll
        for (int c = 0; c < 8; ++c) acc[a][c] = (f32x4){0.f, 0.f, 0.f, 0.f};
#pragma unroll
    for (int ks = 0; ks < 4; ++ks) {
        bf16x8 a0 = *(const bf16x8*)(&s_ft[(32 * w + li) * 136 + lg * 8 + ks * 32]);
        bf16x8 a1 = *(const bf16x8*)(&s_ft[(32 * w + 16 + li) * 136 + lg * 8 + ks * 32]);
#pragma unroll
        for (int ct = 0; ct < 8; ++ct) {
            bf16x8 bv = *(const bf16x8*)(&s_w[(16 * ct + li) * 136 + lg * 8 + ks * 32]);
            acc[0][ct] = MFMA16(a0, bv, acc[0][ct]);
            acc[1][ct] = MFMA16(a1, bv, acc[1][ct]);
        }
    }
#pragma unroll
    for (int rt = 0; rt < 2; ++rt) {
        int m0 = 32 * w + 16 * rt + 4 * lg;
        f32x4 dv = *(const f32x4*)(&s_dinv[m0]);
#pragma unroll
        for (int ct = 0; ct < 8; ++ct) {
            int h = 16 * ct + li;
            f32x4 v = acc[rt][ct];
            unsigned p0 = (unsigned)f2bf(v[0] * dv[0]) | ((unsigned)f2bf(v[1] * dv[1]) << 16);
            unsigned p1 = (unsigned)f2bf(v[2] * dv[2]) | ((unsigned)f2bf(v[3] * dv[3]) << 16);
            uint2 pk; pk.x = p0; pk.y = p1;
            *(uint2*)(ft + ((size_t)bt * H_ + h) * N_ + m0) = pk;
        }
    }
}

// ---------------- gcn_c: h2 = relu(norm@H1W + b2); emb = mean_n(h2) ----------------
__global__ __launch_bounds__(512, 2) void k_gcn_c(
    const unsigned short* __restrict__ ft, const unsigned char* __restrict__ gbm,
    const float* __restrict__ gdinv, const float* __restrict__ b2,
    float* __restrict__ emb) {
    __shared__ unsigned short s_ft[128 * 264];
    __shared__ unsigned char s_bm[8192];
    __shared__ float s_dinv[256];
    __shared__ float s_b[128];
    __shared__ float s_pool[8 * 128];
    const int bt = blockIdx.x, tid = threadIdx.x;
#pragma unroll
    for (int it = 0; it < 8; ++it) {
        int g = it * 512 + tid;
        *(int4*)(&s_ft[(g >> 5) * 264 + (g & 31) * 8]) = *(const int4*)(ft + (size_t)bt * 32768 + g * 8);
    }
    *(int4*)(s_bm + tid * 16) = *(const int4*)(gbm + (size_t)bt * 8192 + tid * 16);
    if (tid < 64) *(float4*)(&s_dinv[tid * 4]) = *(const float4*)(gdinv + bt * 256 + tid * 4);
    if (tid < 32) *(float4*)(&s_b[tid * 4]) = *(const float4*)(b2 + tid * 4);
    __syncthreads();

    const int w = tid >> 6, l = tid & 63, li = l & 15, lg = l >> 4;
    f32x4 acc[2][8];
#pragma unroll
    for (int a = 0; a < 2; ++a)
#pragma unroll
        for (int c = 0; c < 8; ++c) acc[a][c] = (f32x4){0.f, 0.f, 0.f, 0.f};
#pragma unroll
    for (int ks = 0; ks < 8; ++ks) {
        bf16x8 a0 = expand_bits(s_bm[(32 * w + li) * 32 + 4 * ks + lg]);
        bf16x8 a1 = expand_bits(s_bm[(32 * w + 16 + li) * 32 + 4 * ks + lg]);
#pragma unroll
        for (int ct = 0; ct < 8; ++ct) {
            bf16x8 bv = *(const bf16x8*)(&s_ft[(16 * ct + li) * 264 + lg * 8 + ks * 32]);
            acc[0][ct] = MFMA16(a0, bv, acc[0][ct]);
            acc[1][ct] = MFMA16(a1, bv, acc[1][ct]);
        }
    }
    int i0a = 32 * w + 4 * lg;
    f32x4 dv0 = *(const f32x4*)(&s_dinv[i0a]);
    f32x4 dv1 = *(const f32x4*)(&s_dinv[i0a + 16]);
#pragma unroll
    for (int ct = 0; ct < 8; ++ct) {
        int h = 16 * ct + li;
        float bb = s_b[h];
        float s = 0.f;
#pragma unroll
        for (int r = 0; r < 4; ++r) {
            s += fmaxf(acc[0][ct][r] * dv0[r] + bb, 0.f);
            s += fmaxf(acc[1][ct][r] * dv1[r] + bb, 0.f);
        }
        s += __shfl_xor(s, 16);
        s += __shfl_xor(s, 32);
        if (lg == 0) s_pool[w * 128 + h] = s;
    }
    __syncthreads();
    if (tid < 128) {
        float e = 0.f;
#pragma unroll
        for (int ww = 0; ww < 8; ++ww) e += s_pool[ww * 128 + tid];
        emb[(size_t)bt * 128 + tid] = e * (1.f / 256.f);
    }
}

// ---------------- xg = emb @ Wih0^T + bih0 + bhh0   (layout [t][b][1024]) ----------------
__global__ __launch_bounds__(256, 2) void k_xg(
    const float* __restrict__ emb, const float* __restrict__ Wih0,
    const float* __restrict__ bih0, const float* __restrict__ bhh0,
    float* __restrict__ xg) {
    __shared__ float s_e[8][128];
    const int bk = blockIdx.x, tid = threadIdx.x;
    for (int q = 0; q < 4; ++q) {
        int idx = q * 256 + tid;
        int p = idx >> 7, k = idx & 127;
        int tb2 = bk * 8 + p;
        int t = tb2 >> 4, b = tb2 & 15;
        s_e[p][k] = emb[(size_t)(b * T_ + t) * 128 + k];
    }
    __syncthreads();
    for (int cc = 0; cc < 4; ++cc) {
        int col = cc * 256 + tid;
        float bias = bih0[col] + bhh0[col];
        const float4* wr = (const float4*)(Wih0 + (size_t)col * 128);
        float accv[8] = {0, 0, 0, 0, 0, 0, 0, 0};
        for (int k4 = 0; k4 < 32; ++k4) {
            float4 wv = wr[k4];
#pragma unroll
            for (int p = 0; p < 8; ++p) {
                float4 ev = *(const float4*)(&s_e[p][k4 * 4]);
                accv[p] += wv.x * ev.x + wv.y * ev.y + wv.z * ev.z + wv.w * ev.w;
            }
        }
#pragma unroll
        for (int p = 0; p < 8; ++p) {
            int tb2 = bk * 8 + p;
            xg[(size_t)tb2 * 1024 + col] = accv[p] + bias;
        }
    }
}

// ---------------- dataflow LSTM: 8 layer0 blocks + 16 layer1 blocks ----------------
// h0buf/h1buf: [2 parity][16 b][256 j] bf16 (as u32 words). flags[0..7]=L0, [8..23]=L1.
// L0 block bi: j in [32bi,32bi+32), rows r_local = g*32+jl (128 rows), K=256, MFMA.
// L1 block bi: j in [16bi,16bi+16), rows r_local = g*16+jl (64 rows),  K=512 (h0|h1).
// Waits: L0@t: fL0>=t, fL1>=t-1.  L1@t: fL0>=t+1, fL1>=t.  (monotonic, deadlock-free)
__global__ __launch_bounds__(512, 1) void k_lstm(
    const float* __restrict__ xg, const float* __restrict__ Whh0,
    const float* __restrict__ Wih1, const float* __restrict__ Whh1,
    const float* __restrict__ bih1, const float* __restrict__ bhh1,
    const float* __restrict__ Wfc, const float* __restrict__ bfc,
    unsigned* h0buf, unsigned* h1buf, int* flags, float* __restrict__ out) {
    __shared__ __align__(16) char arena[91456];
    const int wg = blockIdx.x, tid = threadIdx.x;
    const int lane = tid & 63;

    if (wg < 8) {
        // ================= LAYER 0 =================
        unsigned short* s_w = (unsigned short*)arena;            // [128][258] bf16
        unsigned short* s_h = (unsigned short*)(arena + 66048);  // [16][258] bf16
        float* s_gate = (float*)(arena + 74304);                 // [128][18] f32
        const int j0 = wg * 32;

        // stage Whh0 slice -> LDS bf16 (once)
#pragma unroll
        for (int it = 0; it < 16; ++it) {
            int e4 = tid + it * 512;
            int rl = e4 >> 6, k0 = (e4 & 63) * 4;
            int rg = (rl >> 5) * 256 + j0 + (rl & 31);
            float4 v = *(const float4*)(Whh0 + (size_t)rg * 256 + k0);
            uint2 pk;
            pk.x = (unsigned)f2bf(v.x) | ((unsigned)f2bf(v.y) << 16);
            pk.y = (unsigned)f2bf(v.z) | ((unsigned)f2bf(v.w) << 16);
            *(uint2*)(s_w + rl * 258 + k0) = pk;
        }
        __syncthreads();

        const int w = tid >> 6, li = lane & 15, lg = lane >> 4;
        const int cb = tid >> 5, cj = tid & 31;        // c-thread: (batch, j-local)
        float c_reg = 0.f;

        for (int t = 0; t < 32; ++t) {
            // prefetch xg gates (stable data, regular cached loads)
            float xgv[4];
#pragma unroll
            for (int g = 0; g < 4; ++g)
                xgv[g] = xg[(size_t)(t * 16 + cb) * 1024 + g * 256 + j0 + cj];
            // waits
            if (tid < 24) {
                const int* fp = flags + tid;
                int tg = (tid < 8) ? t : (t - 1);
                while (tg > 0 && ld_flag(fp) < tg) __builtin_amdgcn_s_sleep(1);
            }
            __syncthreads();
            if (t > 0) {
                // stage h0[t-1] (16x256 bf16 = 2048 words)
                const unsigned* src = h0buf + ((t - 1) & 1) * 2048;
#pragma unroll
                for (int q = 0; q < 4; ++q) {
                    int wd = tid + q * 512;
                    int b = wd >> 7, jw = wd & 127;
                    *(unsigned*)(s_h + b * 258 + jw * 2) = ld_agent_u32(src + wd);
                }
            }
            __syncthreads();
            if (t > 0) {
                // MFMA: wave w owns N-tile rows [16w,16w+16), K=256
                f32x4 acc = (f32x4){0.f, 0.f, 0.f, 0.f};
#pragma unroll
                for (int ks = 0; ks < 8; ++ks) {
                    bf16x8 af = *(const bf16x8*)(s_h + li * 258 + lg * 8 + ks * 32);
                    bf16x8 bf = *(const bf16x8*)(s_w + (16 * w + li) * 258 + lg * 8 + ks * 32);
                    acc = MFMA16(af, bf, acc);
                }
                int base = (16 * w + li) * 18 + 4 * lg;
                *(f32x2*)(s_gate + base) = (f32x2){acc[0], acc[1]};
                *(f32x2*)(s_gate + base + 2) = (f32x2){acc[2], acc[3]};
            }
            __syncthreads();
            // c/h update: thread (cb, cj)
            {
                float gi = xgv[0], gf = xgv[1], gg = xgv[2], go = xgv[3];
                if (t > 0) {
                    gi += s_gate[(0 * 32 + cj) * 18 + cb];
                    gf += s_gate[(1 * 32 + cj) * 18 + cb];
                    gg += s_gate[(2 * 32 + cj) * 18 + cb];
                    go += s_gate[(3 * 32 + cj) * 18 + cb];
                }
                c_reg = sigf(gf) * c_reg + sigf(gi) * tanhf_(gg);
                float h = sigf(go) * tanhf_(c_reg);
                unsigned hu = f2bf(h);
                unsigned other = __shfl_xor(hu, 1);
                if ((cj & 1) == 0)
                    st_agent_u32(h0buf + (t & 1) * 2048 + cb * 128 + ((j0 + cj) >> 1),
                                 hu | (other << 16));
            }
            asm volatile("s_waitcnt vmcnt(0)" ::: "memory");
            __syncthreads();
            if (tid == 0) st_flag(flags + wg, t + 1);
        }
    } else {
        // ================= LAYER 1 =================
        unsigned short* s_w = (unsigned short*)arena;            // [64][514] bf16
        unsigned short* s_h = (unsigned short*)(arena + 65792);  // [16][514] bf16
        float* s_gate = (float*)(arena + 82240);                 // [2][64][18] f32
        const int bi = wg - 8;
        const int j0 = bi * 16;

        // stage [Wih1 | Whh1] slice -> LDS bf16 (once)
#pragma unroll
        for (int it = 0; it < 16; ++it) {
            int e4 = tid + it * 512;
            int rl = e4 >> 7, k0 = (e4 & 127) * 4;
            int rg = (rl >> 4) * 256 + j0 + (rl & 15);
            const float* src = (k0 < 256) ? (Wih1 + (size_t)rg * 256 + k0)
                                          : (Whh1 + (size_t)rg * 256 + (k0 - 256));
            float4 v = *(const float4*)src;
            uint2 pk;
            pk.x = (unsigned)f2bf(v.x) | ((unsigned)f2bf(v.y) << 16);
            pk.y = (unsigned)f2bf(v.z) | ((unsigned)f2bf(v.w) << 16);
            *(uint2*)(s_w + rl * 514 + k0) = pk;
        }

        const int w = tid >> 6, li = lane & 15, lg = lane >> 4;
        const int ct = w & 3, kh = w >> 2;
        const int cb = tid >> 4, cj = tid & 15;       // c-thread (tid<256): (batch, j-local)
        float bias[4];
        if (tid < 256) {
#pragma unroll
            for (int g = 0; g < 4; ++g) {
                int r = g * 256 + j0 + cj;
                bias[g] = bih1[r] + bhh1[r];
            }
        }
        __syncthreads();
        float c_reg = 0.f;

        for (int t = 0; t < 32; ++t) {
            if (tid < 24) {
                const int* fp = flags + tid;
                int tg = (tid < 8) ? (t + 1) : t;
                while (tg > 0 && ld_flag(fp) < tg) __builtin_amdgcn_s_sleep(1);
            }
            __syncthreads();
            {
                // stage A = [h0[t] | h1[t-1]] (16 x 512 bf16 = 4096 words)
                const unsigned* s0 = h0buf + (t & 1) * 2048;
                const unsigned* s1 = h1buf + ((t - 1) & 1) * 2048;
#pragma unroll
                for (int q = 0; q < 8; ++q) {
                    int wd = tid + q * 512;
                    int half = wd >> 11, w2 = wd & 2047;
                    int b = w2 >> 7, jw = w2 & 127;
                    unsigned v;
                    if (half == 0) v = ld_agent_u32(s0 + w2);
                    else v = (t > 0) ? ld_agent_u32(s1 + w2) : 0u;
                    *(unsigned*)(s_h + b * 514 + half * 256 + jw * 2) = v;
                }
            }
            __syncthreads();
            {
                // MFMA: wave (ct,kh): N-tile rows [16ct,16ct+16), K-half kh
                f32x4 acc = (f32x4){0.f, 0.f, 0.f, 0.f};
#pragma unroll
                for (int ks = 0; ks < 8; ++ks) {
                    int ko = (kh * 8 + ks) * 32;
                    bf16x8 af = *(const bf16x8*)(s_h + li * 514 + lg * 8 + ko);
                    bf16x8 bf = *(const bf16x8*)(s_w + (16 * ct + li) * 514 + lg * 8 + ko);
                    acc = MFMA16(af, bf, acc);
                }
                int base = kh * 1152 + (16 * ct + li) * 18 + 4 * lg;
                *(f32x2*)(s_gate + base) = (f32x2){acc[0], acc[1]};
                *(f32x2*)(s_gate + base + 2) = (f32x2){acc[2], acc[3]};
            }
            __syncthreads();
            if (tid < 256) {
                float gt[4];
#pragma unroll
                for (int g = 0; g < 4; ++g) {
                    int base = (g * 16 + cj) * 18 + cb;
                    gt[g] = s_gate[base] + s_gate[1152 + base] + bias[g];
                }
                c_reg = sigf(gt[1]) * c_reg + sigf(gt[0]) * tanhf_(gt[2]);
                float h = sigf(gt[3]) * tanhf_(c_reg);
                unsigned hu = f2bf(h);
                unsigned other = __shfl_xor(hu, 1);
                if ((cj & 1) == 0)
                    st_agent_u32(h1buf + (t & 1) * 2048 + cb * 128 + ((j0 + cj) >> 1),
                                 hu | (other << 16));
            }
            asm volatile("s_waitcnt vmcnt(0)" ::: "memory");
            __syncthreads();
            if (tid == 0) st_flag(flags + 8 + bi, t + 1);
        }

        if (bi == 0) {
            // FC + sigmoid on h1[31] (parity 1)
            if (tid < 16) {
                while (ld_flag(flags + 8 + tid) < 32) __builtin_amdgcn_s_sleep(1);
            }
            __syncthreads();
            float* s_red = s_gate;
            if (tid < 256) {
                int b = tid >> 4, kc = tid & 15;
                const unsigned* hw = h1buf + 2048 + b * 128 + kc * 8;
                float s = 0.f;
#pragma unroll
                for (int q = 0; q < 8; ++q) {
                    unsigned u = ld_agent_u32(hw + q);
                    s += Wfc[kc * 16 + 2 * q] * bf2f((unsigned short)(u & 0xffff));
                    s += Wfc[kc * 16 + 2 * q + 1] * bf2f((unsigned short)(u >> 16));
                }
                s_red[tid] = s;
            }
            __syncthreads();
            if (tid < 16) {
                float s = bfc[0];
#pragma unroll
                for (int q = 0; q < 16; ++q) s += s_red[tid * 16 + q];
                out[tid] = sigf(s);
            }
        }
    }
}

extern "C" void kernel_launch(void* const* d_in, const int* in_sizes, int n_in,
                              void* d_out, int out_size, void* d_ws, size_t ws_size,
                              hipStream_t stream) {
    const int*   adj  = (const int*)  d_in[0];
    const float* x    = (const float*)d_in[1];
    const float* W1   = (const float*)d_in[2];
    const float* b1   = (const float*)d_in[3];
    const float* W2   = (const float*)d_in[4];
    const float* b2   = (const float*)d_in[5];
    const float* Wih0 = (const float*)d_in[6];
    const float* Whh0 = (const float*)d_in[7];
    const float* bih0 = (const float*)d_in[8];
    const float* bhh0 = (const float*)d_in[9];
    const float* Wih1 = (const float*)d_in[10];
    const float* Whh1 = (const float*)d_in[11];
    const float* bih1 = (const float*)d_in[12];
    const float* bhh1 = (const float*)d_in[13];
    const float* Wfc  = (const float*)d_in[14];
    const float* bfc  = (const float*)d_in[15];
    float* out = (float*)d_out;

    if (ws_size < 40764416) return;   // ~40.8 MB scratch

    char* ws = (char*)d_ws;
    unsigned short* ft    = (unsigned short*)(ws);              // 33,554,432 B
    unsigned char*  gbm   = (unsigned char*)(ws + 33554432);    //  4,194,304 B
    float*          gdinv = (float*)(ws + 37748736);            //    524,288 B
    float*          emb   = (float*)(ws + 38273024);            //    262,144 B
    unsigned short* w1t   = (unsigned short*)(ws + 38535168);   //     32,768 B
    unsigned short* w2t   = (unsigned short*)(ws + 38567936);   //     32,768 B
    float*          xg    = (float*)(ws + 38600704);            //  2,097,152 B
    unsigned*       h0buf = (unsigned*)(ws + 40697856);         //     16,384 B
    unsigned*       h1buf = (unsigned*)(ws + 40714240);         //     16,384 B
    int*            flags = (int*)(ws + 40730624);              //       256 B

    hipMemsetAsync(flags, 0, 256, stream);

    k_prep<<<64, 256, 0, stream>>>(W1, W2, w1t, w2t);
    k_gcn_a<<<512, 512, 0, stream>>>(adj, x, w1t, ft, gbm, gdinv);
    k_gcn_b<<<512, 512, 0, stream>>>(ft, gbm, gdinv, b1, w2t);
    k_gcn_c<<<512, 512, 0, stream>>>(ft, gbm, gdinv, b2, emb);
    k_xg<<<64, 256, 0, stream>>>(emb, Wih0, bih0, bhh0, xg);

    void* args[12];
    args[0] = (void*)&xg;
    args[1] = (void*)&Whh0;
    args[2] = (void*)&Wih1;
    args[3] = (void*)&Whh1;
    args[4] = (void*)&bih1;
    args[5] = (void*)&bhh1;
    args[6] = (void*)&Wfc;
    args[7] = (void*)&bfc;
    args[8] = (void*)&h0buf;
    args[9] = (void*)&h1buf;
    args[10] = (void*)&flags;
    args[11] = (void*)&out;
    hipLaunchCooperativeKernel((const void*)k_lstm, dim3(24), dim3(512), args, 0, stream);
}

// Round 5
// 353.730 us; speedup vs baseline: 3.3876x; 1.1011x over previous
//
#include <hip/hip_runtime.h>
#include <hip/hip_bf16.h>

#define B_ 16
#define T_ 32
#define N_ 256
#define F_ 128
#define H_ 128
#define HL_ 256

typedef float f32x4 __attribute__((ext_vector_type(4)));
typedef float f32x2 __attribute__((ext_vector_type(2)));
typedef short bf16x8 __attribute__((ext_vector_type(8)));

#define MFMA16(A, Bv, C) __builtin_amdgcn_mfma_f32_16x16x32_bf16((A), (Bv), (C), 0, 0, 0)

__device__ __forceinline__ unsigned short f2bf(float f) {
    unsigned u = __builtin_bit_cast(unsigned, f);
    return (unsigned short)((u + 0x7FFFu + ((u >> 16) & 1u)) >> 16);
}
__device__ __forceinline__ float bf2f(unsigned short s) {
    unsigned u = ((unsigned)s) << 16;
    return __builtin_bit_cast(float, u);
}

__device__ __forceinline__ bf16x8 cvt8(const float* p) {
    f32x4 a = *(const f32x4*)p;
    f32x4 b = *(const f32x4*)(p + 4);
    bf16x8 r;
    r[0] = (short)f2bf(a[0]); r[1] = (short)f2bf(a[1]);
    r[2] = (short)f2bf(a[2]); r[3] = (short)f2bf(a[3]);
    r[4] = (short)f2bf(b[0]); r[5] = (short)f2bf(b[1]);
    r[6] = (short)f2bf(b[2]); r[7] = (short)f2bf(b[3]);
    return r;
}

__device__ __forceinline__ bf16x8 expand_bits(unsigned b) {
    bf16x8 r;
#pragma unroll
    for (int j = 0; j < 8; ++j) r[j] = (short)(((b >> j) & 1u) ? 0x3F80 : 0);
    return r;
}

__device__ __forceinline__ float sigf(float x) { return 1.f / (1.f + __expf(-x)); }
__device__ __forceinline__ float tanhf_(float x) { float e = __expf(2.f * x); return 1.f - 2.f / (e + 1.f); }

// epoch-tagged h word: lo = 2x bf16 payload, hi = epoch (t+1). Single 8B sc1 op.
__device__ __forceinline__ unsigned poll_u64(const unsigned long long* p, unsigned epoch) {
    unsigned long long v = __hip_atomic_load(p, __ATOMIC_RELAXED, __HIP_MEMORY_SCOPE_AGENT);
    while ((unsigned)(v >> 32) != epoch) {
        __builtin_amdgcn_s_sleep(1);
        v = __hip_atomic_load(p, __ATOMIC_RELAXED, __HIP_MEMORY_SCOPE_AGENT);
    }
    return (unsigned)v;
}
__device__ __forceinline__ void st_u64(unsigned long long* p, unsigned long long v) {
    __hip_atomic_store(p, v, __ATOMIC_RELAXED, __HIP_MEMORY_SCOPE_AGENT);
}

// ---------------- weight prep: W1^T, W2^T in bf16 ----------------
__global__ void k_prep(const float* __restrict__ W1, const float* __restrict__ W2,
                       unsigned short* __restrict__ w1t, unsigned short* __restrict__ w2t) {
    int idx = blockIdx.x * 256 + threadIdx.x;   // 64 blocks * 256 = 16384
    int h = idx >> 7, f = idx & 127;
    w1t[idx] = f2bf(W1[f * 128 + h]);
    w2t[idx] = f2bf(W2[f * 128 + h]);
}

// ---------------- gcn_a: bitmask+dinv from adj, XWT' = dinv .* (x@W1)^T bf16 ----------------
__global__ __launch_bounds__(512, 2) void k_gcn_a(
    const int* __restrict__ adj, const float* __restrict__ x,
    const unsigned short* __restrict__ w1t,
    unsigned short* __restrict__ ft, unsigned char* __restrict__ gbm,
    float* __restrict__ gdinv) {
    __shared__ unsigned char s_bm[256 * 32];
    __shared__ float s_dinv[256];
    __shared__ unsigned short s_w[128 * 136];
    const int bt = blockIdx.x;
    const int tid = threadIdx.x;
    const int* adjb = adj + (size_t)bt * (N_ * N_);

    for (int it = 0; it < 16; ++it) {
        int row = it * 16 + (tid >> 5);
        int c = tid & 31, m0 = c * 8;
        const int* p = adjb + row * N_ + m0;
        int4 q0 = *(const int4*)p;
        int4 q1 = *(const int4*)(p + 4);
        unsigned by = 0;
        by |= (((q0.x != 0) | (m0 + 0 == row)) ? 1u : 0u);
        by |= (((q0.y != 0) | (m0 + 1 == row)) ? 2u : 0u);
        by |= (((q0.z != 0) | (m0 + 2 == row)) ? 4u : 0u);
        by |= (((q0.w != 0) | (m0 + 3 == row)) ? 8u : 0u);
        by |= (((q1.x != 0) | (m0 + 4 == row)) ? 16u : 0u);
        by |= (((q1.y != 0) | (m0 + 5 == row)) ? 32u : 0u);
        by |= (((q1.z != 0) | (m0 + 6 == row)) ? 64u : 0u);
        by |= (((q1.w != 0) | (m0 + 7 == row)) ? 128u : 0u);
        s_bm[row * 32 + c] = (unsigned char)by;
        int pc = __popc(by);
        pc += __shfl_xor(pc, 1); pc += __shfl_xor(pc, 2); pc += __shfl_xor(pc, 4);
        pc += __shfl_xor(pc, 8); pc += __shfl_xor(pc, 16);
        if (c == 0) s_dinv[row] = rsqrtf((float)pc);
    }
    for (int it = 0; it < 4; ++it) {
        int g = it * 512 + tid;
        *(int4*)(&s_w[(g >> 4) * 136 + (g & 15) * 8]) = *(const int4*)(w1t + g * 8);
    }
    __syncthreads();
    *(int4*)(gbm + (size_t)bt * 8192 + tid * 16) = *(const int4*)(s_bm + tid * 16);
    if (tid < 64) *(float4*)(gdinv + bt * 256 + tid * 4) = *(const float4*)(s_dinv + tid * 4);

    const int w = tid >> 6, l = tid & 63, li = l & 15, lg = l >> 4;
    const float* xb = x + (size_t)bt * (N_ * F_);
    f32x4 acc[2][8];
#pragma unroll
    for (int a = 0; a < 2; ++a)
#pragma unroll
        for (int c = 0; c < 8; ++c) acc[a][c] = (f32x4){0.f, 0.f, 0.f, 0.f};

#pragma unroll
    for (int ks = 0; ks < 4; ++ks) {
        bf16x8 a0 = cvt8(xb + (size_t)(32 * w + li) * F_ + lg * 8 + ks * 32);
        bf16x8 a1 = cvt8(xb + (size_t)(32 * w + 16 + li) * F_ + lg * 8 + ks * 32);
#pragma unroll
        for (int ct = 0; ct < 8; ++ct) {
            bf16x8 bv = *(const bf16x8*)(&s_w[(16 * ct + li) * 136 + lg * 8 + ks * 32]);
            acc[0][ct] = MFMA16(a0, bv, acc[0][ct]);
            acc[1][ct] = MFMA16(a1, bv, acc[1][ct]);
        }
    }
#pragma unroll
    for (int rt = 0; rt < 2; ++rt) {
        int m0 = 32 * w + 16 * rt + 4 * lg;
        f32x4 dv = *(const f32x4*)(&s_dinv[m0]);
#pragma unroll
        for (int ct = 0; ct < 8; ++ct) {
            int h = 16 * ct + li;
            f32x4 v = acc[rt][ct];
            unsigned p0 = (unsigned)f2bf(v[0] * dv[0]) | ((unsigned)f2bf(v[1] * dv[1]) << 16);
            unsigned p1 = (unsigned)f2bf(v[2] * dv[2]) | ((unsigned)f2bf(v[3] * dv[3]) << 16);
            uint2 pk; pk.x = p0; pk.y = p1;
            *(uint2*)(ft + ((size_t)bt * H_ + h) * N_ + m0) = pk;
        }
    }
}

// ---------------- gcn_b: h1 = relu(norm@XW + b1); FT <- dinv .* (h1@W2)^T ----------------
__global__ __launch_bounds__(512, 2) void k_gcn_b(
    unsigned short* ft,
    const unsigned char* __restrict__ gbm, const float* __restrict__ gdinv,
    const float* __restrict__ b1, const unsigned short* __restrict__ w2t) {
    __shared__ unsigned short s_ft[256 * 136];   // XWT [128][264] then h1 [256][136]
    __shared__ unsigned short s_w[128 * 136];
    __shared__ unsigned char s_bm[8192];
    __shared__ float s_dinv[256];
    __shared__ float s_b[128];
    const int bt = blockIdx.x, tid = threadIdx.x;
#pragma unroll
    for (int it = 0; it < 8; ++it) {
        int g = it * 512 + tid;
        *(int4*)(&s_ft[(g >> 5) * 264 + (g & 31) * 8]) = *(const int4*)(ft + (size_t)bt * 32768 + g * 8);
    }
#pragma unroll
    for (int it = 0; it < 4; ++it) {
        int g = it * 512 + tid;
        *(int4*)(&s_w[(g >> 4) * 136 + (g & 15) * 8]) = *(const int4*)(w2t + g * 8);
    }
    *(int4*)(s_bm + tid * 16) = *(const int4*)(gbm + (size_t)bt * 8192 + tid * 16);
    if (tid < 64) *(float4*)(&s_dinv[tid * 4]) = *(const float4*)(gdinv + bt * 256 + tid * 4);
    if (tid < 32) *(float4*)(&s_b[tid * 4]) = *(const float4*)(b1 + tid * 4);
    __syncthreads();

    const int w = tid >> 6, l = tid & 63, li = l & 15, lg = l >> 4;
    f32x4 acc[2][8];
#pragma unroll
    for (int a = 0; a < 2; ++a)
#pragma unroll
        for (int c = 0; c < 8; ++c) acc[a][c] = (f32x4){0.f, 0.f, 0.f, 0.f};

#pragma unroll
    for (int ks = 0; ks < 8; ++ks) {
        bf16x8 a0 = expand_bits(s_bm[(32 * w + li) * 32 + 4 * ks + lg]);
        bf16x8 a1 = expand_bits(s_bm[(32 * w + 16 + li) * 32 + 4 * ks + lg]);
#pragma unroll
        for (int ct = 0; ct < 8; ++ct) {
            bf16x8 bv = *(const bf16x8*)(&s_ft[(16 * ct + li) * 264 + lg * 8 + ks * 32]);
            acc[0][ct] = MFMA16(a0, bv, acc[0][ct]);
            acc[1][ct] = MFMA16(a1, bv, acc[1][ct]);
        }
    }
    __syncthreads();   // all XWT reads done; reuse region as h1
#pragma unroll
    for (int rt = 0; rt < 2; ++rt) {
        int i0 = 32 * w + 16 * rt + 4 * lg;
        f32x4 dv = *(const f32x4*)(&s_dinv[i0]);
#pragma unroll
        for (int ct = 0; ct < 8; ++ct) {
            int h = 16 * ct + li;
            float bb = s_b[h];
#pragma unroll
            for (int r = 0; r < 4; ++r)
                s_ft[(i0 + r) * 136 + h] = f2bf(fmaxf(acc[rt][ct][r] * dv[r] + bb, 0.f));
        }
    }
    __syncthreads();
    // gemm2: h1 @ W2  (K=128)
#pragma unroll
    for (int a = 0; a < 2; ++a)
#pragma unroll
        for (int c = 0; c < 8; ++c) acc[a][c] = (f32x4){0.f, 0.f, 0.f, 0.f};
#pragma unroll
    for (int ks = 0; ks < 4; ++ks) {
        bf16x8 a0 = *(const bf16x8*)(&s_ft[(32 * w + li) * 136 + lg * 8 + ks * 32]);
        bf16x8 a1 = *(const bf16x8*)(&s_ft[(32 * w + 16 + li) * 136 + lg * 8 + ks * 32]);
#pragma unroll
        for (int ct = 0; ct < 8; ++ct) {
            bf16x8 bv = *(const bf16x8*)(&s_w[(16 * ct + li) * 136 + lg * 8 + ks * 32]);
            acc[0][ct] = MFMA16(a0, bv, acc[0][ct]);
            acc[1][ct] = MFMA16(a1, bv, acc[1][ct]);
        }
    }
#pragma unroll
    for (int rt = 0; rt < 2; ++rt) {
        int m0 = 32 * w + 16 * rt + 4 * lg;
        f32x4 dv = *(const f32x4*)(&s_dinv[m0]);
#pragma unroll
        for (int ct = 0; ct < 8; ++ct) {
            int h = 16 * ct + li;
            f32x4 v = acc[rt][ct];
            unsigned p0 = (unsigned)f2bf(v[0] * dv[0]) | ((unsigned)f2bf(v[1] * dv[1]) << 16);
            unsigned p1 = (unsigned)f2bf(v[2] * dv[2]) | ((unsigned)f2bf(v[3] * dv[3]) << 16);
            uint2 pk; pk.x = p0; pk.y = p1;
            *(uint2*)(ft + ((size_t)bt * H_ + h) * N_ + m0) = pk;
        }
    }
}

// ---------------- gcn_c: h2 = relu(norm@H1W + b2); emb = mean_n(h2) ----------------
__global__ __launch_bounds__(512, 2) void k_gcn_c(
    const unsigned short* __restrict__ ft, const unsigned char* __restrict__ gbm,
    const float* __restrict__ gdinv, const float* __restrict__ b2,
    float* __restrict__ emb) {
    __shared__ unsigned short s_ft[128 * 264];
    __shared__ unsigned char s_bm[8192];
    __shared__ float s_dinv[256];
    __shared__ float s_b[128];
    __shared__ float s_pool[8 * 128];
    const int bt = blockIdx.x, tid = threadIdx.x;
#pragma unroll
    for (int it = 0; it < 8; ++it) {
        int g = it * 512 + tid;
        *(int4*)(&s_ft[(g >> 5) * 264 + (g & 31) * 8]) = *(const int4*)(ft + (size_t)bt * 32768 + g * 8);
    }
    *(int4*)(s_bm + tid * 16) = *(const int4*)(gbm + (size_t)bt * 8192 + tid * 16);
    if (tid < 64) *(float4*)(&s_dinv[tid * 4]) = *(const float4*)(gdinv + bt * 256 + tid * 4);
    if (tid < 32) *(float4*)(&s_b[tid * 4]) = *(const float4*)(b2 + tid * 4);
    __syncthreads();

    const int w = tid >> 6, l = tid & 63, li = l & 15, lg = l >> 4;
    f32x4 acc[2][8];
#pragma unroll
    for (int a = 0; a < 2; ++a)
#pragma unroll
        for (int c = 0; c < 8; ++c) acc[a][c] = (f32x4){0.f, 0.f, 0.f, 0.f};
#pragma unroll
    for (int ks = 0; ks < 8; ++ks) {
        bf16x8 a0 = expand_bits(s_bm[(32 * w + li) * 32 + 4 * ks + lg]);
        bf16x8 a1 = expand_bits(s_bm[(32 * w + 16 + li) * 32 + 4 * ks + lg]);
#pragma unroll
        for (int ct = 0; ct < 8; ++ct) {
            bf16x8 bv = *(const bf16x8*)(&s_ft[(16 * ct + li) * 264 + lg * 8 + ks * 32]);
            acc[0][ct] = MFMA16(a0, bv, acc[0][ct]);
            acc[1][ct] = MFMA16(a1, bv, acc[1][ct]);
        }
    }
    int i0a = 32 * w + 4 * lg;
    f32x4 dv0 = *(const f32x4*)(&s_dinv[i0a]);
    f32x4 dv1 = *(const f32x4*)(&s_dinv[i0a + 16]);
#pragma unroll
    for (int ct = 0; ct < 8; ++ct) {
        int h = 16 * ct + li;
        float bb = s_b[h];
        float s = 0.f;
#pragma unroll
        for (int r = 0; r < 4; ++r) {
            s += fmaxf(acc[0][ct][r] * dv0[r] + bb, 0.f);
            s += fmaxf(acc[1][ct][r] * dv1[r] + bb, 0.f);
        }
        s += __shfl_xor(s, 16);
        s += __shfl_xor(s, 32);
        if (lg == 0) s_pool[w * 128 + h] = s;
    }
    __syncthreads();
    if (tid < 128) {
        float e = 0.f;
#pragma unroll
        for (int ww = 0; ww < 8; ++ww) e += s_pool[ww * 128 + tid];
        emb[(size_t)bt * 128 + tid] = e * (1.f / 256.f);
    }
}

// ---------------- xg = emb @ Wih0^T + bih0 + bhh0   (layout [t][b][1024]) ----------------
__global__ __launch_bounds__(256, 2) void k_xg(
    const float* __restrict__ emb, const float* __restrict__ Wih0,
    const float* __restrict__ bih0, const float* __restrict__ bhh0,
    float* __restrict__ xg) {
    __shared__ float s_e[8][128];
    const int bk = blockIdx.x, tid = threadIdx.x;
    for (int q = 0; q < 4; ++q) {
        int idx = q * 256 + tid;
        int p = idx >> 7, k = idx & 127;
        int tb2 = bk * 8 + p;
        int t = tb2 >> 4, b = tb2 & 15;
        s_e[p][k] = emb[(size_t)(b * T_ + t) * 128 + k];
    }
    __syncthreads();
    for (int cc = 0; cc < 4; ++cc) {
        int col = cc * 256 + tid;
        float bias = bih0[col] + bhh0[col];
        const float4* wr = (const float4*)(Wih0 + (size_t)col * 128);
        float accv[8] = {0, 0, 0, 0, 0, 0, 0, 0};
        for (int k4 = 0; k4 < 32; ++k4) {
            float4 wv = wr[k4];
#pragma unroll
            for (int p = 0; p < 8; ++p) {
                float4 ev = *(const float4*)(&s_e[p][k4 * 4]);
                accv[p] += wv.x * ev.x + wv.y * ev.y + wv.z * ev.z + wv.w * ev.w;
            }
        }
#pragma unroll
        for (int p = 0; p < 8; ++p) {
            int tb2 = bk * 8 + p;
            xg[(size_t)tb2 * 1024 + col] = accv[p] + bias;
        }
    }
}

// ---------------- dataflow LSTM: 8 L0 blocks + 16 L1 blocks, data-as-flag ----------------
// h0w/h1w: [32 t][16 b][128 jpair] u64 {lo: 2x bf16, hi: epoch=t+1}. Write-once, no
// overwrites -> no backpressure, no flags, no vmcnt drains. Consumers poll epochs.
// L0@t stages h0[t-1] (epoch t); L1@t stages h0[t] (epoch t+1) + h1[t-1] (epoch t).
__global__ __launch_bounds__(512, 1) void k_lstm(
    const float* __restrict__ xg, const float* __restrict__ Whh0,
    const float* __restrict__ Wih1, const float* __restrict__ Whh1,
    const float* __restrict__ bih1, const float* __restrict__ bhh1,
    const float* __restrict__ Wfc, const float* __restrict__ bfc,
    unsigned long long* h0w, unsigned long long* h1w, float* __restrict__ out) {
    __shared__ __align__(16) char arena[91456];
    const int wg = blockIdx.x, tid = threadIdx.x;
    const int lane = tid & 63;

    if (wg < 8) {
        // ================= LAYER 0 =================
        unsigned short* s_w = (unsigned short*)arena;            // [128][258] bf16
        unsigned short* s_h = (unsigned short*)(arena + 66048);  // [16][258] bf16
        float* s_gate = (float*)(arena + 74304);                 // [128][18] f32
        const int j0 = wg * 32;

        // stage Whh0 slice -> LDS bf16 (once)
#pragma unroll
        for (int it = 0; it < 16; ++it) {
            int e4 = tid + it * 512;
            int rl = e4 >> 6, k0 = (e4 & 63) * 4;
            int rg = (rl >> 5) * 256 + j0 + (rl & 31);
            float4 v = *(const float4*)(Whh0 + (size_t)rg * 256 + k0);
            uint2 pk;
            pk.x = (unsigned)f2bf(v.x) | ((unsigned)f2bf(v.y) << 16);
            pk.y = (unsigned)f2bf(v.z) | ((unsigned)f2bf(v.w) << 16);
            *(uint2*)(s_w + rl * 258 + k0) = pk;
        }
        __syncthreads();

        const int w = tid >> 6, li = lane & 15, lg = lane >> 4;
        const int cb = tid >> 5, cj = tid & 31;        // c-thread: (batch, j-local)
        float c_reg = 0.f;

        for (int t = 0; t < 32; ++t) {
            // prefetch xg gates (stable data, regular cached loads)
            float xgv[4];
#pragma unroll
            for (int g = 0; g < 4; ++g)
                xgv[g] = xg[(size_t)(t * 16 + cb) * 1024 + g * 256 + j0 + cj];
            if (t > 0) {
                // stage h0[t-1]: poll 2048 epoch-tagged u64 words (4/thread)
                const unsigned long long* src = h0w + (size_t)(t - 1) * 2048;
#pragma unroll
                for (int q = 0; q < 4; ++q) {
                    int wd = tid + q * 512;
                    int b = wd >> 7, jp = wd & 127;
                    unsigned lo = poll_u64(src + wd, (unsigned)t);
                    *(unsigned*)(s_h + b * 258 + jp * 2) = lo;
                }
            }
            __syncthreads();
            if (t > 0) {
                // MFMA: wave w owns N-tile rows [16w,16w+16), K=256
                f32x4 acc = (f32x4){0.f, 0.f, 0.f, 0.f};
#pragma unroll
                for (int ks = 0; ks < 8; ++ks) {
                    bf16x8 af = *(const bf16x8*)(s_h + li * 258 + lg * 8 + ks * 32);
                    bf16x8 bf = *(const bf16x8*)(s_w + (16 * w + li) * 258 + lg * 8 + ks * 32);
                    acc = MFMA16(af, bf, acc);
                }
                int base = (16 * w + li) * 18 + 4 * lg;
                *(f32x2*)(s_gate + base) = (f32x2){acc[0], acc[1]};
                *(f32x2*)(s_gate + base + 2) = (f32x2){acc[2], acc[3]};
            }
            __syncthreads();
            // c/h update: thread (cb, cj); publish epoch-tagged pair
            {
                float gi = xgv[0], gf = xgv[1], gg = xgv[2], go = xgv[3];
                if (t > 0) {
                    gi += s_gate[(0 * 32 + cj) * 18 + cb];
                    gf += s_gate[(1 * 32 + cj) * 18 + cb];
                    gg += s_gate[(2 * 32 + cj) * 18 + cb];
                    go += s_gate[(3 * 32 + cj) * 18 + cb];
                }
                c_reg = sigf(gf) * c_reg + sigf(gi) * tanhf_(gg);
                float h = sigf(go) * tanhf_(c_reg);
                unsigned hu = f2bf(h);
                unsigned other = __shfl_xor(hu, 1);
                if ((cj & 1) == 0) {
                    unsigned long long v = (unsigned long long)(hu | (other << 16))
                                         | ((unsigned long long)(t + 1) << 32);
                    st_u64(h0w + (size_t)t * 2048 + cb * 128 + ((j0 + cj) >> 1), v);
                }
            }
        }
    } else {
        // ================= LAYER 1 =================
        unsigned short* s_w = (unsigned short*)arena;            // [64][514] bf16
        unsigned short* s_h = (unsigned short*)(arena + 65792);  // [16][514] bf16
        float* s_gate = (float*)(arena + 82240);                 // [2][64][18] f32
        const int bi = wg - 8;
        const int j0 = bi * 16;

        // stage [Wih1 | Whh1] slice -> LDS bf16 (once)
#pragma unroll
        for (int it = 0; it < 16; ++it) {
            int e4 = tid + it * 512;
            int rl = e4 >> 7, k0 = (e4 & 127) * 4;
            int rg = (rl >> 4) * 256 + j0 + (rl & 15);
            const float* src = (k0 < 256) ? (Wih1 + (size_t)rg * 256 + k0)
                                          : (Whh1 + (size_t)rg * 256 + (k0 - 256));
            float4 v = *(const float4*)src;
            uint2 pk;
            pk.x = (unsigned)f2bf(v.x) | ((unsigned)f2bf(v.y) << 16);
            pk.y = (unsigned)f2bf(v.z) | ((unsigned)f2bf(v.w) << 16);
            *(uint2*)(s_w + rl * 514 + k0) = pk;
        }

        const int w = tid >> 6, li = lane & 15, lg = lane >> 4;
        const int ct = w & 3, kh = w >> 2;
        const int cb = tid >> 4, cj = tid & 15;       // c-thread (tid<256): (batch, j-local)
        float bias[4];
        if (tid < 256) {
#pragma unroll
            for (int g = 0; g < 4; ++g) {
                int r = g * 256 + j0 + cj;
                bias[g] = bih1[r] + bhh1[r];
            }
        }
        __syncthreads();
        float c_reg = 0.f;

        for (int t = 0; t < 32; ++t) {
            // stage A = [h0[t] | h1[t-1]]: poll 4096 u64 words (8/thread)
            const unsigned long long* s0 = h0w + (size_t)t * 2048;
            const unsigned long long* s1 = h1w + (size_t)(t - 1) * 2048;
#pragma unroll
            for (int q = 0; q < 8; ++q) {
                int wd = tid + q * 512;
                int half = wd >> 11, w2 = wd & 2047;
                int b = w2 >> 7, jp = w2 & 127;
                unsigned lo;
                if (half == 0) lo = poll_u64(s0 + w2, (unsigned)(t + 1));
                else lo = (t > 0) ? poll_u64(s1 + w2, (unsigned)t) : 0u;
                *(unsigned*)(s_h + b * 514 + half * 256 + jp * 2) = lo;
            }
            __syncthreads();
            {
                // MFMA: wave (ct,kh): N-tile rows [16ct,16ct+16), K-half kh
                f32x4 acc = (f32x4){0.f, 0.f, 0.f, 0.f};
#pragma unroll
                for (int ks = 0; ks < 8; ++ks) {
                    int ko = (kh * 8 + ks) * 32;
                    bf16x8 af = *(const bf16x8*)(s_h + li * 514 + lg * 8 + ko);
                    bf16x8 bf = *(const bf16x8*)(s_w + (16 * ct + li) * 514 + lg * 8 + ko);
                    acc = MFMA16(af, bf, acc);
                }
                int base = kh * 1152 + (16 * ct + li) * 18 + 4 * lg;
                *(f32x2*)(s_gate + base) = (f32x2){acc[0], acc[1]};
                *(f32x2*)(s_gate + base + 2) = (f32x2){acc[2], acc[3]};
            }
            __syncthreads();
            if (tid < 256) {
                float gt[4];
#pragma unroll
                for (int g = 0; g < 4; ++g) {
                    int base = (g * 16 + cj) * 18 + cb;
                    gt[g] = s_gate[base] + s_gate[1152 + base] + bias[g];
                }
                c_reg = sigf(gt[1]) * c_reg + sigf(gt[0]) * tanhf_(gt[2]);
                float h = sigf(gt[3]) * tanhf_(c_reg);
                unsigned hu = f2bf(h);
                unsigned other = __shfl_xor(hu, 1);
                if ((cj & 1) == 0) {
                    unsigned long long v = (unsigned long long)(hu | (other << 16))
                                         | ((unsigned long long)(t + 1) << 32);
                    st_u64(h1w + (size_t)t * 2048 + cb * 128 + ((j0 + cj) >> 1), v);
                }
            }
        }

        if (bi == 0) {
            // FC + sigmoid on h1[31] (poll epoch 32 per word)
            float* s_red = s_gate;
            if (tid < 256) {
                int b = tid >> 4, kc = tid & 15;
                const unsigned long long* hw = h1w + (size_t)31 * 2048 + b * 128 + kc * 8;
                float s = 0.f;
#pragma unroll
                for (int q = 0; q < 8; ++q) {
                    unsigned u = poll_u64(hw + q, 32u);
                    s += Wfc[kc * 16 + 2 * q] * bf2f((unsigned short)(u & 0xffff));
                    s += Wfc[kc * 16 + 2 * q + 1] * bf2f((unsigned short)(u >> 16));
                }
                s_red[tid] = s;
            }
            __syncthreads();
            if (tid < 16) {
                float s = bfc[0];
#pragma unroll
                for (int q = 0; q < 16; ++q) s += s_red[tid * 16 + q];
                out[tid] = sigf(s);
            }
        }
    }
}

extern "C" void kernel_launch(void* const* d_in, const int* in_sizes, int n_in,
                              void* d_out, int out_size, void* d_ws, size_t ws_size,
                              hipStream_t stream) {
    const int*   adj  = (const int*)  d_in[0];
    const float* x    = (const float*)d_in[1];
    const float* W1   = (const float*)d_in[2];
    const float* b1   = (const float*)d_in[3];
    const float* W2   = (const float*)d_in[4];
    const float* b2   = (const float*)d_in[5];
    const float* Wih0 = (const float*)d_in[6];
    const float* Whh0 = (const float*)d_in[7];
    const float* bih0 = (const float*)d_in[8];
    const float* bhh0 = (const float*)d_in[9];
    const float* Wih1 = (const float*)d_in[10];
    const float* Whh1 = (const float*)d_in[11];
    const float* bih1 = (const float*)d_in[12];
    const float* bhh1 = (const float*)d_in[13];
    const float* Wfc  = (const float*)d_in[14];
    const float* bfc  = (const float*)d_in[15];
    float* out = (float*)d_out;

    if (ws_size < 40764416) return;   // ~40.8 MB scratch

    char* ws = (char*)d_ws;
    unsigned short* ft    = (unsigned short*)(ws);              // 33,554,432 B
    unsigned char*  gbm   = (unsigned char*)(ws + 33554432);    //  4,194,304 B (dead after gcn_c)
    float*          gdinv = (float*)(ws + 37748736);            //    524,288 B
    float*          emb   = (float*)(ws + 38273024);            //    262,144 B
    unsigned short* w1t   = (unsigned short*)(ws + 38535168);   //     32,768 B
    unsigned short* w2t   = (unsigned short*)(ws + 38567936);   //     32,768 B
    float*          xg    = (float*)(ws + 38600704);            //  2,097,152 B
    // h-buffers overlay the gbm region (gbm is consumed before k_lstm runs)
    unsigned long long* h0w = (unsigned long long*)(ws + 33554432);  // 524,288 B
    unsigned long long* h1w = (unsigned long long*)(ws + 34078720);  // 524,288 B

    k_prep<<<64, 256, 0, stream>>>(W1, W2, w1t, w2t);
    k_gcn_a<<<512, 512, 0, stream>>>(adj, x, w1t, ft, gbm, gdinv);
    k_gcn_b<<<512, 512, 0, stream>>>(ft, gbm, gdinv, b1, w2t);
    k_gcn_c<<<512, 512, 0, stream>>>(ft, gbm, gdinv, b2, emb);
    // zero the epoch tags (stream-ordered after gcn_c's last gbm read)
    hipMemsetAsync(ws + 33554432, 0, 1048576, stream);
    k_xg<<<64, 256, 0, stream>>>(emb, Wih0, bih0, bhh0, xg);

    void* args[11];
    args[0] = (void*)&xg;
    args[1] = (void*)&Whh0;
    args[2] = (void*)&Wih1;
    args[3] = (void*)&Whh1;
    args[4] = (void*)&bih1;
    args[5] = (void*)&bhh1;
    args[6] = (void*)&Wfc;
    args[7] = (void*)&bfc;
    args[8] = (void*)&h0w;
    args[9] = (void*)&h1w;
    args[10] = (void*)&out;
    hipLaunchCooperativeKernel((const void*)k_lstm, dim3(24), dim3(512), args, 0, stream);
}

// Round 6
// 330.212 us; speedup vs baseline: 3.6288x; 1.0712x over previous
//
#include <hip/hip_runtime.h>
#include <hip/hip_bf16.h>

#define B_ 16
#define T_ 32
#define N_ 256
#define F_ 128
#define H_ 128
#define HL_ 256

typedef float f32x4 __attribute__((ext_vector_type(4)));
typedef float f32x2 __attribute__((ext_vector_type(2)));
typedef short bf16x8 __attribute__((ext_vector_type(8)));

#define MFMA16(A, Bv, C) __builtin_amdgcn_mfma_f32_16x16x32_bf16((A), (Bv), (C), 0, 0, 0)

__device__ __forceinline__ unsigned short f2bf(float f) {
    unsigned u = __builtin_bit_cast(unsigned, f);
    return (unsigned short)((u + 0x7FFFu + ((u >> 16) & 1u)) >> 16);
}
__device__ __forceinline__ float bf2f(unsigned short s) {
    unsigned u = ((unsigned)s) << 16;
    return __builtin_bit_cast(float, u);
}

__device__ __forceinline__ bf16x8 cvt8(const float* p) {
    f32x4 a = *(const f32x4*)p;
    f32x4 b = *(const f32x4*)(p + 4);
    bf16x8 r;
    r[0] = (short)f2bf(a[0]); r[1] = (short)f2bf(a[1]);
    r[2] = (short)f2bf(a[2]); r[3] = (short)f2bf(a[3]);
    r[4] = (short)f2bf(b[0]); r[5] = (short)f2bf(b[1]);
    r[6] = (short)f2bf(b[2]); r[7] = (short)f2bf(b[3]);
    return r;
}

__device__ __forceinline__ bf16x8 expand_bits(unsigned b) {
    bf16x8 r;
#pragma unroll
    for (int j = 0; j < 8; ++j) r[j] = (short)(((b >> j) & 1u) ? 0x3F80 : 0);
    return r;
}

__device__ __forceinline__ float sigf(float x) { return 1.f / (1.f + __expf(-x)); }
__device__ __forceinline__ float tanhf_(float x) { float e = __expf(2.f * x); return 1.f - 2.f / (e + 1.f); }

// epoch-tagged h word: lo = 2x bf16 payload, hi = epoch (t+1). Single 8B sc1 op.
__device__ __forceinline__ unsigned long long ld_u64(const unsigned long long* p) {
    return __hip_atomic_load(p, __ATOMIC_RELAXED, __HIP_MEMORY_SCOPE_AGENT);
}
__device__ __forceinline__ void st_u64(unsigned long long* p, unsigned long long v) {
    __hip_atomic_store(p, v, __ATOMIC_RELAXED, __HIP_MEMORY_SCOPE_AGENT);
}

// ---------------- weight prep: W1^T, W2^T in bf16 ----------------
__global__ void k_prep(const float* __restrict__ W1, const float* __restrict__ W2,
                       unsigned short* __restrict__ w1t, unsigned short* __restrict__ w2t) {
    int idx = blockIdx.x * 256 + threadIdx.x;   // 64 blocks * 256 = 16384
    int h = idx >> 7, f = idx & 127;
    w1t[idx] = f2bf(W1[f * 128 + h]);
    w2t[idx] = f2bf(W2[f * 128 + h]);
}

// ---------------- gcn_a: bitmask+dinv from adj, XWT' = dinv .* (x@W1)^T bf16 ----------------
__global__ __launch_bounds__(512, 2) void k_gcn_a(
    const int* __restrict__ adj, const float* __restrict__ x,
    const unsigned short* __restrict__ w1t,
    unsigned short* __restrict__ ft, unsigned char* __restrict__ gbm,
    float* __restrict__ gdinv) {
    __shared__ unsigned char s_bm[256 * 32];
    __shared__ float s_dinv[256];
    __shared__ unsigned short s_w[128 * 136];
    const int bt = blockIdx.x;
    const int tid = threadIdx.x;
    const int* adjb = adj + (size_t)bt * (N_ * N_);

    for (int it = 0; it < 16; ++it) {
        int row = it * 16 + (tid >> 5);
        int c = tid & 31, m0 = c * 8;
        const int* p = adjb + row * N_ + m0;
        int4 q0 = *(const int4*)p;
        int4 q1 = *(const int4*)(p + 4);
        unsigned by = 0;
        by |= (((q0.x != 0) | (m0 + 0 == row)) ? 1u : 0u);
        by |= (((q0.y != 0) | (m0 + 1 == row)) ? 2u : 0u);
        by |= (((q0.z != 0) | (m0 + 2 == row)) ? 4u : 0u);
        by |= (((q0.w != 0) | (m0 + 3 == row)) ? 8u : 0u);
        by |= (((q1.x != 0) | (m0 + 4 == row)) ? 16u : 0u);
        by |= (((q1.y != 0) | (m0 + 5 == row)) ? 32u : 0u);
        by |= (((q1.z != 0) | (m0 + 6 == row)) ? 64u : 0u);
        by |= (((q1.w != 0) | (m0 + 7 == row)) ? 128u : 0u);
        s_bm[row * 32 + c] = (unsigned char)by;
        int pc = __popc(by);
        pc += __shfl_xor(pc, 1); pc += __shfl_xor(pc, 2); pc += __shfl_xor(pc, 4);
        pc += __shfl_xor(pc, 8); pc += __shfl_xor(pc, 16);
        if (c == 0) s_dinv[row] = rsqrtf((float)pc);
    }
    for (int it = 0; it < 4; ++it) {
        int g = it * 512 + tid;
        *(int4*)(&s_w[(g >> 4) * 136 + (g & 15) * 8]) = *(const int4*)(w1t + g * 8);
    }
    __syncthreads();
    *(int4*)(gbm + (size_t)bt * 8192 + tid * 16) = *(const int4*)(s_bm + tid * 16);
    if (tid < 64) *(float4*)(gdinv + bt * 256 + tid * 4) = *(const float4*)(s_dinv + tid * 4);

    const int w = tid >> 6, l = tid & 63, li = l & 15, lg = l >> 4;
    const float* xb = x + (size_t)bt * (N_ * F_);
    f32x4 acc[2][8];
#pragma unroll
    for (int a = 0; a < 2; ++a)
#pragma unroll
        for (int c = 0; c < 8; ++c) acc[a][c] = (f32x4){0.f, 0.f, 0.f, 0.f};

#pragma unroll
    for (int ks = 0; ks < 4; ++ks) {
        bf16x8 a0 = cvt8(xb + (size_t)(32 * w + li) * F_ + lg * 8 + ks * 32);
        bf16x8 a1 = cvt8(xb + (size_t)(32 * w + 16 + li) * F_ + lg * 8 + ks * 32);
#pragma unroll
        for (int ct = 0; ct < 8; ++ct) {
            bf16x8 bv = *(const bf16x8*)(&s_w[(16 * ct + li) * 136 + lg * 8 + ks * 32]);
            acc[0][ct] = MFMA16(a0, bv, acc[0][ct]);
            acc[1][ct] = MFMA16(a1, bv, acc[1][ct]);
        }
    }
#pragma unroll
    for (int rt = 0; rt < 2; ++rt) {
        int m0 = 32 * w + 16 * rt + 4 * lg;
        f32x4 dv = *(const f32x4*)(&s_dinv[m0]);
#pragma unroll
        for (int ct = 0; ct < 8; ++ct) {
            int h = 16 * ct + li;
            f32x4 v = acc[rt][ct];
            unsigned p0 = (unsigned)f2bf(v[0] * dv[0]) | ((unsigned)f2bf(v[1] * dv[1]) << 16);
            unsigned p1 = (unsigned)f2bf(v[2] * dv[2]) | ((unsigned)f2bf(v[3] * dv[3]) << 16);
            uint2 pk; pk.x = p0; pk.y = p1;
            *(uint2*)(ft + ((size_t)bt * H_ + h) * N_ + m0) = pk;
        }
    }
}

// ---------------- gcn_b: h1 = relu(norm@XW + b1); FT <- dinv .* (h1@W2)^T ----------------
__global__ __launch_bounds__(512, 2) void k_gcn_b(
    unsigned short* ft,
    const unsigned char* __restrict__ gbm, const float* __restrict__ gdinv,
    const float* __restrict__ b1, const unsigned short* __restrict__ w2t) {
    __shared__ unsigned short s_ft[256 * 136];   // XWT [128][264] then h1 [256][136]
    __shared__ unsigned short s_w[128 * 136];
    __shared__ unsigned char s_bm[8192];
    __shared__ float s_dinv[256];
    __shared__ float s_b[128];
    const int bt = blockIdx.x, tid = threadIdx.x;
#pragma unroll
    for (int it = 0; it < 8; ++it) {
        int g = it * 512 + tid;
        *(int4*)(&s_ft[(g >> 5) * 264 + (g & 31) * 8]) = *(const int4*)(ft + (size_t)bt * 32768 + g * 8);
    }
#pragma unroll
    for (int it = 0; it < 4; ++it) {
        int g = it * 512 + tid;
        *(int4*)(&s_w[(g >> 4) * 136 + (g & 15) * 8]) = *(const int4*)(w2t + g * 8);
    }
    *(int4*)(s_bm + tid * 16) = *(const int4*)(gbm + (size_t)bt * 8192 + tid * 16);
    if (tid < 64) *(float4*)(&s_dinv[tid * 4]) = *(const float4*)(gdinv + bt * 256 + tid * 4);
    if (tid < 32) *(float4*)(&s_b[tid * 4]) = *(const float4*)(b1 + tid * 4);
    __syncthreads();

    const int w = tid >> 6, l = tid & 63, li = l & 15, lg = l >> 4;
    f32x4 acc[2][8];
#pragma unroll
    for (int a = 0; a < 2; ++a)
#pragma unroll
        for (int c = 0; c < 8; ++c) acc[a][c] = (f32x4){0.f, 0.f, 0.f, 0.f};

#pragma unroll
    for (int ks = 0; ks < 8; ++ks) {
        bf16x8 a0 = expand_bits(s_bm[(32 * w + li) * 32 + 4 * ks + lg]);
        bf16x8 a1 = expand_bits(s_bm[(32 * w + 16 + li) * 32 + 4 * ks + lg]);
#pragma unroll
        for (int ct = 0; ct < 8; ++ct) {
            bf16x8 bv = *(const bf16x8*)(&s_ft[(16 * ct + li) * 264 + lg * 8 + ks * 32]);
            acc[0][ct] = MFMA16(a0, bv, acc[0][ct]);
            acc[1][ct] = MFMA16(a1, bv, acc[1][ct]);
        }
    }
    __syncthreads();   // all XWT reads done; reuse region as h1
#pragma unroll
    for (int rt = 0; rt < 2; ++rt) {
        int i0 = 32 * w + 16 * rt + 4 * lg;
        f32x4 dv = *(const f32x4*)(&s_dinv[i0]);
#pragma unroll
        for (int ct = 0; ct < 8; ++ct) {
            int h = 16 * ct + li;
            float bb = s_b[h];
#pragma unroll
            for (int r = 0; r < 4; ++r)
                s_ft[(i0 + r) * 136 + h] = f2bf(fmaxf(acc[rt][ct][r] * dv[r] + bb, 0.f));
        }
    }
    __syncthreads();
    // gemm2: h1 @ W2  (K=128)
#pragma unroll
    for (int a = 0; a < 2; ++a)
#pragma unroll
        for (int c = 0; c < 8; ++c) acc[a][c] = (f32x4){0.f, 0.f, 0.f, 0.f};
#pragma unroll
    for (int ks = 0; ks < 4; ++ks) {
        bf16x8 a0 = *(const bf16x8*)(&s_ft[(32 * w + li) * 136 + lg * 8 + ks * 32]);
        bf16x8 a1 = *(const bf16x8*)(&s_ft[(32 * w + 16 + li) * 136 + lg * 8 + ks * 32]);
#pragma unroll
        for (int ct = 0; ct < 8; ++ct) {
            bf16x8 bv = *(const bf16x8*)(&s_w[(16 * ct + li) * 136 + lg * 8 + ks * 32]);
            acc[0][ct] = MFMA16(a0, bv, acc[0][ct]);
            acc[1][ct] = MFMA16(a1, bv, acc[1][ct]);
        }
    }
#pragma unroll
    for (int rt = 0; rt < 2; ++rt) {
        int m0 = 32 * w + 16 * rt + 4 * lg;
        f32x4 dv = *(const f32x4*)(&s_dinv[m0]);
#pragma unroll
        for (int ct = 0; ct < 8; ++ct) {
            int h = 16 * ct + li;
            f32x4 v = acc[rt][ct];
            unsigned p0 = (unsigned)f2bf(v[0] * dv[0]) | ((unsigned)f2bf(v[1] * dv[1]) << 16);
            unsigned p1 = (unsigned)f2bf(v[2] * dv[2]) | ((unsigned)f2bf(v[3] * dv[3]) << 16);
            uint2 pk; pk.x = p0; pk.y = p1;
            *(uint2*)(ft + ((size_t)bt * H_ + h) * N_ + m0) = pk;
        }
    }
}

// ---------------- gcn_c: h2 = relu(norm@H1W + b2); emb = mean_n(h2) ----------------
__global__ __launch_bounds__(512, 2) void k_gcn_c(
    const unsigned short* __restrict__ ft, const unsigned char* __restrict__ gbm,
    const float* __restrict__ gdinv, const float* __restrict__ b2,
    float* __restrict__ emb) {
    __shared__ unsigned short s_ft[128 * 264];
    __shared__ unsigned char s_bm[8192];
    __shared__ float s_dinv[256];
    __shared__ float s_b[128];
    __shared__ float s_pool[8 * 128];
    const int bt = blockIdx.x, tid = threadIdx.x;
#pragma unroll
    for (int it = 0; it < 8; ++it) {
        int g = it * 512 + tid;
        *(int4*)(&s_ft[(g >> 5) * 264 + (g & 31) * 8]) = *(const int4*)(ft + (size_t)bt * 32768 + g * 8);
    }
    *(int4*)(s_bm + tid * 16) = *(const int4*)(gbm + (size_t)bt * 8192 + tid * 16);
    if (tid < 64) *(float4*)(&s_dinv[tid * 4]) = *(const float4*)(gdinv + bt * 256 + tid * 4);
    if (tid < 32) *(float4*)(&s_b[tid * 4]) = *(const float4*)(b2 + tid * 4);
    __syncthreads();

    const int w = tid >> 6, l = tid & 63, li = l & 15, lg = l >> 4;
    f32x4 acc[2][8];
#pragma unroll
    for (int a = 0; a < 2; ++a)
#pragma unroll
        for (int c = 0; c < 8; ++c) acc[a][c] = (f32x4){0.f, 0.f, 0.f, 0.f};
#pragma unroll
    for (int ks = 0; ks < 8; ++ks) {
        bf16x8 a0 = expand_bits(s_bm[(32 * w + li) * 32 + 4 * ks + lg]);
        bf16x8 a1 = expand_bits(s_bm[(32 * w + 16 + li) * 32 + 4 * ks + lg]);
#pragma unroll
        for (int ct = 0; ct < 8; ++ct) {
            bf16x8 bv = *(const bf16x8*)(&s_ft[(16 * ct + li) * 264 + lg * 8 + ks * 32]);
            acc[0][ct] = MFMA16(a0, bv, acc[0][ct]);
            acc[1][ct] = MFMA16(a1, bv, acc[1][ct]);
        }
    }
    int i0a = 32 * w + 4 * lg;
    f32x4 dv0 = *(const f32x4*)(&s_dinv[i0a]);
    f32x4 dv1 = *(const f32x4*)(&s_dinv[i0a + 16]);
#pragma unroll
    for (int ct = 0; ct < 8; ++ct) {
        int h = 16 * ct + li;
        float bb = s_b[h];
        float s = 0.f;
#pragma unroll
        for (int r = 0; r < 4; ++r) {
            s += fmaxf(acc[0][ct][r] * dv0[r] + bb, 0.f);
            s += fmaxf(acc[1][ct][r] * dv1[r] + bb, 0.f);
        }
        s += __shfl_xor(s, 16);
        s += __shfl_xor(s, 32);
        if (lg == 0) s_pool[w * 128 + h] = s;
    }
    __syncthreads();
    if (tid < 128) {
        float e = 0.f;
#pragma unroll
        for (int ww = 0; ww < 8; ++ww) e += s_pool[ww * 128 + tid];
        emb[(size_t)bt * 128 + tid] = e * (1.f / 256.f);
    }
}

// ---------------- xg = emb @ Wih0^T + bih0 + bhh0   (layout [t][b][1024]) ----------------
__global__ __launch_bounds__(256, 2) void k_xg(
    const float* __restrict__ emb, const float* __restrict__ Wih0,
    const float* __restrict__ bih0, const float* __restrict__ bhh0,
    float* __restrict__ xg) {
    __shared__ float s_e[8][128];
    const int bk = blockIdx.x, tid = threadIdx.x;
    for (int q = 0; q < 4; ++q) {
        int idx = q * 256 + tid;
        int p = idx >> 7, k = idx & 127;
        int tb2 = bk * 8 + p;
        int t = tb2 >> 4, b = tb2 & 15;
        s_e[p][k] = emb[(size_t)(b * T_ + t) * 128 + k];
    }
    __syncthreads();
    for (int cc = 0; cc < 4; ++cc) {
        int col = cc * 256 + tid;
        float bias = bih0[col] + bhh0[col];
        const float4* wr = (const float4*)(Wih0 + (size_t)col * 128);
        float accv[8] = {0, 0, 0, 0, 0, 0, 0, 0};
        for (int k4 = 0; k4 < 32; ++k4) {
            float4 wv = wr[k4];
#pragma unroll
            for (int p = 0; p < 8; ++p) {
                float4 ev = *(const float4*)(&s_e[p][k4 * 4]);
                accv[p] += wv.x * ev.x + wv.y * ev.y + wv.z * ev.z + wv.w * ev.w;
            }
        }
#pragma unroll
        for (int p = 0; p < 8; ++p) {
            int tb2 = bk * 8 + p;
            xg[(size_t)tb2 * 1024 + col] = accv[p] + bias;
        }
    }
}

// ---------------- dataflow LSTM: 8 L0 blocks + 16 L1 blocks, data-as-flag ----------------
// h0w/h1w: [32 t][16 b][128 jpair] u64 {lo: 2x bf16, hi: epoch=t+1}. Write-once.
// BATCHED polls: all words loaded with independent sc1 loads (1 MALL RT for the
// whole batch), epochs checked together; re-load only on mismatch.
__global__ __launch_bounds__(512, 1) void k_lstm(
    const float* __restrict__ xg, const float* __restrict__ Whh0,
    const float* __restrict__ Wih1, const float* __restrict__ Whh1,
    const float* __restrict__ bih1, const float* __restrict__ bhh1,
    const float* __restrict__ Wfc, const float* __restrict__ bfc,
    unsigned long long* h0w, unsigned long long* h1w, float* __restrict__ out) {
    __shared__ __align__(16) char arena[91456];
    const int wg = blockIdx.x, tid = threadIdx.x;
    const int lane = tid & 63;

    if (wg < 8) {
        // ================= LAYER 0 =================
        unsigned short* s_w = (unsigned short*)arena;            // [128][258] bf16
        unsigned short* s_h = (unsigned short*)(arena + 66048);  // [16][258] bf16
        float* s_gate = (float*)(arena + 74304);                 // [128][18] f32
        const int j0 = wg * 32;

        // stage Whh0 slice -> LDS bf16 (once)
#pragma unroll
        for (int it = 0; it < 16; ++it) {
            int e4 = tid + it * 512;
            int rl = e4 >> 6, k0 = (e4 & 63) * 4;
            int rg = (rl >> 5) * 256 + j0 + (rl & 31);
            float4 v = *(const float4*)(Whh0 + (size_t)rg * 256 + k0);
            uint2 pk;
            pk.x = (unsigned)f2bf(v.x) | ((unsigned)f2bf(v.y) << 16);
            pk.y = (unsigned)f2bf(v.z) | ((unsigned)f2bf(v.w) << 16);
            *(uint2*)(s_w + rl * 258 + k0) = pk;
        }
        __syncthreads();

        const int w = tid >> 6, li = lane & 15, lg = lane >> 4;
        const int cb = tid >> 5, cj = tid & 31;        // c-thread: (batch, j-local)
        float c_reg = 0.f;

        for (int t = 0; t < 32; ++t) {
            // prefetch xg gates (stable data, regular cached loads)
            float xgv[4];
#pragma unroll
            for (int g = 0; g < 4; ++g)
                xgv[g] = xg[(size_t)(t * 16 + cb) * 1024 + g * 256 + j0 + cj];
            if (t > 0) {
                // batched poll+stage of h0[t-1] (4 words/thread, 1 RT/round)
                const unsigned long long* src = h0w + (size_t)(t - 1) * 2048;
                unsigned long long v[4];
                const unsigned e = (unsigned)t;
                for (;;) {
#pragma unroll
                    for (int q = 0; q < 4; ++q) v[q] = ld_u64(src + tid + q * 512);
                    bool ok = true;
#pragma unroll
                    for (int q = 0; q < 4; ++q) ok &= ((unsigned)(v[q] >> 32) == e);
                    if (ok) break;
                    __builtin_amdgcn_s_sleep(1);
                }
#pragma unroll
                for (int q = 0; q < 4; ++q) {
                    int wd = tid + q * 512;
                    int b = wd >> 7, jp = wd & 127;
                    *(unsigned*)(s_h + b * 258 + jp * 2) = (unsigned)v[q];
                }
            }
            __syncthreads();
            if (t > 0) {
                // MFMA: wave w owns N-tile rows [16w,16w+16), K=256
                f32x4 acc = (f32x4){0.f, 0.f, 0.f, 0.f};
#pragma unroll
                for (int ks = 0; ks < 8; ++ks) {
                    bf16x8 af = *(const bf16x8*)(s_h + li * 258 + lg * 8 + ks * 32);
                    bf16x8 bf = *(const bf16x8*)(s_w + (16 * w + li) * 258 + lg * 8 + ks * 32);
                    acc = MFMA16(af, bf, acc);
                }
                int base = (16 * w + li) * 18 + 4 * lg;
                *(f32x2*)(s_gate + base) = (f32x2){acc[0], acc[1]};
                *(f32x2*)(s_gate + base + 2) = (f32x2){acc[2], acc[3]};
            }
            __syncthreads();
            // c/h update: thread (cb, cj); publish epoch-tagged pair
            {
                float gi = xgv[0], gf = xgv[1], gg = xgv[2], go = xgv[3];
                if (t > 0) {
                    gi += s_gate[(0 * 32 + cj) * 18 + cb];
                    gf += s_gate[(1 * 32 + cj) * 18 + cb];
                    gg += s_gate[(2 * 32 + cj) * 18 + cb];
                    go += s_gate[(3 * 32 + cj) * 18 + cb];
                }
                c_reg = sigf(gf) * c_reg + sigf(gi) * tanhf_(gg);
                float h = sigf(go) * tanhf_(c_reg);
                unsigned hu = f2bf(h);
                unsigned other = __shfl_xor(hu, 1);
                if ((cj & 1) == 0) {
                    unsigned long long v = (unsigned long long)(hu | (other << 16))
                                         | ((unsigned long long)(t + 1) << 32);
                    st_u64(h0w + (size_t)t * 2048 + cb * 128 + ((j0 + cj) >> 1), v);
                }
            }
        }
    } else {
        // ================= LAYER 1 =================
        unsigned short* s_w = (unsigned short*)arena;            // [64][514] bf16
        unsigned short* s_h = (unsigned short*)(arena + 65792);  // [16][514] bf16
        float* s_gate = (float*)(arena + 82240);                 // [2][64][18] f32
        const int bi = wg - 8;
        const int j0 = bi * 16;

        // stage [Wih1 | Whh1] slice -> LDS bf16 (once)
#pragma unroll
        for (int it = 0; it < 16; ++it) {
            int e4 = tid + it * 512;
            int rl = e4 >> 7, k0 = (e4 & 127) * 4;
            int rg = (rl >> 4) * 256 + j0 + (rl & 15);
            const float* src = (k0 < 256) ? (Wih1 + (size_t)rg * 256 + k0)
                                          : (Whh1 + (size_t)rg * 256 + (k0 - 256));
            float4 v = *(const float4*)src;
            uint2 pk;
            pk.x = (unsigned)f2bf(v.x) | ((unsigned)f2bf(v.y) << 16);
            pk.y = (unsigned)f2bf(v.z) | ((unsigned)f2bf(v.w) << 16);
            *(uint2*)(s_w + rl * 514 + k0) = pk;
        }

        const int w = tid >> 6, li = lane & 15, lg = lane >> 4;
        const int ct = w & 3, kh = w >> 2;
        const int cb = tid >> 4, cj = tid & 15;       // c-thread (tid<256): (batch, j-local)
        float bias[4];
        if (tid < 256) {
#pragma unroll
            for (int g = 0; g < 4; ++g) {
                int r = g * 256 + j0 + cj;
                bias[g] = bih1[r] + bhh1[r];
            }
        }
        __syncthreads();
        float c_reg = 0.f;

        for (int t = 0; t < 32; ++t) {
            // batched poll+stage of [h0[t] | h1[t-1]] (8 words/thread, 1 RT/round)
            const unsigned long long* s0 = h0w + (size_t)t * 2048;
            const unsigned long long* s1 = h1w + (size_t)(t - 1) * 2048;
            unsigned long long v[8];
            const unsigned e0 = (unsigned)(t + 1), e1 = (unsigned)t;
            if (t > 0) {
                for (;;) {
#pragma unroll
                    for (int q = 0; q < 4; ++q) v[q] = ld_u64(s0 + tid + q * 512);
#pragma unroll
                    for (int q = 0; q < 4; ++q) v[4 + q] = ld_u64(s1 + tid + q * 512);
                    bool ok = true;
#pragma unroll
                    for (int q = 0; q < 4; ++q) ok &= ((unsigned)(v[q] >> 32) == e0);
#pragma unroll
                    for (int q = 0; q < 4; ++q) ok &= ((unsigned)(v[4 + q] >> 32) == e1);
                    if (ok) break;
                    __builtin_amdgcn_s_sleep(1);
                }
            } else {
                for (;;) {
#pragma unroll
                    for (int q = 0; q < 4; ++q) v[q] = ld_u64(s0 + tid + q * 512);
                    bool ok = true;
#pragma unroll
                    for (int q = 0; q < 4; ++q) ok &= ((unsigned)(v[q] >> 32) == e0);
                    if (ok) break;
                    __builtin_amdgcn_s_sleep(1);
                }
#pragma unroll
                for (int q = 0; q < 4; ++q) v[4 + q] = 0ull;
            }
#pragma unroll
            for (int q = 0; q < 4; ++q) {
                int wd = tid + q * 512;
                int b = wd >> 7, jp = wd & 127;
                *(unsigned*)(s_h + b * 514 + jp * 2) = (unsigned)v[q];
                *(unsigned*)(s_h + b * 514 + 256 + jp * 2) = (unsigned)v[4 + q];
            }
            __syncthreads();
            {
                // MFMA: wave (ct,kh): N-tile rows [16ct,16ct+16), K-half kh
                f32x4 acc = (f32x4){0.f, 0.f, 0.f, 0.f};
#pragma unroll
                for (int ks = 0; ks < 8; ++ks) {
                    int ko = (kh * 8 + ks) * 32;
                    bf16x8 af = *(const bf16x8*)(s_h + li * 514 + lg * 8 + ko);
                    bf16x8 bf = *(const bf16x8*)(s_w + (16 * ct + li) * 514 + lg * 8 + ko);
                    acc = MFMA16(af, bf, acc);
                }
                int base = kh * 1152 + (16 * ct + li) * 18 + 4 * lg;
                *(f32x2*)(s_gate + base) = (f32x2){acc[0], acc[1]};
                *(f32x2*)(s_gate + base + 2) = (f32x2){acc[2], acc[3]};
            }
            __syncthreads();
            if (tid < 256) {
                float gt[4];
#pragma unroll
                for (int g = 0; g < 4; ++g) {
                    int base = (g * 16 + cj) * 18 + cb;
                    gt[g] = s_gate[base] + s_gate[1152 + base] + bias[g];
                }
                c_reg = sigf(gt[1]) * c_reg + sigf(gt[0]) * tanhf_(gt[2]);
                float h = sigf(gt[3]) * tanhf_(c_reg);
                unsigned hu = f2bf(h);
                unsigned other = __shfl_xor(hu, 1);
                if ((cj & 1) == 0) {
                    unsigned long long v2 = (unsigned long long)(hu | (other << 16))
                                          | ((unsigned long long)(t + 1) << 32);
                    st_u64(h1w + (size_t)t * 2048 + cb * 128 + ((j0 + cj) >> 1), v2);
                }
            }
        }

        if (bi == 0) {
            // FC + sigmoid on h1[31] (batched poll, epoch 32)
            float* s_red = s_gate;
            if (tid < 256) {
                int b = tid >> 4, kc = tid & 15;
                const unsigned long long* hw = h1w + (size_t)31 * 2048 + b * 128 + kc * 8;
                unsigned long long v[8];
                for (;;) {
#pragma unroll
                    for (int q = 0; q < 8; ++q) v[q] = ld_u64(hw + q);
                    bool ok = true;
#pragma unroll
                    for (int q = 0; q < 8; ++q) ok &= ((unsigned)(v[q] >> 32) == 32u);
                    if (ok) break;
                    __builtin_amdgcn_s_sleep(1);
                }
                float s = 0.f;
#pragma unroll
                for (int q = 0; q < 8; ++q) {
                    unsigned u = (unsigned)v[q];
                    s += Wfc[kc * 16 + 2 * q] * bf2f((unsigned short)(u & 0xffff));
                    s += Wfc[kc * 16 + 2 * q + 1] * bf2f((unsigned short)(u >> 16));
                }
                s_red[tid] = s;
            }
            __syncthreads();
            if (tid < 16) {
                float s = bfc[0];
#pragma unroll
                for (int q = 0; q < 16; ++q) s += s_red[tid * 16 + q];
                out[tid] = sigf(s);
            }
        }
    }
}

extern "C" void kernel_launch(void* const* d_in, const int* in_sizes, int n_in,
                              void* d_out, int out_size, void* d_ws, size_t ws_size,
                              hipStream_t stream) {
    const int*   adj  = (const int*)  d_in[0];
    const float* x    = (const float*)d_in[1];
    const float* W1   = (const float*)d_in[2];
    const float* b1   = (const float*)d_in[3];
    const float* W2   = (const float*)d_in[4];
    const float* b2   = (const float*)d_in[5];
    const float* Wih0 = (const float*)d_in[6];
    const float* Whh0 = (const float*)d_in[7];
    const float* bih0 = (const float*)d_in[8];
    const float* bhh0 = (const float*)d_in[9];
    const float* Wih1 = (const float*)d_in[10];
    const float* Whh1 = (const float*)d_in[11];
    const float* bih1 = (const float*)d_in[12];
    const float* bhh1 = (const float*)d_in[13];
    const float* Wfc  = (const float*)d_in[14];
    const float* bfc  = (const float*)d_in[15];
    float* out = (float*)d_out;

    if (ws_size < 40764416) return;   // ~40.8 MB scratch

    char* ws = (char*)d_ws;
    unsigned short* ft    = (unsigned short*)(ws);              // 33,554,432 B
    unsigned char*  gbm   = (unsigned char*)(ws + 33554432);    //  4,194,304 B (dead after gcn_c)
    float*          gdinv = (float*)(ws + 37748736);            //    524,288 B
    float*          emb   = (float*)(ws + 38273024);            //    262,144 B
    unsigned short* w1t   = (unsigned short*)(ws + 38535168);   //     32,768 B
    unsigned short* w2t   = (unsigned short*)(ws + 38567936);   //     32,768 B
    float*          xg    = (float*)(ws + 38600704);            //  2,097,152 B
    // h-buffers overlay the gbm region (gbm is consumed before k_lstm runs)
    unsigned long long* h0w = (unsigned long long*)(ws + 33554432);  // 524,288 B
    unsigned long long* h1w = (unsigned long long*)(ws + 34078720);  // 524,288 B

    k_prep<<<64, 256, 0, stream>>>(W1, W2, w1t, w2t);
    k_gcn_a<<<512, 512, 0, stream>>>(adj, x, w1t, ft, gbm, gdinv);
    k_gcn_b<<<512, 512, 0, stream>>>(ft, gbm, gdinv, b1, w2t);
    k_gcn_c<<<512, 512, 0, stream>>>(ft, gbm, gdinv, b2, emb);
    // zero the epoch tags (stream-ordered after gcn_c's last gbm read)
    hipMemsetAsync(ws + 33554432, 0, 1048576, stream);
    k_xg<<<64, 256, 0, stream>>>(emb, Wih0, bih0, bhh0, xg);

    void* args[11];
    args[0] = (void*)&xg;
    args[1] = (void*)&Whh0;
    args[2] = (void*)&Wih1;
    args[3] = (void*)&Whh1;
    args[4] = (void*)&bih1;
    args[5] = (void*)&bhh1;
    args[6] = (void*)&Wfc;
    args[7] = (void*)&bfc;
    args[8] = (void*)&h0w;
    args[9] = (void*)&h1w;
    args[10] = (void*)&out;
    hipLaunchCooperativeKernel((const void*)k_lstm, dim3(24), dim3(512), args, 0, stream);
}

// Round 8
// 313.594 us; speedup vs baseline: 3.8211x; 1.0530x over previous
//
#include <hip/hip_runtime.h>
#include <hip/hip_bf16.h>

#define B_ 16
#define T_ 32
#define N_ 256
#define F_ 128
#define H_ 128
#define HL_ 256

typedef float f32x4 __attribute__((ext_vector_type(4)));
typedef float f32x2 __attribute__((ext_vector_type(2)));
typedef short bf16x8 __attribute__((ext_vector_type(8)));

#define MFMA16(A, Bv, C) __builtin_amdgcn_mfma_f32_16x16x32_bf16((A), (Bv), (C), 0, 0, 0)

__device__ __forceinline__ unsigned short f2bf(float f) {
    unsigned u = __builtin_bit_cast(unsigned, f);
    return (unsigned short)((u + 0x7FFFu + ((u >> 16) & 1u)) >> 16);
}
__device__ __forceinline__ float bf2f(unsigned short s) {
    unsigned u = ((unsigned)s) << 16;
    return __builtin_bit_cast(float, u);
}

__device__ __forceinline__ bf16x8 cvt8(const float* p) {
    f32x4 a = *(const f32x4*)p;
    f32x4 b = *(const f32x4*)(p + 4);
    bf16x8 r;
    r[0] = (short)f2bf(a[0]); r[1] = (short)f2bf(a[1]);
    r[2] = (short)f2bf(a[2]); r[3] = (short)f2bf(a[3]);
    r[4] = (short)f2bf(b[0]); r[5] = (short)f2bf(b[1]);
    r[6] = (short)f2bf(b[2]); r[7] = (short)f2bf(b[3]);
    return r;
}

__device__ __forceinline__ bf16x8 expand_bits(unsigned b) {
    bf16x8 r;
#pragma unroll
    for (int j = 0; j < 8; ++j) r[j] = (short)(((b >> j) & 1u) ? 0x3F80 : 0);
    return r;
}

__device__ __forceinline__ float sigf(float x) { return 1.f / (1.f + __expf(-x)); }
__device__ __forceinline__ float tanhf_(float x) { float e = __expf(2.f * x); return 1.f - 2.f / (e + 1.f); }

// epoch-tagged h word: lo = 2x bf16 payload, hi = epoch (t+1). Single 8B sc1 op.
__device__ __forceinline__ unsigned long long ld_u64(const unsigned long long* p) {
    return __hip_atomic_load(p, __ATOMIC_RELAXED, __HIP_MEMORY_SCOPE_AGENT);
}
__device__ __forceinline__ void st_u64(unsigned long long* p, unsigned long long v) {
    __hip_atomic_store(p, v, __ATOMIC_RELAXED, __HIP_MEMORY_SCOPE_AGENT);
}

// ---------------- weight prep: W1^T, W2^T in bf16 ----------------
__global__ void k_prep(const float* __restrict__ W1, const float* __restrict__ W2,
                       unsigned short* __restrict__ w1t, unsigned short* __restrict__ w2t) {
    int idx = blockIdx.x * 256 + threadIdx.x;   // 64 blocks * 256 = 16384
    int h = idx >> 7, f = idx & 127;
    w1t[idx] = f2bf(W1[f * 128 + h]);
    w2t[idx] = f2bf(W2[f * 128 + h]);
}

// ---------------- fused GCN: per (b,t) block does the entire 2-layer GCN + pool ----------------
// phase1: XWT' = dinv .* (x@W1)^T           -> s_ft [128][264] bf16
// phase2: h1 = relu(norm@XWT + b1)          -> s_ft [256][136] bf16 (overwrite)
// phase3: FT2' = dinv .* (h1@W2)^T          -> s_ft [128][264] bf16 (overwrite)
// phase4: h2 = relu(norm@FT2 + b2); emb = mean_n(h2)
__global__ __launch_bounds__(512, 1) void k_gcn(
    const int* __restrict__ adj, const float* __restrict__ x,
    const unsigned short* __restrict__ w1t, const unsigned short* __restrict__ w2t,
    const float* __restrict__ b1, const float* __restrict__ b2,
    float* __restrict__ emb) {
    __shared__ unsigned short s_ft[256 * 136];   // 69,632 B
    __shared__ unsigned short s_w[128 * 136];    // 34,816 B
    __shared__ unsigned char s_bm[8192];
    __shared__ float s_dinv[256];
    __shared__ float s_b1[128];
    __shared__ float s_b2[128];
    __shared__ float s_pool[8 * 128];
    const int bt = blockIdx.x, tid = threadIdx.x;
    const int* adjb = adj + (size_t)bt * (N_ * N_);

    // --- stage: bitmask + dinv ---
    for (int it = 0; it < 16; ++it) {
        int row = it * 16 + (tid >> 5);
        int c = tid & 31, m0 = c * 8;
        const int* p = adjb + row * N_ + m0;
        int4 q0 = *(const int4*)p;
        int4 q1 = *(const int4*)(p + 4);
        unsigned by = 0;
        by |= (((q0.x != 0) | (m0 + 0 == row)) ? 1u : 0u);
        by |= (((q0.y != 0) | (m0 + 1 == row)) ? 2u : 0u);
        by |= (((q0.z != 0) | (m0 + 2 == row)) ? 4u : 0u);
        by |= (((q0.w != 0) | (m0 + 3 == row)) ? 8u : 0u);
        by |= (((q1.x != 0) | (m0 + 4 == row)) ? 16u : 0u);
        by |= (((q1.y != 0) | (m0 + 5 == row)) ? 32u : 0u);
        by |= (((q1.z != 0) | (m0 + 6 == row)) ? 64u : 0u);
        by |= (((q1.w != 0) | (m0 + 7 == row)) ? 128u : 0u);
        s_bm[row * 32 + c] = (unsigned char)by;
        int pc = __popc(by);
        pc += __shfl_xor(pc, 1); pc += __shfl_xor(pc, 2); pc += __shfl_xor(pc, 4);
        pc += __shfl_xor(pc, 8); pc += __shfl_xor(pc, 16);
        if (c == 0) s_dinv[row] = rsqrtf((float)pc);
    }
    // --- stage: W1^T + biases ---
    for (int it = 0; it < 4; ++it) {
        int g = it * 512 + tid;
        *(int4*)(&s_w[(g >> 4) * 136 + (g & 15) * 8]) = *(const int4*)(w1t + g * 8);
    }
    if (tid < 32) *(float4*)(&s_b1[tid * 4]) = *(const float4*)(b1 + tid * 4);
    else if (tid < 64) *(float4*)(&s_b2[(tid - 32) * 4]) = *(const float4*)(b2 + (tid - 32) * 4);
    __syncthreads();   // sync0

    const int w = tid >> 6, l = tid & 63, li = l & 15, lg = l >> 4;
    const float* xb = x + (size_t)bt * (N_ * F_);
    f32x4 acc[2][8];

    // ===== phase 1: XWT' = dinv .* (x@W1)^T =====
#pragma unroll
    for (int a = 0; a < 2; ++a)
#pragma unroll
        for (int c = 0; c < 8; ++c) acc[a][c] = (f32x4){0.f, 0.f, 0.f, 0.f};
#pragma unroll
    for (int ks = 0; ks < 4; ++ks) {
        bf16x8 a0 = cvt8(xb + (size_t)(32 * w + li) * F_ + lg * 8 + ks * 32);
        bf16x8 a1 = cvt8(xb + (size_t)(32 * w + 16 + li) * F_ + lg * 8 + ks * 32);
#pragma unroll
        for (int ct = 0; ct < 8; ++ct) {
            bf16x8 bv = *(const bf16x8*)(&s_w[(16 * ct + li) * 136 + lg * 8 + ks * 32]);
            acc[0][ct] = MFMA16(a0, bv, acc[0][ct]);
            acc[1][ct] = MFMA16(a1, bv, acc[1][ct]);
        }
    }
    __syncthreads();   // sync1: W1T reads done -> s_w reusable; s_ft writes may begin
#pragma unroll
    for (int rt = 0; rt < 2; ++rt) {
        int m0 = 32 * w + 16 * rt + 4 * lg;
        f32x4 dv = *(const f32x4*)(&s_dinv[m0]);
#pragma unroll
        for (int ct = 0; ct < 8; ++ct) {
            int h = 16 * ct + li;
            f32x4 v = acc[rt][ct];
            unsigned p0 = (unsigned)f2bf(v[0] * dv[0]) | ((unsigned)f2bf(v[1] * dv[1]) << 16);
            unsigned p1 = (unsigned)f2bf(v[2] * dv[2]) | ((unsigned)f2bf(v[3] * dv[3]) << 16);
            uint2 pk; pk.x = p0; pk.y = p1;
            *(uint2*)(&s_ft[h * 264 + m0]) = pk;
        }
    }
    // reload s_w with W2^T (no reader of s_w until phase 3)
    for (int it = 0; it < 4; ++it) {
        int g = it * 512 + tid;
        *(int4*)(&s_w[(g >> 4) * 136 + (g & 15) * 8]) = *(const int4*)(w2t + g * 8);
    }
    __syncthreads();   // sync2: XWT visible

    // ===== phase 2: S1 = norm @ XWT =====
#pragma unroll
    for (int a = 0; a < 2; ++a)
#pragma unroll
        for (int c = 0; c < 8; ++c) acc[a][c] = (f32x4){0.f, 0.f, 0.f, 0.f};
#pragma unroll
    for (int ks = 0; ks < 8; ++ks) {
        bf16x8 a0 = expand_bits(s_bm[(32 * w + li) * 32 + 4 * ks + lg]);
        bf16x8 a1 = expand_bits(s_bm[(32 * w + 16 + li) * 32 + 4 * ks + lg]);
#pragma unroll
        for (int ct = 0; ct < 8; ++ct) {
            bf16x8 bv = *(const bf16x8*)(&s_ft[(16 * ct + li) * 264 + lg * 8 + ks * 32]);
            acc[0][ct] = MFMA16(a0, bv, acc[0][ct]);
            acc[1][ct] = MFMA16(a1, bv, acc[1][ct]);
        }
    }
    __syncthreads();   // sync3: XWT reads done -> h1 overwrite safe
#pragma unroll
    for (int rt = 0; rt < 2; ++rt) {
        int i0 = 32 * w + 16 * rt + 4 * lg;
        f32x4 dv = *(const f32x4*)(&s_dinv[i0]);
#pragma unroll
        for (int ct = 0; ct < 8; ++ct) {
            int h = 16 * ct + li;
            float bb = s_b1[h];
#pragma unroll
            for (int r = 0; r < 4; ++r)
                s_ft[(i0 + r) * 136 + h] = f2bf(fmaxf(acc[rt][ct][r] * dv[r] + bb, 0.f));
        }
    }
    __syncthreads();   // sync4: h1 visible

    // ===== phase 3: FT2' = dinv .* (h1@W2)^T =====
#pragma unroll
    for (int a = 0; a < 2; ++a)
#pragma unroll
        for (int c = 0; c < 8; ++c) acc[a][c] = (f32x4){0.f, 0.f, 0.f, 0.f};
#pragma unroll
    for (int ks = 0; ks < 4; ++ks) {
        bf16x8 a0 = *(const bf16x8*)(&s_ft[(32 * w + li) * 136 + lg * 8 + ks * 32]);
        bf16x8 a1 = *(const bf16x8*)(&s_ft[(32 * w + 16 + li) * 136 + lg * 8 + ks * 32]);
#pragma unroll
        for (int ct = 0; ct < 8; ++ct) {
            bf16x8 bv = *(const bf16x8*)(&s_w[(16 * ct + li) * 136 + lg * 8 + ks * 32]);
            acc[0][ct] = MFMA16(a0, bv, acc[0][ct]);
            acc[1][ct] = MFMA16(a1, bv, acc[1][ct]);
        }
    }
    __syncthreads();   // sync5: h1 reads done -> FT2 overwrite safe
#pragma unroll
    for (int rt = 0; rt < 2; ++rt) {
        int m0 = 32 * w + 16 * rt + 4 * lg;
        f32x4 dv = *(const f32x4*)(&s_dinv[m0]);
#pragma unroll
        for (int ct = 0; ct < 8; ++ct) {
            int h = 16 * ct + li;
            f32x4 v = acc[rt][ct];
            unsigned p0 = (unsigned)f2bf(v[0] * dv[0]) | ((unsigned)f2bf(v[1] * dv[1]) << 16);
            unsigned p1 = (unsigned)f2bf(v[2] * dv[2]) | ((unsigned)f2bf(v[3] * dv[3]) << 16);
            uint2 pk; pk.x = p0; pk.y = p1;
            *(uint2*)(&s_ft[h * 264 + m0]) = pk;
        }
    }
    __syncthreads();   // sync6: FT2 visible

    // ===== phase 4: h2 = relu(norm@FT2 + b2); emb = mean_n(h2) =====
#pragma unroll
    for (int a = 0; a < 2; ++a)
#pragma unroll
        for (int c = 0; c < 8; ++c) acc[a][c] = (f32x4){0.f, 0.f, 0.f, 0.f};
#pragma unroll
    for (int ks = 0; ks < 8; ++ks) {
        bf16x8 a0 = expand_bits(s_bm[(32 * w + li) * 32 + 4 * ks + lg]);
        bf16x8 a1 = expand_bits(s_bm[(32 * w + 16 + li) * 32 + 4 * ks + lg]);
#pragma unroll
        for (int ct = 0; ct < 8; ++ct) {
            bf16x8 bv = *(const bf16x8*)(&s_ft[(16 * ct + li) * 264 + lg * 8 + ks * 32]);
            acc[0][ct] = MFMA16(a0, bv, acc[0][ct]);
            acc[1][ct] = MFMA16(a1, bv, acc[1][ct]);
        }
    }
    int i0a = 32 * w + 4 * lg;
    f32x4 dv0 = *(const f32x4*)(&s_dinv[i0a]);
    f32x4 dv1 = *(const f32x4*)(&s_dinv[i0a + 16]);
#pragma unroll
    for (int ct = 0; ct < 8; ++ct) {
        int h = 16 * ct + li;
        float bb = s_b2[h];
        float s = 0.f;
#pragma unroll
        for (int r = 0; r < 4; ++r) {
            s += fmaxf(acc[0][ct][r] * dv0[r] + bb, 0.f);
            s += fmaxf(acc[1][ct][r] * dv1[r] + bb, 0.f);
        }
        s += __shfl_xor(s, 16);
        s += __shfl_xor(s, 32);
        if (lg == 0) s_pool[w * 128 + h] = s;
    }
    __syncthreads();
    if (tid < 128) {
        float e = 0.f;
#pragma unroll
        for (int ww = 0; ww < 8; ++ww) e += s_pool[ww * 128 + tid];
        emb[(size_t)bt * 128 + tid] = e * (1.f / 256.f);
    }
}

// ---------------- xg = emb @ Wih0^T + bih0 + bhh0   (layout [t][b][1024]) ----------------
__global__ __launch_bounds__(256, 2) void k_xg(
    const float* __restrict__ emb, const float* __restrict__ Wih0,
    const float* __restrict__ bih0, const float* __restrict__ bhh0,
    float* __restrict__ xg) {
    __shared__ float s_e[8][128];
    const int bk = blockIdx.x, tid = threadIdx.x;
    for (int q = 0; q < 4; ++q) {
        int idx = q * 256 + tid;
        int p = idx >> 7, k = idx & 127;
        int tb2 = bk * 8 + p;
        int t = tb2 >> 4, b = tb2 & 15;
        s_e[p][k] = emb[(size_t)(b * T_ + t) * 128 + k];
    }
    __syncthreads();
    for (int cc = 0; cc < 4; ++cc) {
        int col = cc * 256 + tid;
        float bias = bih0[col] + bhh0[col];
        const float4* wr = (const float4*)(Wih0 + (size_t)col * 128);
        float accv[8] = {0, 0, 0, 0, 0, 0, 0, 0};
        for (int k4 = 0; k4 < 32; ++k4) {
            float4 wv = wr[k4];
#pragma unroll
            for (int p = 0; p < 8; ++p) {
                float4 ev = *(const float4*)(&s_e[p][k4 * 4]);
                accv[p] += wv.x * ev.x + wv.y * ev.y + wv.z * ev.z + wv.w * ev.w;
            }
        }
#pragma unroll
        for (int p = 0; p < 8; ++p) {
            int tb2 = bk * 8 + p;
            xg[(size_t)tb2 * 1024 + col] = accv[p] + bias;
        }
    }
}

// ---------------- dataflow LSTM: 8 L0 blocks + 16 L1 blocks, data-as-flag ----------------
// (round-6 proven version: MALL sc1 exchange, batched epoch polls)
__global__ __launch_bounds__(512, 1) void k_lstm(
    const float* __restrict__ xg, const float* __restrict__ Whh0,
    const float* __restrict__ Wih1, const float* __restrict__ Whh1,
    const float* __restrict__ bih1, const float* __restrict__ bhh1,
    const float* __restrict__ Wfc, const float* __restrict__ bfc,
    unsigned long long* h0w, unsigned long long* h1w, float* __restrict__ out) {
    __shared__ __align__(16) char arena[91456];
    const int wg = blockIdx.x, tid = threadIdx.x;
    const int lane = tid & 63;

    if (wg < 8) {
        // ================= LAYER 0 =================
        unsigned short* s_w = (unsigned short*)arena;            // [128][258] bf16
        unsigned short* s_h = (unsigned short*)(arena + 66048);  // [16][258] bf16
        float* s_gate = (float*)(arena + 74304);                 // [128][18] f32
        const int j0 = wg * 32;

#pragma unroll
        for (int it = 0; it < 16; ++it) {
            int e4 = tid + it * 512;
            int rl = e4 >> 6, k0 = (e4 & 63) * 4;
            int rg = (rl >> 5) * 256 + j0 + (rl & 31);
            float4 v = *(const float4*)(Whh0 + (size_t)rg * 256 + k0);
            uint2 pk;
            pk.x = (unsigned)f2bf(v.x) | ((unsigned)f2bf(v.y) << 16);
            pk.y = (unsigned)f2bf(v.z) | ((unsigned)f2bf(v.w) << 16);
            *(uint2*)(s_w + rl * 258 + k0) = pk;
        }
        __syncthreads();

        const int w = tid >> 6, li = lane & 15, lg = lane >> 4;
        const int cb = tid >> 5, cj = tid & 31;
        float c_reg = 0.f;

        for (int t = 0; t < 32; ++t) {
            float xgv[4];
#pragma unroll
            for (int g = 0; g < 4; ++g)
                xgv[g] = xg[(size_t)(t * 16 + cb) * 1024 + g * 256 + j0 + cj];
            if (t > 0) {
                const unsigned long long* src = h0w + (size_t)(t - 1) * 2048;
                unsigned long long v[4];
                const unsigned e = (unsigned)t;
                for (;;) {
#pragma unroll
                    for (int q = 0; q < 4; ++q) v[q] = ld_u64(src + tid + q * 512);
                    bool ok = true;
#pragma unroll
                    for (int q = 0; q < 4; ++q) ok &= ((unsigned)(v[q] >> 32) == e);
                    if (ok) break;
                    __builtin_amdgcn_s_sleep(1);
                }
#pragma unroll
                for (int q = 0; q < 4; ++q) {
                    int wd = tid + q * 512;
                    int b = wd >> 7, jp = wd & 127;
                    *(unsigned*)(s_h + b * 258 + jp * 2) = (unsigned)v[q];
                }
            }
            __syncthreads();
            if (t > 0) {
                f32x4 acc = (f32x4){0.f, 0.f, 0.f, 0.f};
#pragma unroll
                for (int ks = 0; ks < 8; ++ks) {
                    bf16x8 af = *(const bf16x8*)(s_h + li * 258 + lg * 8 + ks * 32);
                    bf16x8 bf = *(const bf16x8*)(s_w + (16 * w + li) * 258 + lg * 8 + ks * 32);
                    acc = MFMA16(af, bf, acc);
                }
                int base = (16 * w + li) * 18 + 4 * lg;
                *(f32x2*)(s_gate + base) = (f32x2){acc[0], acc[1]};
                *(f32x2*)(s_gate + base + 2) = (f32x2){acc[2], acc[3]};
            }
            __syncthreads();
            {
                float gi = xgv[0], gf = xgv[1], gg = xgv[2], go = xgv[3];
                if (t > 0) {
                    gi += s_gate[(0 * 32 + cj) * 18 + cb];
                    gf += s_gate[(1 * 32 + cj) * 18 + cb];
                    gg += s_gate[(2 * 32 + cj) * 18 + cb];
                    go += s_gate[(3 * 32 + cj) * 18 + cb];
                }
                c_reg = sigf(gf) * c_reg + sigf(gi) * tanhf_(gg);
                float h = sigf(go) * tanhf_(c_reg);
                unsigned hu = f2bf(h);
                unsigned other = __shfl_xor(hu, 1);
                if ((cj & 1) == 0) {
                    unsigned long long v = (unsigned long long)(hu | (other << 16))
                                         | ((unsigned long long)(t + 1) << 32);
                    st_u64(h0w + (size_t)t * 2048 + cb * 128 + ((j0 + cj) >> 1), v);
                }
            }
        }
    } else {
        // ================= LAYER 1 =================
        unsigned short* s_w = (unsigned short*)arena;            // [64][514] bf16
        unsigned short* s_h = (unsigned short*)(arena + 65792);  // [16][514] bf16
        float* s_gate = (float*)(arena + 82240);                 // [2][64][18] f32
        const int bi = wg - 8;
        const int j0 = bi * 16;

#pragma unroll
        for (int it = 0; it < 16; ++it) {
            int e4 = tid + it * 512;
            int rl = e4 >> 7, k0 = (e4 & 127) * 4;
            int rg = (rl >> 4) * 256 + j0 + (rl & 15);
            const float* src = (k0 < 256) ? (Wih1 + (size_t)rg * 256 + k0)
                                          : (Whh1 + (size_t)rg * 256 + (k0 - 256));
            float4 v = *(const float4*)src;
            uint2 pk;
            pk.x = (unsigned)f2bf(v.x) | ((unsigned)f2bf(v.y) << 16);
            pk.y = (unsigned)f2bf(v.z) | ((unsigned)f2bf(v.w) << 16);
            *(uint2*)(s_w + rl * 514 + k0) = pk;
        }

        const int w = tid >> 6, li = lane & 15, lg = lane >> 4;
        const int ct = w & 3, kh = w >> 2;
        const int cb = tid >> 4, cj = tid & 15;
        float bias[4];
        if (tid < 256) {
#pragma unroll
            for (int g = 0; g < 4; ++g) {
                int r = g * 256 + j0 + cj;
                bias[g] = bih1[r] + bhh1[r];
            }
        }
        __syncthreads();
        float c_reg = 0.f;

        for (int t = 0; t < 32; ++t) {
            const unsigned long long* s0 = h0w + (size_t)t * 2048;
            const unsigned long long* s1 = h1w + (size_t)(t - 1) * 2048;
            unsigned long long v[8];
            const unsigned e0 = (unsigned)(t + 1), e1 = (unsigned)t;
            if (t > 0) {
                for (;;) {
#pragma unroll
                    for (int q = 0; q < 4; ++q) v[q] = ld_u64(s0 + tid + q * 512);
#pragma unroll
                    for (int q = 0; q < 4; ++q) v[4 + q] = ld_u64(s1 + tid + q * 512);
                    bool ok = true;
#pragma unroll
                    for (int q = 0; q < 4; ++q) ok &= ((unsigned)(v[q] >> 32) == e0);
#pragma unroll
                    for (int q = 0; q < 4; ++q) ok &= ((unsigned)(v[4 + q] >> 32) == e1);
                    if (ok) break;
                    __builtin_amdgcn_s_sleep(1);
                }
            } else {
                for (;;) {
#pragma unroll
                    for (int q = 0; q < 4; ++q) v[q] = ld_u64(s0 + tid + q * 512);
                    bool ok = true;
#pragma unroll
                    for (int q = 0; q < 4; ++q) ok &= ((unsigned)(v[q] >> 32) == e0);
                    if (ok) break;
                    __builtin_amdgcn_s_sleep(1);
                }
#pragma unroll
                for (int q = 0; q < 4; ++q) v[4 + q] = 0ull;
            }
#pragma unroll
            for (int q = 0; q < 4; ++q) {
                int wd = tid + q * 512;
                int b = wd >> 7, jp = wd & 127;
                *(unsigned*)(s_h + b * 514 + jp * 2) = (unsigned)v[q];
                *(unsigned*)(s_h + b * 514 + 256 + jp * 2) = (unsigned)v[4 + q];
            }
            __syncthreads();
            {
                f32x4 acc = (f32x4){0.f, 0.f, 0.f, 0.f};
#pragma unroll
                for (int ks = 0; ks < 8; ++ks) {
                    int ko = (kh * 8 + ks) * 32;
                    bf16x8 af = *(const bf16x8*)(s_h + li * 514 + lg * 8 + ko);
                    bf16x8 bf = *(const bf16x8*)(s_w + (16 * ct + li) * 514 + lg * 8 + ko);
                    acc = MFMA16(af, bf, acc);
                }
                int base = kh * 1152 + (16 * ct + li) * 18 + 4 * lg;
                *(f32x2*)(s_gate + base) = (f32x2){acc[0], acc[1]};
                *(f32x2*)(s_gate + base + 2) = (f32x2){acc[2], acc[3]};
            }
            __syncthreads();
            if (tid < 256) {
                float gt[4];
#pragma unroll
                for (int g = 0; g < 4; ++g) {
                    int base = (g * 16 + cj) * 18 + cb;
                    gt[g] = s_gate[base] + s_gate[1152 + base] + bias[g];
                }
                c_reg = sigf(gt[1]) * c_reg + sigf(gt[0]) * tanhf_(gt[2]);
                float h = sigf(gt[3]) * tanhf_(c_reg);
                unsigned hu = f2bf(h);
                unsigned other = __shfl_xor(hu, 1);
                if ((cj & 1) == 0) {
                    unsigned long long v2 = (unsigned long long)(hu | (other << 16))
                                          | ((unsigned long long)(t + 1) << 32);
                    st_u64(h1w + (size_t)t * 2048 + cb * 128 + ((j0 + cj) >> 1), v2);
                }
            }
        }

        if (bi == 0) {
            float* s_red = s_gate;
            if (tid < 256) {
                int b = tid >> 4, kc = tid & 15;
                const unsigned long long* hw = h1w + (size_t)31 * 2048 + b * 128 + kc * 8;
                unsigned long long v[8];
                for (;;) {
#pragma unroll
                    for (int q = 0; q < 8; ++q) v[q] = ld_u64(hw + q);
                    bool ok = true;
#pragma unroll
                    for (int q = 0; q < 8; ++q) ok &= ((unsigned)(v[q] >> 32) == 32u);
                    if (ok) break;
                    __builtin_amdgcn_s_sleep(1);
                }
                float s = 0.f;
#pragma unroll
                for (int q = 0; q < 8; ++q) {
                    unsigned u = (unsigned)v[q];
                    s += Wfc[kc * 16 + 2 * q] * bf2f((unsigned short)(u & 0xffff));
                    s += Wfc[kc * 16 + 2 * q + 1] * bf2f((unsigned short)(u >> 16));
                }
                s_red[tid] = s;
            }
            __syncthreads();
            if (tid < 16) {
                float s = bfc[0];
#pragma unroll
                for (int q = 0; q < 16; ++q) s += s_red[tid * 16 + q];
                out[tid] = sigf(s);
            }
        }
    }
}

extern "C" void kernel_launch(void* const* d_in, const int* in_sizes, int n_in,
                              void* d_out, int out_size, void* d_ws, size_t ws_size,
                              hipStream_t stream) {
    const int*   adj  = (const int*)  d_in[0];
    const float* x    = (const float*)d_in[1];
    const float* W1   = (const float*)d_in[2];
    const float* b1   = (const float*)d_in[3];
    const float* W2   = (const float*)d_in[4];
    const float* b2   = (const float*)d_in[5];
    const float* Wih0 = (const float*)d_in[6];
    const float* Whh0 = (const float*)d_in[7];
    const float* bih0 = (const float*)d_in[8];
    const float* bhh0 = (const float*)d_in[9];
    const float* Wih1 = (const float*)d_in[10];
    const float* Whh1 = (const float*)d_in[11];
    const float* bih1 = (const float*)d_in[12];
    const float* bhh1 = (const float*)d_in[13];
    const float* Wfc  = (const float*)d_in[14];
    const float* bfc  = (const float*)d_in[15];
    float* out = (float*)d_out;

    if (ws_size < 4194304) return;   // needs ~3.5 MB scratch

    char* ws = (char*)d_ws;
    unsigned long long* h0w = (unsigned long long*)(ws);             //   524,288 B
    unsigned long long* h1w = (unsigned long long*)(ws + 524288);    //   524,288 B
    float*          emb   = (float*)(ws + 1048576);                  //   262,144 B
    unsigned short* w1t   = (unsigned short*)(ws + 1310720);         //    32,768 B
    unsigned short* w2t   = (unsigned short*)(ws + 1343488);         //    32,768 B
    float*          xg    = (float*)(ws + 1376256);                  // 2,097,152 B

    hipMemsetAsync(ws, 0, 1048576, stream);   // zero h epochs

    k_prep<<<64, 256, 0, stream>>>(W1, W2, w1t, w2t);
    k_gcn<<<512, 512, 0, stream>>>(adj, x, w1t, w2t, b1, b2, emb);
    k_xg<<<64, 256, 0, stream>>>(emb, Wih0, bih0, bhh0, xg);

    void* args[11];
    args[0] = (void*)&xg;
    args[1] = (void*)&Whh0;
    args[2] = (void*)&Wih1;
    args[3] = (void*)&Whh1;
    args[4] = (void*)&bih1;
    args[5] = (void*)&bhh1;
    args[6] = (void*)&Wfc;
    args[7] = (void*)&bfc;
    args[8] = (void*)&h0w;
    args[9] = (void*)&h1w;
    args[10] = (void*)&out;
    hipLaunchCooperativeKernel((const void*)k_lstm, dim3(24), dim3(512), args, 0, stream);
}

// Round 9
// 247.177 us; speedup vs baseline: 4.8479x; 1.2687x over previous
//
#include <hip/hip_runtime.h>
#include <hip/hip_bf16.h>

#define B_ 16
#define T_ 32
#define N_ 256
#define F_ 128
#define H_ 128
#define HL_ 256

typedef float f32x4 __attribute__((ext_vector_type(4)));
typedef float f32x2 __attribute__((ext_vector_type(2)));
typedef short bf16x8 __attribute__((ext_vector_type(8)));

#define MFMA16(A, Bv, C) __builtin_amdgcn_mfma_f32_16x16x32_bf16((A), (Bv), (C), 0, 0, 0)

__device__ __forceinline__ unsigned short f2bf(float f) {
    unsigned u = __builtin_bit_cast(unsigned, f);
    return (unsigned short)((u + 0x7FFFu + ((u >> 16) & 1u)) >> 16);
}
__device__ __forceinline__ float bf2f(unsigned short s) {
    unsigned u = ((unsigned)s) << 16;
    return __builtin_bit_cast(float, u);
}

__device__ __forceinline__ bf16x8 cvt8(const float* p) {
    f32x4 a = *(const f32x4*)p;
    f32x4 b = *(const f32x4*)(p + 4);
    bf16x8 r;
    r[0] = (short)f2bf(a[0]); r[1] = (short)f2bf(a[1]);
    r[2] = (short)f2bf(a[2]); r[3] = (short)f2bf(a[3]);
    r[4] = (short)f2bf(b[0]); r[5] = (short)f2bf(b[1]);
    r[6] = (short)f2bf(b[2]); r[7] = (short)f2bf(b[3]);
    return r;
}

__device__ __forceinline__ bf16x8 expand_bits(unsigned b) {
    bf16x8 r;
#pragma unroll
    for (int j = 0; j < 8; ++j) r[j] = (short)(((b >> j) & 1u) ? 0x3F80 : 0);
    return r;
}

__device__ __forceinline__ float sigf(float x) { return 1.f / (1.f + __expf(-x)); }
__device__ __forceinline__ float tanhf_(float x) { float e = __expf(2.f * x); return 1.f - 2.f / (e + 1.f); }

// epoch-tagged u64 word via MALL (sc1): lo 32 = payload, hi 32 = epoch.
__device__ __forceinline__ unsigned long long ld_u64(const unsigned long long* p) {
    return __hip_atomic_load(p, __ATOMIC_RELAXED, __HIP_MEMORY_SCOPE_AGENT);
}
__device__ __forceinline__ void st_u64(unsigned long long* p, unsigned long long v) {
    __hip_atomic_store(p, v, __ATOMIC_RELAXED, __HIP_MEMORY_SCOPE_AGENT);
}

// ---------------- weight prep: W1^T, W2^T in bf16 ----------------
__global__ void k_prep(const float* __restrict__ W1, const float* __restrict__ W2,
                       unsigned short* __restrict__ w1t, unsigned short* __restrict__ w2t) {
    int idx = blockIdx.x * 256 + threadIdx.x;   // 64 blocks * 256 = 16384
    int h = idx >> 7, f = idx & 127;
    w1t[idx] = f2bf(W1[f * 128 + h]);
    w2t[idx] = f2bf(W2[f * 128 + h]);
}

// ================= fused GCN + xg + dataflow LSTM, one launch =================
// blocks 0..7   : LSTM layer0 (dataflow, polls xgw + h0w)
// blocks 8..23  : LSTM layer1 (polls h0w + h1w); block 8 does FC tail
// blocks 24..535: GCN for k=wg-24, t=k>>4, b=k&15 (t-major so xg(t) arrives in order);
//                 computes 2-layer GCN + mean-pool + xg row, publishes xgw epoch-tagged.
// xgw: [32 t][16 b][1024 col] u64 {f32 payload, epoch=1}; h0w/h1w as before.
__global__ __launch_bounds__(512, 1) void k_fused(
    const int* __restrict__ adj, const float* __restrict__ x,
    const unsigned short* __restrict__ w1t, const unsigned short* __restrict__ w2t,
    const float* __restrict__ b1, const float* __restrict__ b2,
    const float* __restrict__ Wih0, const float* __restrict__ bih0,
    const float* __restrict__ bhh0, const float* __restrict__ Whh0,
    const float* __restrict__ Wih1, const float* __restrict__ Whh1,
    const float* __restrict__ bih1, const float* __restrict__ bhh1,
    const float* __restrict__ Wfc, const float* __restrict__ bfc,
    unsigned long long* xgw, unsigned long long* h0w, unsigned long long* h1w,
    float* __restrict__ out) {
    __shared__ __align__(16) char arena[118784];
    const int wg = blockIdx.x, tid = threadIdx.x;
    const int lane = tid & 63;

    if (wg >= 24) {
        // ===================== GCN role =====================
        const int k = wg - 24;
        const int t = k >> 4, b = k & 15;
        const int bt_in = b * 32 + t;                    // input [B][T] index
        unsigned short* s_ft = (unsigned short*)arena;                 // [256][136]/[128][264]
        unsigned short* s_w  = (unsigned short*)(arena + 69632);       // [128][136]
        unsigned char*  s_bm = (unsigned char*)(arena + 104448);       // 8192
        float* s_dinv = (float*)(arena + 112640);                      // 256 f32
        float* s_b1   = (float*)(arena + 113664);                      // 128 f32
        float* s_b2   = (float*)(arena + 114176);                      // 128 f32
        float* s_pool = (float*)(arena + 114688);                      // 8*128 f32
        const int* adjb = adj + (size_t)bt_in * (N_ * N_);

        for (int it = 0; it < 16; ++it) {
            int row = it * 16 + (tid >> 5);
            int c = tid & 31, m0 = c * 8;
            const int* p = adjb + row * N_ + m0;
            int4 q0 = *(const int4*)p;
            int4 q1 = *(const int4*)(p + 4);
            unsigned by = 0;
            by |= (((q0.x != 0) | (m0 + 0 == row)) ? 1u : 0u);
            by |= (((q0.y != 0) | (m0 + 1 == row)) ? 2u : 0u);
            by |= (((q0.z != 0) | (m0 + 2 == row)) ? 4u : 0u);
            by |= (((q0.w != 0) | (m0 + 3 == row)) ? 8u : 0u);
            by |= (((q1.x != 0) | (m0 + 4 == row)) ? 16u : 0u);
            by |= (((q1.y != 0) | (m0 + 5 == row)) ? 32u : 0u);
            by |= (((q1.z != 0) | (m0 + 6 == row)) ? 64u : 0u);
            by |= (((q1.w != 0) | (m0 + 7 == row)) ? 128u : 0u);
            s_bm[row * 32 + c] = (unsigned char)by;
            int pc = __popc(by);
            pc += __shfl_xor(pc, 1); pc += __shfl_xor(pc, 2); pc += __shfl_xor(pc, 4);
            pc += __shfl_xor(pc, 8); pc += __shfl_xor(pc, 16);
            if (c == 0) s_dinv[row] = rsqrtf((float)pc);
        }
        for (int it = 0; it < 4; ++it) {
            int g = it * 512 + tid;
            *(int4*)(&s_w[(g >> 4) * 136 + (g & 15) * 8]) = *(const int4*)(w1t + g * 8);
        }
        if (tid < 32) *(float4*)(&s_b1[tid * 4]) = *(const float4*)(b1 + tid * 4);
        else if (tid < 64) *(float4*)(&s_b2[(tid - 32) * 4]) = *(const float4*)(b2 + (tid - 32) * 4);
        __syncthreads();

        const int w = tid >> 6, li = lane & 15, lg = lane >> 4;
        const float* xb = x + (size_t)bt_in * (N_ * F_);
        f32x4 acc[2][8];

        // phase 1: XWT' = dinv .* (x@W1)^T
#pragma unroll
        for (int a = 0; a < 2; ++a)
#pragma unroll
            for (int c = 0; c < 8; ++c) acc[a][c] = (f32x4){0.f, 0.f, 0.f, 0.f};
#pragma unroll
        for (int ks = 0; ks < 4; ++ks) {
            bf16x8 a0 = cvt8(xb + (size_t)(32 * w + li) * F_ + lg * 8 + ks * 32);
            bf16x8 a1 = cvt8(xb + (size_t)(32 * w + 16 + li) * F_ + lg * 8 + ks * 32);
#pragma unroll
            for (int ct = 0; ct < 8; ++ct) {
                bf16x8 bv = *(const bf16x8*)(&s_w[(16 * ct + li) * 136 + lg * 8 + ks * 32]);
                acc[0][ct] = MFMA16(a0, bv, acc[0][ct]);
                acc[1][ct] = MFMA16(a1, bv, acc[1][ct]);
            }
        }
        __syncthreads();
#pragma unroll
        for (int rt = 0; rt < 2; ++rt) {
            int m0 = 32 * w + 16 * rt + 4 * lg;
            f32x4 dv = *(const f32x4*)(&s_dinv[m0]);
#pragma unroll
            for (int ct = 0; ct < 8; ++ct) {
                int h = 16 * ct + li;
                f32x4 v = acc[rt][ct];
                unsigned p0 = (unsigned)f2bf(v[0] * dv[0]) | ((unsigned)f2bf(v[1] * dv[1]) << 16);
                unsigned p1 = (unsigned)f2bf(v[2] * dv[2]) | ((unsigned)f2bf(v[3] * dv[3]) << 16);
                uint2 pk; pk.x = p0; pk.y = p1;
                *(uint2*)(&s_ft[h * 264 + m0]) = pk;
            }
        }
        for (int it = 0; it < 4; ++it) {
            int g = it * 512 + tid;
            *(int4*)(&s_w[(g >> 4) * 136 + (g & 15) * 8]) = *(const int4*)(w2t + g * 8);
        }
        __syncthreads();

        // phase 2: h1 = relu(norm@XWT + b1)
#pragma unroll
        for (int a = 0; a < 2; ++a)
#pragma unroll
            for (int c = 0; c < 8; ++c) acc[a][c] = (f32x4){0.f, 0.f, 0.f, 0.f};
#pragma unroll
        for (int ks = 0; ks < 8; ++ks) {
            bf16x8 a0 = expand_bits(s_bm[(32 * w + li) * 32 + 4 * ks + lg]);
            bf16x8 a1 = expand_bits(s_bm[(32 * w + 16 + li) * 32 + 4 * ks + lg]);
#pragma unroll
            for (int ct = 0; ct < 8; ++ct) {
                bf16x8 bv = *(const bf16x8*)(&s_ft[(16 * ct + li) * 264 + lg * 8 + ks * 32]);
                acc[0][ct] = MFMA16(a0, bv, acc[0][ct]);
                acc[1][ct] = MFMA16(a1, bv, acc[1][ct]);
            }
        }
        __syncthreads();
#pragma unroll
        for (int rt = 0; rt < 2; ++rt) {
            int i0 = 32 * w + 16 * rt + 4 * lg;
            f32x4 dv = *(const f32x4*)(&s_dinv[i0]);
#pragma unroll
            for (int ct = 0; ct < 8; ++ct) {
                int h = 16 * ct + li;
                float bb = s_b1[h];
#pragma unroll
                for (int r = 0; r < 4; ++r)
                    s_ft[(i0 + r) * 136 + h] = f2bf(fmaxf(acc[rt][ct][r] * dv[r] + bb, 0.f));
            }
        }
        __syncthreads();

        // phase 3: FT2' = dinv .* (h1@W2)^T
#pragma unroll
        for (int a = 0; a < 2; ++a)
#pragma unroll
            for (int c = 0; c < 8; ++c) acc[a][c] = (f32x4){0.f, 0.f, 0.f, 0.f};
#pragma unroll
        for (int ks = 0; ks < 4; ++ks) {
            bf16x8 a0 = *(const bf16x8*)(&s_ft[(32 * w + li) * 136 + lg * 8 + ks * 32]);
            bf16x8 a1 = *(const bf16x8*)(&s_ft[(32 * w + 16 + li) * 136 + lg * 8 + ks * 32]);
#pragma unroll
            for (int ct = 0; ct < 8; ++ct) {
                bf16x8 bv = *(const bf16x8*)(&s_w[(16 * ct + li) * 136 + lg * 8 + ks * 32]);
                acc[0][ct] = MFMA16(a0, bv, acc[0][ct]);
                acc[1][ct] = MFMA16(a1, bv, acc[1][ct]);
            }
        }
        __syncthreads();
#pragma unroll
        for (int rt = 0; rt < 2; ++rt) {
            int m0 = 32 * w + 16 * rt + 4 * lg;
            f32x4 dv = *(const f32x4*)(&s_dinv[m0]);
#pragma unroll
            for (int ct = 0; ct < 8; ++ct) {
                int h = 16 * ct + li;
                f32x4 v = acc[rt][ct];
                unsigned p0 = (unsigned)f2bf(v[0] * dv[0]) | ((unsigned)f2bf(v[1] * dv[1]) << 16);
                unsigned p1 = (unsigned)f2bf(v[2] * dv[2]) | ((unsigned)f2bf(v[3] * dv[3]) << 16);
                uint2 pk; pk.x = p0; pk.y = p1;
                *(uint2*)(&s_ft[h * 264 + m0]) = pk;
            }
        }
        __syncthreads();

        // phase 4: h2 = relu(norm@FT2 + b2); emb = mean_n(h2)
#pragma unroll
        for (int a = 0; a < 2; ++a)
#pragma unroll
            for (int c = 0; c < 8; ++c) acc[a][c] = (f32x4){0.f, 0.f, 0.f, 0.f};
#pragma unroll
        for (int ks = 0; ks < 8; ++ks) {
            bf16x8 a0 = expand_bits(s_bm[(32 * w + li) * 32 + 4 * ks + lg]);
            bf16x8 a1 = expand_bits(s_bm[(32 * w + 16 + li) * 32 + 4 * ks + lg]);
#pragma unroll
            for (int ct = 0; ct < 8; ++ct) {
                bf16x8 bv = *(const bf16x8*)(&s_ft[(16 * ct + li) * 264 + lg * 8 + ks * 32]);
                acc[0][ct] = MFMA16(a0, bv, acc[0][ct]);
                acc[1][ct] = MFMA16(a1, bv, acc[1][ct]);
            }
        }
        int i0a = 32 * w + 4 * lg;
        f32x4 dv0 = *(const f32x4*)(&s_dinv[i0a]);
        f32x4 dv1 = *(const f32x4*)(&s_dinv[i0a + 16]);
#pragma unroll
        for (int ct = 0; ct < 8; ++ct) {
            int h = 16 * ct + li;
            float bb = s_b2[h];
            float s = 0.f;
#pragma unroll
            for (int r = 0; r < 4; ++r) {
                s += fmaxf(acc[0][ct][r] * dv0[r] + bb, 0.f);
                s += fmaxf(acc[1][ct][r] * dv1[r] + bb, 0.f);
            }
            s += __shfl_xor(s, 16);
            s += __shfl_xor(s, 32);
            if (lg == 0) s_pool[w * 128 + h] = s;
        }
        __syncthreads();
        float* s_emb = s_dinv;   // dead after phase 4
        if (tid < 128) {
            float e = 0.f;
#pragma unroll
            for (int ww = 0; ww < 8; ++ww) e += s_pool[ww * 128 + tid];
            s_emb[tid] = e * (1.f / 256.f);
        }
        __syncthreads();

        // xg row: xg[col] = emb . Wih0[col] + bih0[col] + bhh0[col]; publish epoch=1
        const f32x4* ev = (const f32x4*)s_emb;
#pragma unroll
        for (int cc = 0; cc < 2; ++cc) {
            int col = cc * 512 + tid;
            float a = bih0[col] + bhh0[col];
            const f32x4* wr = (const f32x4*)(Wih0 + (size_t)col * 128);
            float a0 = 0.f, a1 = 0.f, a2 = 0.f, a3 = 0.f;
            for (int k4 = 0; k4 < 32; k4 += 4) {
                f32x4 w0 = wr[k4], w1 = wr[k4 + 1], w2 = wr[k4 + 2], w3 = wr[k4 + 3];
                f32x4 e0 = ev[k4], e1 = ev[k4 + 1], e2 = ev[k4 + 2], e3 = ev[k4 + 3];
                a0 += w0[0]*e0[0] + w0[1]*e0[1] + w0[2]*e0[2] + w0[3]*e0[3];
                a1 += w1[0]*e1[0] + w1[1]*e1[1] + w1[2]*e1[2] + w1[3]*e1[3];
                a2 += w2[0]*e2[0] + w2[1]*e2[1] + w2[2]*e2[2] + w2[3]*e2[3];
                a3 += w3[0]*e3[0] + w3[1]*e3[1] + w3[2]*e3[2] + w3[3]*e3[3];
            }
            float v = a + ((a0 + a1) + (a2 + a3));
            unsigned long long pk = (unsigned long long)__builtin_bit_cast(unsigned, v)
                                  | (1ull << 32);
            st_u64(xgw + (size_t)k * 1024 + col, pk);
        }
    } else if (wg < 8) {
        // ===================== LSTM layer 0 =====================
        unsigned short* s_w = (unsigned short*)arena;            // [128][258] bf16
        unsigned short* s_h = (unsigned short*)(arena + 66048);  // [16][258] bf16
        float* s_gate = (float*)(arena + 74304);                 // [128][18] f32
        const int j0 = wg * 32;

#pragma unroll
        for (int it = 0; it < 16; ++it) {
            int e4 = tid + it * 512;
            int rl = e4 >> 6, k0 = (e4 & 63) * 4;
            int rg = (rl >> 5) * 256 + j0 + (rl & 31);
            float4 v = *(const float4*)(Whh0 + (size_t)rg * 256 + k0);
            uint2 pk;
            pk.x = (unsigned)f2bf(v.x) | ((unsigned)f2bf(v.y) << 16);
            pk.y = (unsigned)f2bf(v.z) | ((unsigned)f2bf(v.w) << 16);
            *(uint2*)(s_w + rl * 258 + k0) = pk;
        }
        __syncthreads();

        const int w = tid >> 6, li = lane & 15, lg = lane >> 4;
        const int cb = tid >> 5, cj = tid & 31;
        float c_reg = 0.f;

        for (int t = 0; t < 32; ++t) {
            // batched poll: 4 xg words (+ 4 h words for t>0), one MALL RT per round
            const unsigned long long* xsrc = xgw + (size_t)(t * 16 + cb) * 1024 + j0 + cj;
            unsigned long long xv[4];
            if (t > 0) {
                const unsigned long long* src = h0w + (size_t)(t - 1) * 2048;
                unsigned long long v[4];
                const unsigned e = (unsigned)t;
                for (;;) {
#pragma unroll
                    for (int q = 0; q < 4; ++q) v[q] = ld_u64(src + tid + q * 512);
#pragma unroll
                    for (int g = 0; g < 4; ++g) xv[g] = ld_u64(xsrc + g * 256);
                    bool ok = true;
#pragma unroll
                    for (int q = 0; q < 4; ++q) ok &= ((unsigned)(v[q] >> 32) == e);
#pragma unroll
                    for (int g = 0; g < 4; ++g) ok &= ((unsigned)(xv[g] >> 32) == 1u);
                    if (ok) break;
                    __builtin_amdgcn_s_sleep(1);
                }
#pragma unroll
                for (int q = 0; q < 4; ++q) {
                    int wd = tid + q * 512;
                    int b = wd >> 7, jp = wd & 127;
                    *(unsigned*)(s_h + b * 258 + jp * 2) = (unsigned)v[q];
                }
            } else {
                for (;;) {
#pragma unroll
                    for (int g = 0; g < 4; ++g) xv[g] = ld_u64(xsrc + g * 256);
                    bool ok = true;
#pragma unroll
                    for (int g = 0; g < 4; ++g) ok &= ((unsigned)(xv[g] >> 32) == 1u);
                    if (ok) break;
                    __builtin_amdgcn_s_sleep(1);
                }
            }
            __syncthreads();
            if (t > 0) {
                f32x4 acc = (f32x4){0.f, 0.f, 0.f, 0.f};
#pragma unroll
                for (int ks = 0; ks < 8; ++ks) {
                    bf16x8 af = *(const bf16x8*)(s_h + li * 258 + lg * 8 + ks * 32);
                    bf16x8 bf = *(const bf16x8*)(s_w + (16 * w + li) * 258 + lg * 8 + ks * 32);
                    acc = MFMA16(af, bf, acc);
                }
                int base = (16 * w + li) * 18 + 4 * lg;
                *(f32x2*)(s_gate + base) = (f32x2){acc[0], acc[1]};
                *(f32x2*)(s_gate + base + 2) = (f32x2){acc[2], acc[3]};
            }
            __syncthreads();
            {
                float gi = __builtin_bit_cast(float, (unsigned)xv[0]);
                float gf = __builtin_bit_cast(float, (unsigned)xv[1]);
                float gg = __builtin_bit_cast(float, (unsigned)xv[2]);
                float go = __builtin_bit_cast(float, (unsigned)xv[3]);
                if (t > 0) {
                    gi += s_gate[(0 * 32 + cj) * 18 + cb];
                    gf += s_gate[(1 * 32 + cj) * 18 + cb];
                    gg += s_gate[(2 * 32 + cj) * 18 + cb];
                    go += s_gate[(3 * 32 + cj) * 18 + cb];
                }
                c_reg = sigf(gf) * c_reg + sigf(gi) * tanhf_(gg);
                float h = sigf(go) * tanhf_(c_reg);
                unsigned hu = f2bf(h);
                unsigned other = __shfl_xor(hu, 1);
                if ((cj & 1) == 0) {
                    unsigned long long v = (unsigned long long)(hu | (other << 16))
                                         | ((unsigned long long)(t + 1) << 32);
                    st_u64(h0w + (size_t)t * 2048 + cb * 128 + ((j0 + cj) >> 1), v);
                }
            }
        }
    } else {
        // ===================== LSTM layer 1 =====================
        unsigned short* s_w = (unsigned short*)arena;            // [64][514] bf16
        unsigned short* s_h = (unsigned short*)(arena + 65792);  // [16][514] bf16
        float* s_gate = (float*)(arena + 82240);                 // [2][64][18] f32
        const int bi = wg - 8;
        const int j0 = bi * 16;

#pragma unroll
        for (int it = 0; it < 16; ++it) {
            int e4 = tid + it * 512;
            int rl = e4 >> 7, k0 = (e4 & 127) * 4;
            int rg = (rl >> 4) * 256 + j0 + (rl & 15);
            const float* src = (k0 < 256) ? (Wih1 + (size_t)rg * 256 + k0)
                                          : (Whh1 + (size_t)rg * 256 + (k0 - 256));
            float4 v = *(const float4*)src;
            uint2 pk;
            pk.x = (unsigned)f2bf(v.x) | ((unsigned)f2bf(v.y) << 16);
            pk.y = (unsigned)f2bf(v.z) | ((unsigned)f2bf(v.w) << 16);
            *(uint2*)(s_w + rl * 514 + k0) = pk;
        }

        const int w = tid >> 6, li = lane & 15, lg = lane >> 4;
        const int ct = w & 3, kh = w >> 2;
        const int cb = tid >> 4, cj = tid & 15;
        float bias[4];
        if (tid < 256) {
#pragma unroll
            for (int g = 0; g < 4; ++g) {
                int r = g * 256 + j0 + cj;
                bias[g] = bih1[r] + bhh1[r];
            }
        }
        __syncthreads();
        float c_reg = 0.f;

        for (int t = 0; t < 32; ++t) {
            const unsigned long long* s0 = h0w + (size_t)t * 2048;
            const unsigned long long* s1 = h1w + (size_t)(t - 1) * 2048;
            unsigned long long v[8];
            const unsigned e0 = (unsigned)(t + 1), e1 = (unsigned)t;
            if (t > 0) {
                for (;;) {
#pragma unroll
                    for (int q = 0; q < 4; ++q) v[q] = ld_u64(s0 + tid + q * 512);
#pragma unroll
                    for (int q = 0; q < 4; ++q) v[4 + q] = ld_u64(s1 + tid + q * 512);
                    bool ok = true;
#pragma unroll
                    for (int q = 0; q < 4; ++q) ok &= ((unsigned)(v[q] >> 32) == e0);
#pragma unroll
                    for (int q = 0; q < 4; ++q) ok &= ((unsigned)(v[4 + q] >> 32) == e1);
                    if (ok) break;
                    __builtin_amdgcn_s_sleep(1);
                }
            } else {
                for (;;) {
#pragma unroll
                    for (int q = 0; q < 4; ++q) v[q] = ld_u64(s0 + tid + q * 512);
                    bool ok = true;
#pragma unroll
                    for (int q = 0; q < 4; ++q) ok &= ((unsigned)(v[q] >> 32) == e0);
                    if (ok) break;
                    __builtin_amdgcn_s_sleep(1);
                }
#pragma unroll
                for (int q = 0; q < 4; ++q) v[4 + q] = 0ull;
            }
#pragma unroll
            for (int q = 0; q < 4; ++q) {
                int wd = tid + q * 512;
                int b = wd >> 7, jp = wd & 127;
                *(unsigned*)(s_h + b * 514 + jp * 2) = (unsigned)v[q];
                *(unsigned*)(s_h + b * 514 + 256 + jp * 2) = (unsigned)v[4 + q];
            }
            __syncthreads();
            {
                f32x4 acc = (f32x4){0.f, 0.f, 0.f, 0.f};
#pragma unroll
                for (int ks = 0; ks < 8; ++ks) {
                    int ko = (kh * 8 + ks) * 32;
                    bf16x8 af = *(const bf16x8*)(s_h + li * 514 + lg * 8 + ko);
                    bf16x8 bf = *(const bf16x8*)(s_w + (16 * ct + li) * 514 + lg * 8 + ko);
                    acc = MFMA16(af, bf, acc);
                }
                int base = kh * 1152 + (16 * ct + li) * 18 + 4 * lg;
                *(f32x2*)(s_gate + base) = (f32x2){acc[0], acc[1]};
                *(f32x2*)(s_gate + base + 2) = (f32x2){acc[2], acc[3]};
            }
            __syncthreads();
            if (tid < 256) {
                float gt[4];
#pragma unroll
                for (int g = 0; g < 4; ++g) {
                    int base = (g * 16 + cj) * 18 + cb;
                    gt[g] = s_gate[base] + s_gate[1152 + base] + bias[g];
                }
                c_reg = sigf(gt[1]) * c_reg + sigf(gt[0]) * tanhf_(gt[2]);
                float h = sigf(gt[3]) * tanhf_(c_reg);
                unsigned hu = f2bf(h);
                unsigned other = __shfl_xor(hu, 1);
                if ((cj & 1) == 0) {
                    unsigned long long v2 = (unsigned long long)(hu | (other << 16))
                                          | ((unsigned long long)(t + 1) << 32);
                    st_u64(h1w + (size_t)t * 2048 + cb * 128 + ((j0 + cj) >> 1), v2);
                }
            }
        }

        if (bi == 0) {
            float* s_red = s_gate;
            if (tid < 256) {
                int b = tid >> 4, kc = tid & 15;
                const unsigned long long* hw = h1w + (size_t)31 * 2048 + b * 128 + kc * 8;
                unsigned long long v[8];
                for (;;) {
#pragma unroll
                    for (int q = 0; q < 8; ++q) v[q] = ld_u64(hw + q);
                    bool ok = true;
#pragma unroll
                    for (int q = 0; q < 8; ++q) ok &= ((unsigned)(v[q] >> 32) == 32u);
                    if (ok) break;
                    __builtin_amdgcn_s_sleep(1);
                }
                float s = 0.f;
#pragma unroll
                for (int q = 0; q < 8; ++q) {
                    unsigned u = (unsigned)v[q];
                    s += Wfc[kc * 16 + 2 * q] * bf2f((unsigned short)(u & 0xffff));
                    s += Wfc[kc * 16 + 2 * q + 1] * bf2f((unsigned short)(u >> 16));
                }
                s_red[tid] = s;
            }
            __syncthreads();
            if (tid < 16) {
                float s = bfc[0];
#pragma unroll
                for (int q = 0; q < 16; ++q) s += s_red[tid * 16 + q];
                out[tid] = sigf(s);
            }
        }
    }
}

extern "C" void kernel_launch(void* const* d_in, const int* in_sizes, int n_in,
                              void* d_out, int out_size, void* d_ws, size_t ws_size,
                              hipStream_t stream) {
    const int*   adj  = (const int*)  d_in[0];
    const float* x    = (const float*)d_in[1];
    const float* W1   = (const float*)d_in[2];
    const float* b1   = (const float*)d_in[3];
    const float* W2   = (const float*)d_in[4];
    const float* b2   = (const float*)d_in[5];
    const float* Wih0 = (const float*)d_in[6];
    const float* Whh0 = (const float*)d_in[7];
    const float* bih0 = (const float*)d_in[8];
    const float* bhh0 = (const float*)d_in[9];
    const float* Wih1 = (const float*)d_in[10];
    const float* Whh1 = (const float*)d_in[11];
    const float* bih1 = (const float*)d_in[12];
    const float* bhh1 = (const float*)d_in[13];
    const float* Wfc  = (const float*)d_in[14];
    const float* bfc  = (const float*)d_in[15];
    float* out = (float*)d_out;

    if (ws_size < 5308416) return;   // ~5.1 MB scratch

    char* ws = (char*)d_ws;
    unsigned long long* xgw = (unsigned long long*)(ws);             // 4,194,304 B
    unsigned long long* h0w = (unsigned long long*)(ws + 4194304);   //   524,288 B
    unsigned long long* h1w = (unsigned long long*)(ws + 4718592);   //   524,288 B
    unsigned short* w1t = (unsigned short*)(ws + 5242880);           //    32,768 B
    unsigned short* w2t = (unsigned short*)(ws + 5275648);           //    32,768 B

    hipMemsetAsync(ws, 0, 5242880, stream);   // zero xg + h epochs
    k_prep<<<64, 256, 0, stream>>>(W1, W2, w1t, w2t);
    k_fused<<<536, 512, 0, stream>>>(adj, x, w1t, w2t, b1, b2,
                                     Wih0, bih0, bhh0, Whh0, Wih1, Whh1,
                                     bih1, bhh1, Wfc, bfc,
                                     xgw, h0w, h1w, out);
}